// Round 1
// baseline (2799.933 us; speedup 1.0000x reference)
//
#include <hip/hip_runtime.h>
#include <math.h>

#define CDIV(a,b) (((a)+(b)-1)/(b))

__device__ __forceinline__ float sigf(float x){ return 1.0f/(1.0f+expf(-x)); }

// ---------------- utility ----------------
__global__ void zero_kernel(float* __restrict__ p, size_t n){
  size_t i=(size_t)blockIdx.x*blockDim.x+threadIdx.x;
  size_t st=(size_t)gridDim.x*blockDim.x;
  for(;i<n;i+=st) p[i]=0.0f;
}

// ---------------- CSR build ----------------
__global__ void hist_kernel(const int* __restrict__ ei, int E, int N, int* __restrict__ deg){
  int e=blockIdx.x*blockDim.x+threadIdx.x;
  if(e>=E+N) return;
  int d=(e<E)? ei[E+e] : (e-E);
  atomicAdd(&deg[d],1);
}

__global__ void scan1_kernel(const int* __restrict__ deg, int* __restrict__ offs,
                             int* __restrict__ bsums, int N){
  __shared__ int sd[1024];
  int t=threadIdx.x;
  int i=blockIdx.x*1024+t;
  int v=(i<N)?deg[i]:0;
  sd[t]=v;
  __syncthreads();
  for(int s=1;s<1024;s<<=1){
    int u=(t>=s)?sd[t-s]:0;
    __syncthreads();
    sd[t]+=u;
    __syncthreads();
  }
  if(i<N) offs[i]=sd[t]-v;
  if(t==1023) bsums[blockIdx.x]=sd[1023];
}

__global__ void scan2_kernel(int* __restrict__ bsums, int* __restrict__ offs, int NB, int N){
  if(threadIdx.x==0&&blockIdx.x==0){
    int run=0;
    for(int b=0;b<NB;b++){int s=bsums[b]; bsums[b]=run; run+=s;}
    offs[N]=run;
  }
}

__global__ void scan3_kernel(int* __restrict__ offs, const int* __restrict__ bsums,
                             int* __restrict__ cursor, int N){
  int i=blockIdx.x*blockDim.x+threadIdx.x;
  if(i<N){
    int o=offs[i]+bsums[i>>10];
    offs[i]=o;
    cursor[i]=o;
  }
}

__global__ void scatter_kernel(const int* __restrict__ ei, int E, int N,
                               int* __restrict__ cursor, int* __restrict__ csr){
  int e=blockIdx.x*blockDim.x+threadIdx.x;
  if(e>=E+N) return;
  int s,d;
  if(e<E){ s=ei[e]; d=ei[E+e]; } else { s=e-E; d=s; }
  int pos=atomicAdd(&cursor[d],1);
  csr[pos]=s;
}

// ---------------- fp32 GEMM: C[M x 128*gridDim.x tile] ----------------
// C[m][n] = sum_k Asrc[m][k] * Bsrc[n or k][...]  with dual K-source at kSplit.
// BLAYOUT 0: B[k][n] (ldb = out cols count), BLAYOUT 1: B[n][k] (ldb = K of that source)
template<int BLAYOUT>
__global__ __launch_bounds__(256,2) void gemm128(
    const float* __restrict__ A0, int lda0, const float* __restrict__ A1, int lda1,
    const float* __restrict__ B0, int ldb0, const float* __restrict__ B1, int ldb1,
    int kSplit, const float* __restrict__ bias0, const float* __restrict__ bias1,
    float* __restrict__ C, int ldc, int M, int K)
{
  __shared__ float As[16][132];
  __shared__ float Bs[16][132];
  const int t = threadIdx.x;
  const int m0 = blockIdx.y*128, n0 = blockIdx.x*128;
  const int ty = t>>4, tx = t&15;
  float acc[2][2][4][4];
#pragma unroll
  for(int a=0;a<2;a++)
#pragma unroll
  for(int b=0;b<2;b++)
#pragma unroll
  for(int i=0;i<4;i++)
#pragma unroll
  for(int j=0;j<4;j++) acc[a][b][i][j]=0.f;

  for (int k0=0; k0<K; k0+=16){
    const float* A; int lda, ka;
    const float* B; int ldb, kb;
    if (k0 < kSplit){ A=A0; lda=lda0; ka=k0; B=B0; ldb=ldb0; kb=k0; }
    else            { A=A1; lda=lda1; ka=k0-kSplit; B=B1; ldb=ldb1; kb=k0-kSplit; }
#pragma unroll
    for (int ff=0; ff<2; ff++){
      int f = t + ff*256;
      int row = f>>2, kq = f&3;
      int gr = m0+row; if (gr>=M) gr=0;
      float4 av = *reinterpret_cast<const float4*>(A + (size_t)gr*lda + (ka + kq*4));
      As[kq*4+0][row]=av.x; As[kq*4+1][row]=av.y; As[kq*4+2][row]=av.z; As[kq*4+3][row]=av.w;
    }
#pragma unroll
    for (int ff=0; ff<2; ff++){
      int f = t+ff*256;
      if (BLAYOUT==0){
        int kk=f>>5, nq=f&31;
        float4 bv = *reinterpret_cast<const float4*>(B + (size_t)(kb+kk)*ldb + (n0+nq*4));
        *reinterpret_cast<float4*>(&Bs[kk][nq*4]) = bv;
      } else {
        int row=f>>2, kq=f&3;
        float4 bv = *reinterpret_cast<const float4*>(B + (size_t)(n0+row)*ldb + (kb+kq*4));
        Bs[kq*4+0][row]=bv.x; Bs[kq*4+1][row]=bv.y; Bs[kq*4+2][row]=bv.z; Bs[kq*4+3][row]=bv.w;
      }
    }
    __syncthreads();
#pragma unroll
    for(int k=0;k<16;k++){
      const float4 a0v=*reinterpret_cast<const float4*>(&As[k][ty*4]);
      const float4 a1v=*reinterpret_cast<const float4*>(&As[k][64+ty*4]);
      const float4 b0v=*reinterpret_cast<const float4*>(&Bs[k][tx*4]);
      const float4 b1v=*reinterpret_cast<const float4*>(&Bs[k][64+tx*4]);
      const float a[2][4]={{a0v.x,a0v.y,a0v.z,a0v.w},{a1v.x,a1v.y,a1v.z,a1v.w}};
      const float b[2][4]={{b0v.x,b0v.y,b0v.z,b0v.w},{b1v.x,b1v.y,b1v.z,b1v.w}};
#pragma unroll
      for(int rh=0;rh<2;rh++)
#pragma unroll
      for(int i=0;i<4;i++)
#pragma unroll
      for(int ch=0;ch<2;ch++)
#pragma unroll
      for(int jj=0;jj<4;jj++)
        acc[rh][ch][i][jj]+=a[rh][i]*b[ch][jj];
    }
    __syncthreads();
  }
#pragma unroll
  for (int rh=0; rh<2; rh++)
#pragma unroll
  for (int i=0;i<4;i++){
    int r = m0 + rh*64 + ty*4 + i;
    if (r<M){
#pragma unroll
      for (int ch=0; ch<2; ch++){
        int col = n0 + ch*64 + tx*4;
        float4 o;
        o.x=acc[rh][ch][i][0]; o.y=acc[rh][ch][i][1]; o.z=acc[rh][ch][i][2]; o.w=acc[rh][ch][i][3];
        if (bias0){ o.x+=bias0[col]; o.y+=bias0[col+1]; o.z+=bias0[col+2]; o.w+=bias0[col+3]; }
        if (bias1){ o.x+=bias1[col]; o.y+=bias1[col+1]; o.z+=bias1[col+2]; o.w+=bias1[col+3]; }
        *reinterpret_cast<float4*>(C + (size_t)r*ldc + col) = o;
      }
    }
  }
}

// ---------------- GAT attention pieces ----------------
__global__ __launch_bounds__(128) void esed_kernel(const float* __restrict__ htmp,
    const float* __restrict__ as, const float* __restrict__ ad,
    float* __restrict__ es, float* __restrict__ ed, int N){
  int n=blockIdx.x; int j=threadIdx.x;
  float h=htmp[(size_t)n*128+j];
  float ps=h*as[j], pd=h*ad[j];
  for(int s=16;s>=1;s>>=1){ ps+=__shfl_xor(ps,s); pd+=__shfl_xor(pd,s); }
  if((j&31)==0){ es[n*4+(j>>5)]=ps; ed[n*4+(j>>5)]=pd; }
}

__global__ __launch_bounds__(256) void attn_kernel(const float* __restrict__ htmp,
   const float* __restrict__ es, const float* __restrict__ ed,
   const int* __restrict__ offs, const int* __restrict__ csr,
   const float* __restrict__ bias, float* __restrict__ outp, int N){
  int v=blockIdx.x*4+(threadIdx.x>>6);
  if(v>=N) return;
  int lane=threadIdx.x&63;
  int hd=lane>>4;          // head for this lane's channels
  int c0=lane*2;
  int beg=offs[v], end=offs[v+1];
  float edv=ed[v*4+hd];
  float mx=-3.0e38f;
  for(int i=beg;i<end;i++){
    int s=csr[i];
    float e=es[s*4+hd]+edv;
    e=(e>0.f)?e:0.2f*e;
    mx=fmaxf(mx,e);
  }
  float ssum=0.f,a0=0.f,a1=0.f;
  for(int i=beg;i<end;i++){
    int s=csr[i];
    float e=es[s*4+hd]+edv;
    e=(e>0.f)?e:0.2f*e;
    float ex=expf(e-mx);
    ssum+=ex;
    float2 hv=*reinterpret_cast<const float2*>(htmp+(size_t)s*128+c0);
    a0+=ex*hv.x; a1+=ex*hv.y;
  }
  float inv=1.0f/(ssum+1e-16f);
  float o0=a0*inv+bias[c0], o1=a1*inv+bias[c0+1];
  float2 o; o.x=fmaxf(o0,0.f); o.y=fmaxf(o1,0.f);
  *reinterpret_cast<float2*>(outp+(size_t)v*128+c0)=o;
}

// ---------------- LSTM gates + on-the-fly JK score ----------------
__global__ __launch_bounds__(192) void gates_kernel(const float* __restrict__ z,
    float* __restrict__ hbuf, float* __restrict__ cbuf,
    const float* __restrict__ wa, float* __restrict__ score,
    int l_out, int setScore, int rowOff){
  int row=blockIdx.x;
  int j=threadIdx.x;
  const float* zr=z+(size_t)row*768;
  float zi=zr[j], zf=zr[192+j], zg=zr[384+j], zo=zr[576+j];
  size_t gi=(size_t)(rowOff+row)*192+j;
  float c=sigf(zf)*cbuf[gi]+sigf(zi)*tanhf(zg);
  float h=sigf(zo)*tanhf(c);
  cbuf[gi]=c; hbuf[gi]=h;
  float p=h*wa[j];
  for(int s=32;s>=1;s>>=1) p+=__shfl_down(p,s);
  __shared__ float sm[3];
  if((j&63)==0) sm[j>>6]=p;
  __syncthreads();
  if(j==0){
    float tot=sm[0]+sm[1]+sm[2];
    size_t si=(size_t)(rowOff+row)*3+l_out;
    if(setScore) score[si]=tot; else score[si]+=tot;
  }
}

// ---------------- JK softmax + weighted sum + pooling ----------------
__global__ __launch_bounds__(128) void jk_pool_kernel(const float* __restrict__ xs, size_t xstride,
   const float* __restrict__ score, const int* __restrict__ batch,
   float* __restrict__ pooled, float* __restrict__ counts, int N){
  int n=blockIdx.x; int c=threadIdx.x;
  float s0=score[n*3],s1=score[n*3+1],s2=score[n*3+2];
  float m=fmaxf(s0,fmaxf(s1,s2));
  float e0=expf(s0-m),e1=expf(s1-m),e2=expf(s2-m);
  float inv=1.0f/(e0+e1+e2);
  size_t base=(size_t)n*128+c;
  float jk=(xs[base]*e0+xs[xstride+base]*e1+xs[2*xstride+base]*e2)*inv;
  int g=batch[n];
  atomicAdd(&pooled[(size_t)g*128+c],jk);
  if(c==0) atomicAdd(&counts[g],1.0f);
}

__global__ __launch_bounds__(128) void final_kernel(const float* __restrict__ pooled,
   const float* __restrict__ counts, const float* __restrict__ Wl,
   const float* __restrict__ bl, float* __restrict__ out, int G){
  int g=blockIdx.x; int c=threadIdx.x;
  float cnt=fmaxf(counts[g],1.0f);
  float pv=pooled[(size_t)g*128+c]/cnt;
  float p0=pv*Wl[c*2], p1=pv*Wl[c*2+1];
  for(int s=32;s>=1;s>>=1){ p0+=__shfl_down(p0,s); p1+=__shfl_down(p1,s); }
  __shared__ float sm[4];
  int w=c>>6;
  if((c&63)==0){ sm[w*2]=p0; sm[w*2+1]=p1; }
  __syncthreads();
  if(c==0){
    out[g*2+0]=sm[0]+sm[2]+bl[0];
    out[g*2+1]=sm[1]+sm[3]+bl[1];
  }
}

// ---------------- launch ----------------
extern "C" void kernel_launch(void* const* d_in, const int* in_sizes, int n_in,
                              void* d_out, int out_size, void* d_ws, size_t ws_size,
                              hipStream_t stream) {
  const float* x     = (const float*)d_in[0];
  const int*   ei    = (const int*)d_in[1];
  const int*   batch = (const int*)d_in[2];
  const float* W[3]  = {(const float*)d_in[3],(const float*)d_in[7],(const float*)d_in[11]};
  const float* AS[3] = {(const float*)d_in[4],(const float*)d_in[8],(const float*)d_in[12]};
  const float* AD[3] = {(const float*)d_in[5],(const float*)d_in[9],(const float*)d_in[13]};
  const float* BV[3] = {(const float*)d_in[6],(const float*)d_in[10],(const float*)d_in[14]};
  const float* Wih[2]= {(const float*)d_in[15],(const float*)d_in[19]};
  const float* Whh[2]= {(const float*)d_in[16],(const float*)d_in[20]};
  const float* bih[2]= {(const float*)d_in[17],(const float*)d_in[21]};
  const float* bhh[2]= {(const float*)d_in[18],(const float*)d_in[22]};
  const float* Wa    = (const float*)d_in[23];
  const float* Wl    = (const float*)d_in[25];
  const float* bl    = (const float*)d_in[26];
  float* out = (float*)d_out;

  const int N  = in_sizes[2];
  const int E  = in_sizes[1]/2;
  const int ET = E+N;
  const int G  = out_size/2;

  // workspace carve (256B aligned)
  char* p = (char*)d_ws;
  auto alloc = [&](size_t bytes)->char*{ char* r=p; p += ((bytes+255)/256)*256; return r; };
  int*   deg    = (int*)  alloc((size_t)N*4);
  int*   offs   = (int*)  alloc((size_t)(N+1)*4);
  int*   cursor = (int*)  alloc((size_t)N*4);
  int*   bsums  = (int*)  alloc((size_t)CDIV(N,1024)*4);
  int*   csr    = (int*)  alloc((size_t)ET*4);
  float* es     = (float*)alloc((size_t)N*4*4);
  float* ed     = (float*)alloc((size_t)N*4*4);
  float* xs     = (float*)alloc((size_t)3*N*128*4);
  float* htmp   = (float*)alloc((size_t)N*128*4);
  float* hc     = (float*)alloc((size_t)2*N*192*4);   // h then c
  float* score  = (float*)alloc((size_t)N*3*4);
  float* pooled = (float*)alloc((size_t)(G*128+G)*4); // pooled then counts
  float* counts = pooled + (size_t)G*128;
  size_t used = (size_t)(p-(char*)d_ws);
  size_t remain = (ws_size>used)? (ws_size-used) : 0;
  int CHUNK = (int)((remain/((size_t)768*4)));
  if (CHUNK > N) CHUNK = N;
  if (CHUNK < 2048) CHUNK = 2048;   // minimal fallback
  float* zbuf = (float*)p;

  const size_t xstride = (size_t)N*128;
  float* hbuf = hc;
  float* cbuf = hc + (size_t)N*192;

  // 1. CSR build
  zero_kernel<<<2048,256,0,stream>>>((float*)deg,(size_t)N);
  hist_kernel<<<CDIV(ET,256),256,0,stream>>>(ei,E,N,deg);
  int NB = CDIV(N,1024);
  scan1_kernel<<<NB,1024,0,stream>>>(deg,offs,bsums,N);
  scan2_kernel<<<1,64,0,stream>>>(bsums,offs,NB,N);
  scan3_kernel<<<CDIV(N,256),256,0,stream>>>(offs,bsums,cursor,N);
  scatter_kernel<<<CDIV(ET,256),256,0,stream>>>(ei,E,N,cursor,csr);

  // 2. GAT layers
  const float* hin = x;
  for (int l=0; l<3; l++){
    gemm128<0><<<dim3(1,CDIV(N,128)),256,0,stream>>>(
        hin,128, nullptr,0, W[l],128, nullptr,0, 128, nullptr,nullptr,
        htmp,128, N, 128);
    esed_kernel<<<N,128,0,stream>>>(htmp,AS[l],AD[l],es,ed,N);
    attn_kernel<<<CDIV(N,4),256,0,stream>>>(htmp,es,ed,offs,csr,BV[l],xs+(size_t)l*xstride,N);
    hin = xs+(size_t)l*xstride;
  }

  // 3. bidirectional LSTM over the 3 layer outputs, scores on the fly
  for (int dir=0; dir<2; dir++){
    zero_kernel<<<2048,256,0,stream>>>(hc,(size_t)2*N*192);
    for (int st=0; st<3; st++){
      int l_in = dir? (2-st) : st;    // which xs is consumed; also the score slot
      const float* xt = xs + (size_t)l_in*xstride;
      for (int c0=0; c0<N; c0+=CHUNK){
        int Mr = (N-c0 < CHUNK)? (N-c0) : CHUNK;
        gemm128<1><<<dim3(6,CDIV(Mr,128)),256,0,stream>>>(
            xt + (size_t)c0*128, 128, hbuf + (size_t)c0*192, 192,
            Wih[dir],128, Whh[dir],192, 128, bih[dir], bhh[dir],
            zbuf, 768, Mr, 320);
        gates_kernel<<<Mr,192,0,stream>>>(zbuf,hbuf,cbuf,Wa+dir*192,score,l_in,(dir==0)?1:0,c0);
      }
    }
  }

  // 4. JK attention + pooling + final linear
  zero_kernel<<<512,256,0,stream>>>(pooled,(size_t)(G*128+G));
  jk_pool_kernel<<<N,128,0,stream>>>(xs,xstride,score,batch,pooled,counts,N);
  final_kernel<<<G,128,0,stream>>>(pooled,counts,Wl,bl,out,G);
}

// Round 2
// 1709.759 us; speedup vs baseline: 1.6376x; 1.6376x over previous
//
#include <hip/hip_runtime.h>
#include <math.h>

#define CDIV(a,b) (((a)+(b)-1)/(b))

typedef _Float16 f16;
typedef _Float16 f16x8 __attribute__((ext_vector_type(8)));
typedef float f32x4 __attribute__((ext_vector_type(4)));

__device__ __forceinline__ float sigf(float x){ return 1.0f/(1.0f+expf(-x)); }

// ---------------- utility ----------------
__global__ void zero_kernel(float* __restrict__ p, size_t n){
  size_t i=(size_t)blockIdx.x*blockDim.x+threadIdx.x;
  size_t st=(size_t)gridDim.x*blockDim.x;
  for(;i<n;i+=st) p[i]=0.0f;
}

// ---------------- fp16 conversion prep ----------------
__global__ void f2h_kernel(const float* __restrict__ s, f16* __restrict__ d, size_t n){
  size_t i=(size_t)blockIdx.x*blockDim.x+threadIdx.x;
  size_t st=(size_t)gridDim.x*blockDim.x;
  for(;i<n;i+=st) d[i]=(f16)s[i];
}
__global__ void f2h_split_kernel(const float* __restrict__ s, f16* __restrict__ hi,
                                 f16* __restrict__ lo, size_t n){
  size_t i=(size_t)blockIdx.x*blockDim.x+threadIdx.x;
  size_t st=(size_t)gridDim.x*blockDim.x;
  for(;i<n;i+=st){ float f=s[i]; f16 h=(f16)f; hi[i]=h; lo[i]=(f16)(f-(float)h); }
}
// W [128 in][128 out] -> Wt hi/lo [out][in]
__global__ void wtrans_kernel(const float* __restrict__ W, f16* __restrict__ hi,
                              f16* __restrict__ lo){
  int o=blockIdx.x, i=threadIdx.x;
  float f=W[(size_t)i*128+o];
  f16 h=(f16)f; hi[o*128+i]=h; lo[o*128+i]=(f16)(f-(float)h);
}
__global__ void bias2_kernel(const float* __restrict__ a, const float* __restrict__ b,
                             float* __restrict__ o, int n){
  int i=blockIdx.x*blockDim.x+threadIdx.x;
  if(i<n) o[i]=a[i]+b[i];
}

// ---------------- CSR build ----------------
__global__ void hist_kernel(const int* __restrict__ ei, int E, int N, int* __restrict__ deg){
  int e=blockIdx.x*blockDim.x+threadIdx.x;
  if(e>=E+N) return;
  int d=(e<E)? ei[E+e] : (e-E);
  atomicAdd(&deg[d],1);
}
__global__ void scan1_kernel(const int* __restrict__ deg, int* __restrict__ offs,
                             int* __restrict__ bsums, int N){
  __shared__ int sd[1024];
  int t=threadIdx.x;
  int i=blockIdx.x*1024+t;
  int v=(i<N)?deg[i]:0;
  sd[t]=v;
  __syncthreads();
  for(int s=1;s<1024;s<<=1){
    int u=(t>=s)?sd[t-s]:0;
    __syncthreads();
    sd[t]+=u;
    __syncthreads();
  }
  if(i<N) offs[i]=sd[t]-v;
  if(t==1023) bsums[blockIdx.x]=sd[1023];
}
__global__ void scan2_kernel(int* __restrict__ bsums, int* __restrict__ offs, int NB, int N){
  if(threadIdx.x==0&&blockIdx.x==0){
    int run=0;
    for(int b=0;b<NB;b++){int s=bsums[b]; bsums[b]=run; run+=s;}
    offs[N]=run;
  }
}
__global__ void scan3_kernel(int* __restrict__ offs, const int* __restrict__ bsums,
                             int* __restrict__ cursor, int N){
  int i=blockIdx.x*blockDim.x+threadIdx.x;
  if(i<N){
    int o=offs[i]+bsums[i>>10];
    offs[i]=o;
    cursor[i]=o;
  }
}
__global__ void scatter_kernel(const int* __restrict__ ei, int E, int N,
                               int* __restrict__ cursor, int* __restrict__ csr){
  int e=blockIdx.x*blockDim.x+threadIdx.x;
  if(e>=E+N) return;
  int s,d;
  if(e<E){ s=ei[e]; d=ei[E+e]; } else { s=e-E; d=s; }
  int pos=atomicAdd(&cursor[d],1);
  csr[pos]=s;
}

// ---------------- MFMA GEMM (fp16 in, fp32 out), 128x128 tile, BK=64 ----------------
// C[m][n] = sum over nt K-tiles of A_t[m][0..64) * B_t[n][0..64)  (B stored [n][k])
struct GemmDesc {
  const f16* a[10]; const f16* b[10];
  int lda[10], ldb[10];
  int nt; int M; long ldc;
  const float* bias;
  float* C;
};

__global__ __launch_bounds__(256) void gemm_mfma(GemmDesc d){
  __shared__ __align__(16) f16 As[128*64];
  __shared__ __align__(16) f16 Bs[128*64];
  const int t = threadIdx.x;
  const int wv = t>>6, ln = t&63;
  const int m0 = blockIdx.y*128, n0 = blockIdx.x*128;
  const int wr = (wv>>1)*64, wc = (wv&1)*64;
  f32x4 acc[4][4];
#pragma unroll
  for(int i=0;i<4;i++)
#pragma unroll
  for(int j=0;j<4;j++) acc[i][j]=(f32x4){0.f,0.f,0.f,0.f};

  const int sR = ln>>3;        // row within 8-row group
  const int sC = (ln&7)*8;     // f16 col within 64

  for (int kt=0; kt<d.nt; kt++){
    const f16* aS = d.a[kt]; const int lda = d.lda[kt];
    const f16* bS = d.b[kt]; const int ldb = d.ldb[kt];
#pragma unroll
    for (int i=0;i<4;i++){
      int lrow = i*32 + wv*8;                 // wave-uniform base row
      int gr = m0 + lrow + sR; if (gr >= d.M) gr = d.M-1;
      const f16* ga = aS + (size_t)gr*lda + sC;
      __builtin_amdgcn_global_load_lds(
        (const __attribute__((address_space(1))) unsigned int*)ga,
        (__attribute__((address_space(3))) unsigned int*)&As[lrow*64], 16, 0, 0);
      const f16* gb = bS + (size_t)(n0 + lrow + sR)*ldb + sC;
      __builtin_amdgcn_global_load_lds(
        (const __attribute__((address_space(1))) unsigned int*)gb,
        (__attribute__((address_space(3))) unsigned int*)&Bs[lrow*64], 16, 0, 0);
    }
    __syncthreads();
#pragma unroll
    for (int kk=0; kk<2; kk++){
      f16x8 av[4], bv[4];
#pragma unroll
      for (int i=0;i<4;i++)
        av[i] = *(const f16x8*)&As[(wr + i*16 + (ln&15))*64 + kk*32 + (ln>>4)*8];
#pragma unroll
      for (int j=0;j<4;j++)
        bv[j] = *(const f16x8*)&Bs[(wc + j*16 + (ln&15))*64 + kk*32 + (ln>>4)*8];
#pragma unroll
      for (int i=0;i<4;i++)
#pragma unroll
      for (int j=0;j<4;j++)
        acc[i][j] = __builtin_amdgcn_mfma_f32_16x16x32_f16(av[i], bv[j], acc[i][j], 0,0,0);
    }
    __syncthreads();
  }
  const int lc = ln&15, lr4 = (ln>>4)*4;
#pragma unroll
  for (int j=0;j<4;j++){
    int col = n0 + wc + j*16 + lc;
    float bb = d.bias ? d.bias[col] : 0.f;
#pragma unroll
    for (int i=0;i<4;i++){
      int rbase = m0 + wr + i*16 + lr4;
#pragma unroll
      for (int r=0;r<4;r++){
        int row = rbase + r;
        if (row < d.M) d.C[(size_t)row*d.ldc + col] = acc[i][j][r] + bb;
      }
    }
  }
}

// ---------------- GAT attention pieces ----------------
__global__ __launch_bounds__(128) void esed_kernel(const float* __restrict__ htmp,
    const float* __restrict__ as, const float* __restrict__ ad,
    float* __restrict__ es, float* __restrict__ ed, int N){
  int n=blockIdx.x; int j=threadIdx.x;
  float h=htmp[(size_t)n*128+j];
  float ps=h*as[j], pd=h*ad[j];
  for(int s=16;s>=1;s>>=1){ ps+=__shfl_xor(ps,s); pd+=__shfl_xor(pd,s); }
  if((j&31)==0){ es[n*4+(j>>5)]=ps; ed[n*4+(j>>5)]=pd; }
}

__global__ __launch_bounds__(256) void attn_kernel(const float* __restrict__ htmp,
   const float* __restrict__ es, const float* __restrict__ ed,
   const int* __restrict__ offs, const int* __restrict__ csr,
   const float* __restrict__ bias, f16* __restrict__ xsl, int N){
  int v=blockIdx.x*4+(threadIdx.x>>6);
  if(v>=N) return;
  int lane=threadIdx.x&63;
  int hd=lane>>4;          // head for this lane's channels
  int c0=lane*2;
  int beg=offs[v], end=offs[v+1];
  float edv=ed[v*4+hd];
  float mx=-3.0e38f;
  for(int i=beg;i<end;i++){
    int s=csr[i];
    float e=es[s*4+hd]+edv;
    e=(e>0.f)?e:0.2f*e;
    mx=fmaxf(mx,e);
  }
  float ssum=0.f,a0=0.f,a1=0.f;
  for(int i=beg;i<end;i++){
    int s=csr[i];
    float e=es[s*4+hd]+edv;
    e=(e>0.f)?e:0.2f*e;
    float ex=expf(e-mx);
    ssum+=ex;
    float2 hv=*reinterpret_cast<const float2*>(htmp+(size_t)s*128+c0);
    a0+=ex*hv.x; a1+=ex*hv.y;
  }
  float inv=1.0f/(ssum+1e-16f);
  float o0=fmaxf(a0*inv+bias[c0],0.f), o1=fmaxf(a1*inv+bias[c0+1],0.f);
  union { f16 h[2]; unsigned u; } pk;
  pk.h[0]=(f16)o0; pk.h[1]=(f16)o1;
  *reinterpret_cast<unsigned*>(&xsl[(size_t)v*128+c0]) = pk.u;
}

// ---------------- LSTM gates + on-the-fly JK score ----------------
__global__ __launch_bounds__(192) void gates_kernel(const float* __restrict__ z,
    f16* __restrict__ h16, float* __restrict__ cbuf,
    const float* __restrict__ wa, float* __restrict__ score,
    int l_out, int setScore, int rowOff, int Mr){
  int j=threadIdx.x;
  __shared__ float sm[3];
  for (int row=blockIdx.x; row<Mr; row+=gridDim.x){
    const float* zr=z+(size_t)row*768;
    float zi=zr[j], zf=zr[192+j], zg=zr[384+j], zo=zr[576+j];
    size_t gi=(size_t)(rowOff+row)*192+j;
    float c=sigf(zf)*cbuf[gi]+sigf(zi)*tanhf(zg);
    float h=sigf(zo)*tanhf(c);
    cbuf[gi]=c; h16[gi]=(f16)h;
    float p=h*wa[j];
    for(int s=32;s>=1;s>>=1) p+=__shfl_down(p,s);
    if((j&63)==0) sm[j>>6]=p;
    __syncthreads();
    if(j==0){
      float tot=sm[0]+sm[1]+sm[2];
      size_t si=(size_t)(rowOff+row)*3+l_out;
      if(setScore) score[si]=tot; else score[si]+=tot;
    }
    __syncthreads();
  }
}

// ---------------- JK softmax + weighted sum + pooling ----------------
__global__ __launch_bounds__(128) void jk_pool_kernel(const f16* __restrict__ xs, size_t xstride,
   const float* __restrict__ score, const int* __restrict__ batch,
   float* __restrict__ pooled, float* __restrict__ counts, int N){
  int n=blockIdx.x; int c=threadIdx.x;
  float s0=score[n*3],s1=score[n*3+1],s2=score[n*3+2];
  float m=fmaxf(s0,fmaxf(s1,s2));
  float e0=expf(s0-m),e1=expf(s1-m),e2=expf(s2-m);
  float inv=1.0f/(e0+e1+e2);
  size_t base=(size_t)n*128+c;
  float jk=((float)xs[base]*e0+(float)xs[xstride+base]*e1+(float)xs[2*xstride+base]*e2)*inv;
  int g=batch[n];
  atomicAdd(&pooled[(size_t)g*128+c],jk);
  if(c==0) atomicAdd(&counts[g],1.0f);
}

__global__ __launch_bounds__(128) void final_kernel(const float* __restrict__ pooled,
   const float* __restrict__ counts, const float* __restrict__ Wl,
   const float* __restrict__ bl, float* __restrict__ out, int G){
  int g=blockIdx.x; int c=threadIdx.x;
  float cnt=fmaxf(counts[g],1.0f);
  float pv=pooled[(size_t)g*128+c]/cnt;
  float p0=pv*Wl[c*2], p1=pv*Wl[c*2+1];
  for(int s=32;s>=1;s>>=1){ p0+=__shfl_down(p0,s); p1+=__shfl_down(p1,s); }
  __shared__ float sm[4];
  int w=c>>6;
  if((c&63)==0){ sm[w*2]=p0; sm[w*2+1]=p1; }
  __syncthreads();
  if(c==0){
    out[g*2+0]=sm[0]+sm[2]+bl[0];
    out[g*2+1]=sm[1]+sm[3]+bl[1];
  }
}

// ---------------- launch ----------------
extern "C" void kernel_launch(void* const* d_in, const int* in_sizes, int n_in,
                              void* d_out, int out_size, void* d_ws, size_t ws_size,
                              hipStream_t stream) {
  const float* x     = (const float*)d_in[0];
  const int*   ei    = (const int*)d_in[1];
  const int*   batch = (const int*)d_in[2];
  const float* W[3]  = {(const float*)d_in[3],(const float*)d_in[7],(const float*)d_in[11]};
  const float* AS[3] = {(const float*)d_in[4],(const float*)d_in[8],(const float*)d_in[12]};
  const float* AD[3] = {(const float*)d_in[5],(const float*)d_in[9],(const float*)d_in[13]};
  const float* BV[3] = {(const float*)d_in[6],(const float*)d_in[10],(const float*)d_in[14]};
  const float* Wih[2]= {(const float*)d_in[15],(const float*)d_in[19]};
  const float* Whh[2]= {(const float*)d_in[16],(const float*)d_in[20]};
  const float* bih[2]= {(const float*)d_in[17],(const float*)d_in[21]};
  const float* bhh[2]= {(const float*)d_in[18],(const float*)d_in[22]};
  const float* Wa    = (const float*)d_in[23];
  const float* Wl    = (const float*)d_in[25];
  const float* bl    = (const float*)d_in[26];
  float* out = (float*)d_out;

  const int N  = in_sizes[2];
  const int E  = in_sizes[1]/2;
  const int ET = E+N;
  const int G  = out_size/2;
  const int Mpad = CDIV(N,128)*128;

  // ---- workspace carve (256B aligned) ----
  char* p = (char*)d_ws;
  char* wend = (char*)d_ws + ws_size;
  auto alloc = [&](size_t bytes)->char*{ char* r=p; p += ((bytes+255)/256)*256; return r; };
  // fixed region
  int*   deg    = (int*)  alloc((size_t)N*4);
  int*   offs   = (int*)  alloc((size_t)(N+1)*4);
  int*   cursor = (int*)  alloc((size_t)N*4);
  int*   bsums  = (int*)  alloc((size_t)CDIV(N,1024)*4);
  int*   csr    = (int*)  alloc((size_t)ET*4);
  f16*   WtH[3], *WtL[3];
  for(int l=0;l<3;l++){ WtH[l]=(f16*)alloc(128*128*2); WtL[l]=(f16*)alloc(128*128*2); }
  f16 *WihH[2],*WihL[2],*WhhH[2],*WhhL[2];
  float* bsum2[2];
  for(int d2=0;d2<2;d2++){
    WihH[d2]=(f16*)alloc(768*128*2); WihL[d2]=(f16*)alloc(768*128*2);
    WhhH[d2]=(f16*)alloc(768*192*2); WhhL[d2]=(f16*)alloc(768*192*2);
    bsum2[d2]=(float*)alloc(768*4);
  }
  f16*   xs16   = (f16*)  alloc((size_t)3*Mpad*128*2);
  float* score  = (float*)alloc((size_t)N*3*4);
  float* pooled = (float*)alloc((size_t)(G*128+G)*4);
  float* counts = pooled + (size_t)G*128;
  char* P = p;   // phase-overlaid region start
  auto al256 = [](size_t b)->size_t{ return ((b+255)/256)*256; };
  // GAT phase overlay
  f16*   x016 = (f16*)P;
  float* htmp = (float*)(P + al256((size_t)Mpad*128*2));
  float* esb  = (float*)((char*)htmp + al256((size_t)Mpad*128*4));
  float* edb  = (float*)((char*)esb + al256((size_t)N*4*4));
  // LSTM phase overlay (reuses same region; GAT buffers dead by then)
  f16*   h16  = (f16*)P;
  float* cbuf = (float*)(P + al256((size_t)Mpad*192*2));
  float* zbuf = (float*)((char*)cbuf + al256((size_t)Mpad*192*4));
  long remain = (long)(wend - (char*)zbuf);
  long CH = remain / (768*4);
  CH &= ~127L;
  if (CH > Mpad) CH = Mpad;
  if (CH < 128)  CH = 128;   // ws too small would be fatal anyway

  const size_t xstride = (size_t)Mpad*128;

  // ---- 0. weight/input fp16 prep ----
  f2h_kernel<<<512,256,0,stream>>>(x, x016, (size_t)N*128);
  for(int l=0;l<3;l++) wtrans_kernel<<<128,128,0,stream>>>(W[l], WtH[l], WtL[l]);
  for(int d2=0;d2<2;d2++){
    f2h_split_kernel<<<256,256,0,stream>>>(Wih[d2], WihH[d2], WihL[d2], (size_t)768*128);
    f2h_split_kernel<<<256,256,0,stream>>>(Whh[d2], WhhH[d2], WhhL[d2], (size_t)768*192);
    bias2_kernel<<<3,256,0,stream>>>(bih[d2], bhh[d2], bsum2[d2], 768);
  }

  // ---- 1. CSR build ----
  zero_kernel<<<2048,256,0,stream>>>((float*)deg,(size_t)N);
  hist_kernel<<<CDIV(ET,256),256,0,stream>>>(ei,E,N,deg);
  int NB = CDIV(N,1024);
  scan1_kernel<<<NB,1024,0,stream>>>(deg,offs,bsums,N);
  scan2_kernel<<<1,64,0,stream>>>(bsums,offs,NB,N);
  scan3_kernel<<<CDIV(N,256),256,0,stream>>>(offs,bsums,cursor,N);
  scatter_kernel<<<CDIV(ET,256),256,0,stream>>>(ei,E,N,cursor,csr);

  // ---- 2. GAT layers (A single fp16, B split hi/lo; K'=2*128 -> 4 tiles) ----
  const f16* ain = x016;
  for (int l=0; l<3; l++){
    GemmDesc gd{};
    gd.nt=4; gd.M=N; gd.ldc=128; gd.bias=nullptr; gd.C=htmp;
    int ti=0;
    for (int s=0;s<2;s++)
      for (int q=0;q<2;q++){
        gd.a[ti]=ain+q*64;                      gd.lda[ti]=128;
        gd.b[ti]=(s? WtL[l]:WtH[l])+q*64;       gd.ldb[ti]=128;
        ti++;
      }
    gemm_mfma<<<dim3(1,CDIV(N,128)),256,0,stream>>>(gd);
    esed_kernel<<<N,128,0,stream>>>(htmp,AS[l],AD[l],esb,edb,N);
    attn_kernel<<<CDIV(N,4),256,0,stream>>>(htmp,esb,edb,offs,csr,BV[l],
                                            xs16+(size_t)l*xstride,N);
    ain = xs16+(size_t)l*xstride;
  }

  // ---- 3. bidirectional LSTM (K'=2*320 -> 10 tiles), scores on the fly ----
  for (int dir=0; dir<2; dir++){
    zero_kernel<<<2048,256,0,stream>>>((float*)h16,(size_t)Mpad*192/2);
    zero_kernel<<<2048,256,0,stream>>>(cbuf,(size_t)Mpad*192);
    for (int st=0; st<3; st++){
      int l_in = dir? (2-st) : st;
      const f16* xt = xs16 + (size_t)l_in*xstride;
      for (long c0=0; c0<N; c0+=CH){
        int Mr = (int)(((long)N-c0 < CH)? ((long)N-c0) : CH);
        GemmDesc gd{};
        gd.nt=10; gd.M=Mr; gd.ldc=768; gd.bias=bsum2[dir]; gd.C=zbuf;
        int ti=0;
        for (int s=0;s<2;s++)
          for (int q=0;q<5;q++){
            int kk=q*64;
            if (kk<128){
              gd.a[ti]=xt + c0*128 + kk;                       gd.lda[ti]=128;
              gd.b[ti]=(s? WihL[dir]:WihH[dir]) + kk;          gd.ldb[ti]=128;
            } else {
              gd.a[ti]=h16 + c0*192 + (kk-128);                gd.lda[ti]=192;
              gd.b[ti]=(s? WhhL[dir]:WhhH[dir]) + (kk-128);    gd.ldb[ti]=192;
            }
            ti++;
          }
        gemm_mfma<<<dim3(6,CDIV(Mr,128)),256,0,stream>>>(gd);
        int gb = (Mr<8192)? Mr : 8192;
        gates_kernel<<<gb,192,0,stream>>>(zbuf,h16,cbuf,Wa+dir*192,score,
                                          l_in,(dir==0)?1:0,(int)c0,Mr);
      }
    }
  }

  // ---- 4. JK attention + pooling + final linear ----
  zero_kernel<<<512,256,0,stream>>>(pooled,(size_t)(G*128+G));
  jk_pool_kernel<<<N,128,0,stream>>>(xs16,xstride,score,batch,pooled,counts,N);
  final_kernel<<<G,128,0,stream>>>(pooled,counts,Wl,bl,out,G);
}

// Round 3
// 1341.194 us; speedup vs baseline: 2.0876x; 1.2748x over previous
//
#include <hip/hip_runtime.h>
#include <math.h>

#define CDIV(a,b) (((a)+(b)-1)/(b))

typedef _Float16 f16;
typedef _Float16 f16x8 __attribute__((ext_vector_type(8)));
typedef float f32x4 __attribute__((ext_vector_type(4)));

__device__ __forceinline__ float sigf(float x){ return 1.0f/(1.0f+expf(-x)); }

// ---------------- utility ----------------
__global__ void zero_kernel(float* __restrict__ p, size_t n){
  size_t i=(size_t)blockIdx.x*blockDim.x+threadIdx.x;
  size_t st=(size_t)gridDim.x*blockDim.x;
  for(;i<n;i+=st) p[i]=0.0f;
}

// ---------------- fp16 conversion prep ----------------
__global__ void f2h_kernel(const float* __restrict__ s, f16* __restrict__ d, size_t n){
  size_t i=(size_t)blockIdx.x*blockDim.x+threadIdx.x;
  size_t st=(size_t)gridDim.x*blockDim.x;
  for(;i<n;i+=st) d[i]=(f16)s[i];
}
// W [128 in][128 out] -> Wt hi/lo [out][in]
__global__ void wtrans_kernel(const float* __restrict__ W, f16* __restrict__ hi,
                              f16* __restrict__ lo){
  int o=blockIdx.x, i=threadIdx.x;
  float f=W[(size_t)i*128+o];
  f16 h=(f16)f; hi[o*128+i]=h; lo[o*128+i]=(f16)(f-(float)h);
}
// LSTM weights: rows reordered gate-major -> interleaved row' = j*4+gate; split hi/lo
__global__ void lstm_wprep(const float* __restrict__ W, f16* __restrict__ hi,
                           f16* __restrict__ lo, int ld){
  int rn=blockIdx.x; int k=threadIdx.x;
  int j=rn>>2, gate=rn&3;
  float f=W[(size_t)(gate*192+j)*ld + k];
  f16 h=(f16)f;
  hi[(size_t)rn*ld+k]=h; lo[(size_t)rn*ld+k]=(f16)(f-(float)h);
}
__global__ void lstm_bprep(const float* __restrict__ bih, const float* __restrict__ bhh,
                           float* __restrict__ bI){
  int rn=blockIdx.x*blockDim.x+threadIdx.x;
  if(rn<768){ int j=rn>>2,g=rn&3; int go=g*192+j; bI[rn]=bih[go]+bhh[go]; }
}

// ---------------- CSR build ----------------
__global__ void hist_kernel(const int* __restrict__ ei, int E, int N, int* __restrict__ deg){
  int e=blockIdx.x*blockDim.x+threadIdx.x;
  if(e>=E+N) return;
  int d=(e<E)? ei[E+e] : (e-E);
  atomicAdd(&deg[d],1);
}
__global__ void scan1_kernel(const int* __restrict__ deg, int* __restrict__ offs,
                             int* __restrict__ bsums, int N){
  __shared__ int sd[1024];
  int t=threadIdx.x;
  int i=blockIdx.x*1024+t;
  int v=(i<N)?deg[i]:0;
  sd[t]=v;
  __syncthreads();
  for(int s=1;s<1024;s<<=1){
    int u=(t>=s)?sd[t-s]:0;
    __syncthreads();
    sd[t]+=u;
    __syncthreads();
  }
  if(i<N) offs[i]=sd[t]-v;
  if(t==1023) bsums[blockIdx.x]=sd[1023];
}
__global__ void scan2_kernel(int* __restrict__ bsums, int* __restrict__ offs, int NB, int N){
  if(threadIdx.x==0&&blockIdx.x==0){
    int run=0;
    for(int b=0;b<NB;b++){int s=bsums[b]; bsums[b]=run; run+=s;}
    offs[N]=run;
  }
}
__global__ void scan3_kernel(int* __restrict__ offs, const int* __restrict__ bsums,
                             int* __restrict__ cursor, int N){
  int i=blockIdx.x*blockDim.x+threadIdx.x;
  if(i<N){
    int o=offs[i]+bsums[i>>10];
    offs[i]=o;
    cursor[i]=o;
  }
}
__global__ void scatter_kernel(const int* __restrict__ ei, int E, int N,
                               int* __restrict__ cursor, int* __restrict__ csr){
  int e=blockIdx.x*blockDim.x+threadIdx.x;
  if(e>=E+N) return;
  int s,d;
  if(e<E){ s=ei[e]; d=ei[E+e]; } else { s=e-E; d=s; }
  int pos=atomicAdd(&cursor[d],1);
  csr[pos]=s;
}

// ---------------- MFMA GEMM (fp16 in), 128x128 tile, BK=64, fused epilogues --------
// MODE 0: GAT  — write htmp f16 + per-head es/ed dots (grid.x must be 1)
// MODE 1: LSTM — gate nonlinearities, cbuf/h16 update, JK score atomics
//               (weights pre-interleaved row' = j*4+gate)
struct GemmDesc {
  const f16* a[10]; const f16* b[10];
  int lda[10], ldb[10];
  int nt; int M;
  // MODE 0
  f16* htmp; const float* as_; const float* ad_; float* es; float* ed;
  // MODE 1
  f16* h16; float* cbuf; const float* bias; const float* wa; float* score;
  int l_out; int firstStep;
};

template<int MODE>
__global__ __launch_bounds__(256) void gemm_mfma(GemmDesc d){
  __shared__ __align__(16) char smraw[64*132*4];       // 33792 B: staging (32KB) / EP overlay
  f16* As = (f16*)smraw;
  f16* Bs = (f16*)(smraw + 128*64*2);
  float* EP = (float*)smraw;

  const int t = threadIdx.x;
  const int wv = t>>6, ln = t&63;
  const int m0 = blockIdx.y*128, n0 = blockIdx.x*128;
  const int wr = (wv>>1)*64, wc = (wv&1)*64;
  f32x4 acc[4][4];
#pragma unroll
  for(int i=0;i<4;i++)
#pragma unroll
  for(int j=0;j<4;j++) acc[i][j]=(f32x4){0.f,0.f,0.f,0.f};

  const int sR = ln>>3;        // row within 8-row group
  const int sC = (ln&7)*8;     // f16 col within 64

  for (int kt=0; kt<d.nt; kt++){
    const f16* aS = d.a[kt]; const int lda = d.lda[kt];
    const f16* bS = d.b[kt]; const int ldb = d.ldb[kt];
#pragma unroll
    for (int i=0;i<4;i++){
      int lrow = i*32 + wv*8;                 // wave-uniform base row
      int gr = m0 + lrow + sR; if (gr >= d.M) gr = d.M-1;
      const f16* ga = aS + (size_t)gr*lda + sC;
      __builtin_amdgcn_global_load_lds(
        (const __attribute__((address_space(1))) unsigned int*)ga,
        (__attribute__((address_space(3))) unsigned int*)&As[lrow*64], 16, 0, 0);
      const f16* gb = bS + (size_t)(n0 + lrow + sR)*ldb + sC;
      __builtin_amdgcn_global_load_lds(
        (const __attribute__((address_space(1))) unsigned int*)gb,
        (__attribute__((address_space(3))) unsigned int*)&Bs[lrow*64], 16, 0, 0);
    }
    __syncthreads();
#pragma unroll
    for (int kk=0; kk<2; kk++){
      f16x8 av[4], bv[4];
#pragma unroll
      for (int i=0;i<4;i++)
        av[i] = *(const f16x8*)&As[(wr + i*16 + (ln&15))*64 + kk*32 + (ln>>4)*8];
#pragma unroll
      for (int j=0;j<4;j++)
        bv[j] = *(const f16x8*)&Bs[(wc + j*16 + (ln&15))*64 + kk*32 + (ln>>4)*8];
#pragma unroll
      for (int i=0;i<4;i++)
#pragma unroll
      for (int j=0;j<4;j++)
        acc[i][j] = __builtin_amdgcn_mfma_f32_16x16x32_f16(av[i], bv[j], acc[i][j], 0,0,0);
    }
    __syncthreads();
  }

  // ---- fused epilogue: two 64-row phases staged through EP (aliases As/Bs) ----
  const int lc2 = ln&15, lr4 = (ln>>4)*4;
  const int row4 = t>>2, q4 = t&3;     // 64 rows x 4 col-quarters (32 cols each)
#pragma unroll
  for (int ph=0; ph<2; ph++){
    __syncthreads();
    if ((wv>>1) == ph){
#pragma unroll
      for (int i=0;i<4;i++){
#pragma unroll
        for (int jf=0;jf<4;jf++){
          int col = wc + jf*16 + lc2;
#pragma unroll
          for (int r=0;r<4;r++)
            EP[(i*16+lr4+r)*132 + col] = acc[i][jf][r];
        }
      }
    }
    __syncthreads();
    int grow = m0 + ph*64 + row4;
    if (grow < d.M){
      if (MODE==0){
        float s=0.f, dd=0.f;
        const float* asp = d.as_ + q4*32;
        const float* adp = d.ad_ + q4*32;
#pragma unroll
        for (int q8=0;q8<4;q8++){
          f16x8 pk;
#pragma unroll
          for (int r=0;r<8;r++){
            float v = EP[row4*132 + q4*32 + q8*8 + r];
            pk[r] = (f16)v;
            s  += v*asp[q8*8+r];
            dd += v*adp[q8*8+r];
          }
          *(f16x8*)&d.htmp[(size_t)grow*128 + q4*32 + q8*8] = pk;
        }
        d.es[grow*4+q4] = s;
        d.ed[grow*4+q4] = dd;
      } else {
        float sc = 0.f;
        int jg0 = (int)blockIdx.x*32 + q4*8;
        size_t hbase = (size_t)grow*192 + jg0;
        const float* bI = d.bias + (size_t)blockIdx.x*128 + q4*32;
        f16x8 hl;
#pragma unroll
        for (int j=0;j<8;j++){
          float4 z = *(float4*)&EP[row4*132 + q4*32 + j*4];
          float zi=z.x+bI[j*4+0], zf=z.y+bI[j*4+1], zg=z.z+bI[j*4+2], zo=z.w+bI[j*4+3];
          float cold = d.firstStep ? 0.f : d.cbuf[hbase+j];
          float c = sigf(zf)*cold + sigf(zi)*tanhf(zg);
          float h = sigf(zo)*tanhf(c);
          d.cbuf[hbase+j] = c;
          hl[j] = (f16)h;
          sc += h * d.wa[jg0+j];
        }
        *(f16x8*)&d.h16[hbase] = hl;
        sc += __shfl_xor(sc,1);
        sc += __shfl_xor(sc,2);
        if (q4==0) atomicAdd(&d.score[(size_t)grow*3 + d.l_out], sc);
      }
    }
  }
}

// ---------------- GAT attention: single pass, f16 gather ----------------
__global__ __launch_bounds__(256) void attn_kernel(const f16* __restrict__ htmp,
   const float* __restrict__ es, const float* __restrict__ ed,
   const int* __restrict__ offs, const int* __restrict__ csr,
   const float* __restrict__ bias, f16* __restrict__ xsl, int N){
  int v=blockIdx.x*4+(threadIdx.x>>6);
  if(v>=N) return;
  int lane=threadIdx.x&63;
  int hd=lane>>4;          // head for this lane's channels
  int c0=lane*2;
  int beg=offs[v], end=offs[v+1];
  float edv=ed[v*4+hd];
  float ssum=0.f,a0=0.f,a1=0.f;
  for(int i=beg;i<end;i++){
    int s=csr[i];
    float e=es[s*4+hd]+edv;
    e=(e>0.f)?e:0.2f*e;
    float ex=__expf(e);          // no max-shift needed: e is O(+-5), softmax invariant
    ssum+=ex;
    union {unsigned u; f16 h[2];} pk;
    pk.u = *reinterpret_cast<const unsigned*>(&htmp[(size_t)s*128+c0]);
    a0+=ex*(float)pk.h[0]; a1+=ex*(float)pk.h[1];
  }
  float inv=1.0f/(ssum+1e-16f);
  float o0=fmaxf(a0*inv+bias[c0],0.f), o1=fmaxf(a1*inv+bias[c0+1],0.f);
  union { f16 h[2]; unsigned u; } pko;
  pko.h[0]=(f16)o0; pko.h[1]=(f16)o1;
  *reinterpret_cast<unsigned*>(&xsl[(size_t)v*128+c0]) = pko.u;
}

// ---------------- JK softmax + weighted sum + pooling ----------------
__global__ __launch_bounds__(128) void jk_pool_kernel(const f16* __restrict__ xs, size_t xstride,
   const float* __restrict__ score, const int* __restrict__ batch,
   float* __restrict__ pooled, float* __restrict__ counts, int N){
  int n=blockIdx.x; int c=threadIdx.x;
  float s0=score[n*3],s1=score[n*3+1],s2=score[n*3+2];
  float m=fmaxf(s0,fmaxf(s1,s2));
  float e0=expf(s0-m),e1=expf(s1-m),e2=expf(s2-m);
  float inv=1.0f/(e0+e1+e2);
  size_t base=(size_t)n*128+c;
  float jk=((float)xs[base]*e0+(float)xs[xstride+base]*e1+(float)xs[2*xstride+base]*e2)*inv;
  int g=batch[n];
  atomicAdd(&pooled[(size_t)g*128+c],jk);
  if(c==0) atomicAdd(&counts[g],1.0f);
}

__global__ __launch_bounds__(128) void final_kernel(const float* __restrict__ pooled,
   const float* __restrict__ counts, const float* __restrict__ Wl,
   const float* __restrict__ bl, float* __restrict__ out, int G){
  int g=blockIdx.x; int c=threadIdx.x;
  float cnt=fmaxf(counts[g],1.0f);
  float pv=pooled[(size_t)g*128+c]/cnt;
  float p0=pv*Wl[c*2], p1=pv*Wl[c*2+1];
  for(int s=32;s>=1;s>>=1){ p0+=__shfl_down(p0,s); p1+=__shfl_down(p1,s); }
  __shared__ float sm[4];
  int w=c>>6;
  if((c&63)==0){ sm[w*2]=p0; sm[w*2+1]=p1; }
  __syncthreads();
  if(c==0){
    out[g*2+0]=sm[0]+sm[2]+bl[0];
    out[g*2+1]=sm[1]+sm[3]+bl[1];
  }
}

// ---------------- launch ----------------
extern "C" void kernel_launch(void* const* d_in, const int* in_sizes, int n_in,
                              void* d_out, int out_size, void* d_ws, size_t ws_size,
                              hipStream_t stream) {
  const float* x     = (const float*)d_in[0];
  const int*   ei    = (const int*)d_in[1];
  const int*   batch = (const int*)d_in[2];
  const float* W[3]  = {(const float*)d_in[3],(const float*)d_in[7],(const float*)d_in[11]};
  const float* AS[3] = {(const float*)d_in[4],(const float*)d_in[8],(const float*)d_in[12]};
  const float* AD[3] = {(const float*)d_in[5],(const float*)d_in[9],(const float*)d_in[13]};
  const float* BV[3] = {(const float*)d_in[6],(const float*)d_in[10],(const float*)d_in[14]};
  const float* Wih[2]= {(const float*)d_in[15],(const float*)d_in[19]};
  const float* Whh[2]= {(const float*)d_in[16],(const float*)d_in[20]};
  const float* bih[2]= {(const float*)d_in[17],(const float*)d_in[21]};
  const float* bhh[2]= {(const float*)d_in[18],(const float*)d_in[22]};
  const float* Wa    = (const float*)d_in[23];
  const float* Wl    = (const float*)d_in[25];
  const float* bl    = (const float*)d_in[26];
  float* out = (float*)d_out;

  const int N  = in_sizes[2];
  const int E  = in_sizes[1]/2;
  const int ET = E+N;
  const int G  = out_size/2;
  const int Mpad = CDIV(N,128)*128;
  const int GY = CDIV(N,128);

  // ---- workspace carve (256B aligned) ----
  char* p = (char*)d_ws;
  auto alloc = [&](size_t bytes)->char*{ char* r=p; p += ((bytes+255)/256)*256; return r; };
  // fixed region
  int*   deg    = (int*)  alloc((size_t)N*4);
  int*   offs   = (int*)  alloc((size_t)(N+1)*4);
  int*   cursor = (int*)  alloc((size_t)N*4);
  int*   bsums  = (int*)  alloc((size_t)CDIV(N,1024)*4);
  int*   csr    = (int*)  alloc((size_t)ET*4);
  f16*   WtH[3], *WtL[3];
  for(int l=0;l<3;l++){ WtH[l]=(f16*)alloc(128*128*2); WtL[l]=(f16*)alloc(128*128*2); }
  f16 *WihH[2],*WihL[2],*WhhH[2],*WhhL[2];
  float* bsumI[2];
  for(int d2=0;d2<2;d2++){
    WihH[d2]=(f16*)alloc(768*128*2); WihL[d2]=(f16*)alloc(768*128*2);
    WhhH[d2]=(f16*)alloc(768*192*2); WhhL[d2]=(f16*)alloc(768*192*2);
    bsumI[d2]=(float*)alloc(768*4);
  }
  f16*   xs16   = (f16*)  alloc((size_t)3*Mpad*128*2);
  float* score  = (float*)alloc((size_t)N*3*4);
  float* pooled = (float*)alloc((size_t)(G*128+G)*4);
  float* counts = pooled + (size_t)G*128;
  char* P = p;   // phase-overlaid region
  auto al256 = [](size_t b)->size_t{ return ((b+255)/256)*256; };
  // GAT phase overlay
  f16*   x016 = (f16*)P;
  f16*   htmp = (f16*)(P + al256((size_t)Mpad*128*2));
  float* esb  = (float*)((char*)htmp + al256((size_t)Mpad*128*2));
  float* edb  = (float*)((char*)esb + al256((size_t)N*4*4));
  // LSTM phase overlay (GAT buffers dead by then)
  f16*   h16  = (f16*)P;
  float* cbuf = (float*)(P + al256((size_t)Mpad*192*2));

  const size_t xstride = (size_t)Mpad*128;

  // ---- 0. weight/input prep ----
  f2h_kernel<<<512,256,0,stream>>>(x, x016, (size_t)N*128);
  for(int l=0;l<3;l++) wtrans_kernel<<<128,128,0,stream>>>(W[l], WtH[l], WtL[l]);
  for(int d2=0;d2<2;d2++){
    lstm_wprep<<<768,128,0,stream>>>(Wih[d2], WihH[d2], WihL[d2], 128);
    lstm_wprep<<<768,192,0,stream>>>(Whh[d2], WhhH[d2], WhhL[d2], 192);
    lstm_bprep<<<3,256,0,stream>>>(bih[d2], bhh[d2], bsumI[d2]);
  }
  zero_kernel<<<64,256,0,stream>>>(score,(size_t)N*3);
  zero_kernel<<<512,256,0,stream>>>(pooled,(size_t)(G*128+G));

  // ---- 1. CSR build ----
  zero_kernel<<<64,256,0,stream>>>((float*)deg,(size_t)N);
  hist_kernel<<<CDIV(ET,256),256,0,stream>>>(ei,E,N,deg);
  int NB = CDIV(N,1024);
  scan1_kernel<<<NB,1024,0,stream>>>(deg,offs,bsums,N);
  scan2_kernel<<<1,64,0,stream>>>(bsums,offs,NB,N);
  scan3_kernel<<<CDIV(N,256),256,0,stream>>>(offs,bsums,cursor,N);
  scatter_kernel<<<CDIV(ET,256),256,0,stream>>>(ei,E,N,cursor,csr);

  // ---- 2. GAT layers (A fp16, B hi/lo; fused htmp/es/ed epilogue) ----
  const f16* ain = x016;
  for (int l=0; l<3; l++){
    GemmDesc gd{};
    gd.nt=4; gd.M=N;
    gd.htmp=htmp; gd.as_=AS[l]; gd.ad_=AD[l]; gd.es=esb; gd.ed=edb;
    int ti=0;
    for (int s=0;s<2;s++)
      for (int q=0;q<2;q++){
        gd.a[ti]=ain+q*64;                      gd.lda[ti]=128;
        gd.b[ti]=(s? WtL[l]:WtH[l])+q*64;       gd.ldb[ti]=128;
        ti++;
      }
    gemm_mfma<0><<<dim3(1,GY),256,0,stream>>>(gd);
    attn_kernel<<<CDIV(N,4),256,0,stream>>>(htmp,esb,edb,offs,csr,BV[l],
                                            xs16+(size_t)l*xstride,N);
    ain = xs16+(size_t)l*xstride;
  }

  // ---- 3. bidirectional LSTM, gates + scores fused into GEMM epilogue ----
  for (int dir=0; dir<2; dir++){
    for (int st=0; st<3; st++){
      int l_in = dir? (2-st) : st;
      const f16* xt = xs16 + (size_t)l_in*xstride;
      GemmDesc gd{};
      gd.M=N;
      gd.h16=h16; gd.cbuf=cbuf; gd.bias=bsumI[dir]; gd.wa=Wa+dir*192;
      gd.score=score; gd.l_out=l_in; gd.firstStep=(st==0);
      int ti=0;
      for (int s=0;s<2;s++){
        for (int q=0;q<2;q++){
          gd.a[ti]=xt + q*64;                          gd.lda[ti]=128;
          gd.b[ti]=(s? WihL[dir]:WihH[dir]) + q*64;    gd.ldb[ti]=128;
          ti++;
        }
        if (st>0){
          for (int q=0;q<3;q++){
            gd.a[ti]=h16 + q*64;                       gd.lda[ti]=192;
            gd.b[ti]=(s? WhhL[dir]:WhhH[dir]) + q*64;  gd.ldb[ti]=192;
            ti++;
          }
        }
      }
      gd.nt=ti;   // 4 on first step, 10 otherwise
      gemm_mfma<1><<<dim3(6,GY),256,0,stream>>>(gd);
    }
  }

  // ---- 4. JK attention + pooling + final linear ----
  jk_pool_kernel<<<N,128,0,stream>>>(xs16,xstride,score,batch,pooled,counts,N);
  final_kernel<<<G,128,0,stream>>>(pooled,counts,Wl,bl,out,G);
}

// Round 4
// 1224.855 us; speedup vs baseline: 2.2859x; 1.0950x over previous
//
#include <hip/hip_runtime.h>
#include <math.h>

#define CDIV(a,b) (((a)+(b)-1)/(b))

typedef _Float16 f16;
typedef _Float16 f16x8 __attribute__((ext_vector_type(8)));
typedef float f32x4 __attribute__((ext_vector_type(4)));

__device__ __forceinline__ float sigf(float x){ return 1.0f/(1.0f+expf(-x)); }

// ---------------- utility ----------------
__global__ void zero_kernel(float* __restrict__ p, size_t n){
  size_t i=(size_t)blockIdx.x*blockDim.x+threadIdx.x;
  size_t st=(size_t)gridDim.x*blockDim.x;
  for(;i<n;i+=st) p[i]=0.0f;
}

// ---------------- fp16 conversion prep ----------------
__global__ void f2h_kernel(const float* __restrict__ s, f16* __restrict__ d, size_t n){
  size_t i=(size_t)blockIdx.x*blockDim.x+threadIdx.x;
  size_t st=(size_t)gridDim.x*blockDim.x;
  for(;i<n;i+=st) d[i]=(f16)s[i];
}
// W [128 in][128 out] -> Wt hi/lo [out][in]
__global__ void wtrans_kernel(const float* __restrict__ W, f16* __restrict__ hi,
                              f16* __restrict__ lo){
  int o=blockIdx.x, i=threadIdx.x;
  float f=W[(size_t)i*128+o];
  f16 h=(f16)f; hi[o*128+i]=h; lo[o*128+i]=(f16)(f-(float)h);
}
// LSTM weights: rows reordered gate-major -> interleaved row' = j*4+gate; split hi/lo
__global__ void lstm_wprep(const float* __restrict__ W, f16* __restrict__ hi,
                           f16* __restrict__ lo, int ld){
  int rn=blockIdx.x; int k=threadIdx.x;
  int j=rn>>2, gate=rn&3;
  float f=W[(size_t)(gate*192+j)*ld + k];
  f16 h=(f16)f;
  hi[(size_t)rn*ld+k]=h; lo[(size_t)rn*ld+k]=(f16)(f-(float)h);
}
__global__ void lstm_bprep(const float* __restrict__ bih, const float* __restrict__ bhh,
                           float* __restrict__ bI){
  int rn=blockIdx.x*blockDim.x+threadIdx.x;
  if(rn<768){ int j=rn>>2,g=rn&3; int go=g*192+j; bI[rn]=bih[go]+bhh[go]; }
}

// ---------------- CSR build ----------------
__global__ void hist_kernel(const int* __restrict__ ei, int E, int N, int* __restrict__ deg){
  int e=blockIdx.x*blockDim.x+threadIdx.x;
  if(e>=E+N) return;
  int d=(e<E)? ei[E+e] : (e-E);
  atomicAdd(&deg[d],1);
}
__global__ void scan1_kernel(const int* __restrict__ deg, int* __restrict__ offs,
                             int* __restrict__ bsums, int N){
  __shared__ int sd[1024];
  int t=threadIdx.x;
  int i=blockIdx.x*1024+t;
  int v=(i<N)?deg[i]:0;
  sd[t]=v;
  __syncthreads();
  for(int s=1;s<1024;s<<=1){
    int u=(t>=s)?sd[t-s]:0;
    __syncthreads();
    sd[t]+=u;
    __syncthreads();
  }
  if(i<N) offs[i]=sd[t]-v;
  if(t==1023) bsums[blockIdx.x]=sd[1023];
}
__global__ void scan2_kernel(int* __restrict__ bsums, int* __restrict__ offs, int NB, int N){
  if(threadIdx.x==0&&blockIdx.x==0){
    int run=0;
    for(int b=0;b<NB;b++){int s=bsums[b]; bsums[b]=run; run+=s;}
    offs[N]=run;
  }
}
__global__ void scan3_kernel(int* __restrict__ offs, const int* __restrict__ bsums,
                             int* __restrict__ cursor, int N){
  int i=blockIdx.x*blockDim.x+threadIdx.x;
  if(i<N){
    int o=offs[i]+bsums[i>>10];
    offs[i]=o;
    cursor[i]=o;
  }
}
__global__ void scatter_kernel(const int* __restrict__ ei, int E, int N,
                               int* __restrict__ cursor, int* __restrict__ csr){
  int e=blockIdx.x*blockDim.x+threadIdx.x;
  if(e>=E+N) return;
  int s,d;
  if(e<E){ s=ei[e]; d=ei[E+e]; } else { s=e-E; d=s; }
  int pos=atomicAdd(&cursor[d],1);
  csr[pos]=s;
}

// ---------------- MFMA GEMM (fp16 in), 128x128 tile, BK=64, fused epilogues --------
// MODE 0: GAT  — write htmp f16 + per-head es/ed dots (NXB must be 1)
// MODE 1: LSTM — gate nonlinearities, cbuf/h16 update, JK score atomics
// 1-D grid with bijective XCD remap (same row-panel's N-blocks share one XCD L2).
// LDS tiles are XOR-swizzled (T2): linear global_load_lds dest, pre-swizzled global
// source column, matching XOR on ds_read.
struct GemmDesc {
  const f16* a[10]; const f16* b[10];
  int lda[10], ldb[10];
  int nt; int M; int GY; int NXB;
  // MODE 0
  f16* htmp; const float* as_; const float* ad_; float* es; float* ed;
  // MODE 1
  f16* h16; float* cbuf; const float* bias; const float* wa; float* score;
  int l_out; int firstStep;
};

template<int MODE>
__global__ __launch_bounds__(256) void gemm_mfma(GemmDesc d){
  __shared__ __align__(16) char smraw[64*132*4];       // 33792 B: staging (32KB) / EP overlay
  f16* As = (f16*)smraw;
  f16* Bs = (f16*)(smraw + 128*64*2);
  float* EP = (float*)smraw;

  // XCD-aware remap: consecutive wg ids round-robin XCDs; give each XCD whole panels
  const int wg = blockIdx.x;
  const int xcd = wg & 7, kk0 = wg >> 3;
  const int xb = kk0 % d.NXB;
  const int yp = xcd + 8*(kk0 / d.NXB);
  if (yp >= d.GY) return;

  const int t = threadIdx.x;
  const int wv = t>>6, ln = t&63;
  const int m0 = yp*128, n0 = xb*128;
  const int wr = (wv>>1)*64, wc = (wv&1)*64;
  f32x4 acc[4][4];
#pragma unroll
  for(int i=0;i<4;i++)
#pragma unroll
  for(int j=0;j<4;j++) acc[i][j]=(f32x4){0.f,0.f,0.f,0.f};

  const int sR = ln>>3;                    // row within 8-row group
  const int sC = ((ln&7)*8) ^ (sR<<3);     // SWIZZLED source col (f16 elems)

  for (int kt=0; kt<d.nt; kt++){
    const f16* aS = d.a[kt]; const int lda = d.lda[kt];
    const f16* bS = d.b[kt]; const int ldb = d.ldb[kt];
#pragma unroll
    for (int i=0;i<4;i++){
      int lrow = i*32 + wv*8;                 // wave-uniform base row
      int gr = m0 + lrow + sR; if (gr >= d.M) gr = d.M-1;
      const f16* ga = aS + (size_t)gr*lda + sC;
      __builtin_amdgcn_global_load_lds(
        (const __attribute__((address_space(1))) unsigned int*)ga,
        (__attribute__((address_space(3))) unsigned int*)&As[lrow*64], 16, 0, 0);
      const f16* gb = bS + (size_t)(n0 + lrow + sR)*ldb + sC;
      __builtin_amdgcn_global_load_lds(
        (const __attribute__((address_space(1))) unsigned int*)gb,
        (__attribute__((address_space(3))) unsigned int*)&Bs[lrow*64], 16, 0, 0);
    }
    __syncthreads();
    const int swz = (ln&7)<<3;               // read-side XOR (row&7 == ln&7 here)
#pragma unroll
    for (int kk=0; kk<2; kk++){
      f16x8 av[4], bv[4];
#pragma unroll
      for (int i=0;i<4;i++)
        av[i] = *(const f16x8*)&As[(wr + i*16 + (ln&15))*64 + ((kk*32 + (ln>>4)*8) ^ swz)];
#pragma unroll
      for (int j=0;j<4;j++)
        bv[j] = *(const f16x8*)&Bs[(wc + j*16 + (ln&15))*64 + ((kk*32 + (ln>>4)*8) ^ swz)];
#pragma unroll
      for (int i=0;i<4;i++)
#pragma unroll
      for (int j=0;j<4;j++)
        acc[i][j] = __builtin_amdgcn_mfma_f32_16x16x32_f16(av[i], bv[j], acc[i][j], 0,0,0);
    }
    __syncthreads();
  }

  // ---- fused epilogue: two 64-row phases staged through EP (aliases As/Bs) ----
  const int lc2 = ln&15, lr4 = (ln>>4)*4;
  const int row4 = t>>2, q4 = t&3;     // 64 rows x 4 col-quarters (32 cols each)
#pragma unroll
  for (int ph=0; ph<2; ph++){
    __syncthreads();
    if ((wv>>1) == ph){
#pragma unroll
      for (int i=0;i<4;i++){
#pragma unroll
        for (int jf=0;jf<4;jf++){
          int col = wc + jf*16 + lc2;
#pragma unroll
          for (int r=0;r<4;r++)
            EP[(i*16+lr4+r)*132 + col] = acc[i][jf][r];
        }
      }
    }
    __syncthreads();
    int grow = m0 + ph*64 + row4;
    if (grow < d.M){
      if (MODE==0){
        float s=0.f, dd=0.f;
        const float* asp = d.as_ + q4*32;
        const float* adp = d.ad_ + q4*32;
#pragma unroll
        for (int q8=0;q8<4;q8++){
          f16x8 pk;
#pragma unroll
          for (int r=0;r<8;r++){
            float v = EP[row4*132 + q4*32 + q8*8 + r];
            pk[r] = (f16)v;
            s  += v*asp[q8*8+r];
            dd += v*adp[q8*8+r];
          }
          *(f16x8*)&d.htmp[(size_t)grow*128 + q4*32 + q8*8] = pk;
        }
        d.es[grow*4+q4] = s;
        d.ed[grow*4+q4] = dd;
      } else {
        float sc = 0.f;
        int jg0 = xb*32 + q4*8;
        size_t hbase = (size_t)grow*192 + jg0;
        const float* bI = d.bias + (size_t)xb*128 + q4*32;
        f16x8 hl;
#pragma unroll
        for (int j=0;j<8;j++){
          float4 z = *(float4*)&EP[row4*132 + q4*32 + j*4];
          float zi=z.x+bI[j*4+0], zf=z.y+bI[j*4+1], zg=z.z+bI[j*4+2], zo=z.w+bI[j*4+3];
          float cold = d.firstStep ? 0.f : d.cbuf[hbase+j];
          float c = sigf(zf)*cold + sigf(zi)*tanhf(zg);
          float h = sigf(zo)*tanhf(c);
          d.cbuf[hbase+j] = c;
          hl[j] = (f16)h;
          sc += h * d.wa[jg0+j];
        }
        *(f16x8*)&d.h16[hbase] = hl;
        sc += __shfl_xor(sc,1);
        sc += __shfl_xor(sc,2);
        if (q4==0) atomicAdd(&d.score[(size_t)grow*3 + d.l_out], sc);
      }
    }
  }
}

// ---------------- GAT attention: single pass, f16 gather ----------------
__global__ __launch_bounds__(256) void attn_kernel(const f16* __restrict__ htmp,
   const float* __restrict__ es, const float* __restrict__ ed,
   const int* __restrict__ offs, const int* __restrict__ csr,
   const float* __restrict__ bias, f16* __restrict__ xsl, int N){
  int v=blockIdx.x*4+(threadIdx.x>>6);
  if(v>=N) return;
  int lane=threadIdx.x&63;
  int hd=lane>>4;          // head for this lane's channels
  int c0=lane*2;
  int beg=offs[v], end=offs[v+1];
  float edv=ed[v*4+hd];
  float ssum=0.f,a0=0.f,a1=0.f;
  for(int i=beg;i<end;i++){
    int s=csr[i];
    float e=es[s*4+hd]+edv;
    e=(e>0.f)?e:0.2f*e;
    float ex=__expf(e);          // no max-shift needed: e is O(+-5), softmax invariant
    ssum+=ex;
    union {unsigned u; f16 h[2];} pk;
    pk.u = *reinterpret_cast<const unsigned*>(&htmp[(size_t)s*128+c0]);
    a0+=ex*(float)pk.h[0]; a1+=ex*(float)pk.h[1];
  }
  float inv=1.0f/(ssum+1e-16f);
  float o0=fmaxf(a0*inv+bias[c0],0.f), o1=fmaxf(a1*inv+bias[c0+1],0.f);
  union { f16 h[2]; unsigned u; } pko;
  pko.h[0]=(f16)o0; pko.h[1]=(f16)o1;
  *reinterpret_cast<unsigned*>(&xsl[(size_t)v*128+c0]) = pko.u;
}

// ---------------- JK softmax + weighted sum + pooling ----------------
__global__ __launch_bounds__(128) void jk_pool_kernel(const f16* __restrict__ xs, size_t xstride,
   const float* __restrict__ score, const int* __restrict__ batch,
   float* __restrict__ pooled, float* __restrict__ counts, int N){
  int n=blockIdx.x; int c=threadIdx.x;
  float s0=score[n*3],s1=score[n*3+1],s2=score[n*3+2];
  float m=fmaxf(s0,fmaxf(s1,s2));
  float e0=expf(s0-m),e1=expf(s1-m),e2=expf(s2-m);
  float inv=1.0f/(e0+e1+e2);
  size_t base=(size_t)n*128+c;
  float jk=((float)xs[base]*e0+(float)xs[xstride+base]*e1+(float)xs[2*xstride+base]*e2)*inv;
  int g=batch[n];
  atomicAdd(&pooled[(size_t)g*128+c],jk);
  if(c==0) atomicAdd(&counts[g],1.0f);
}

__global__ __launch_bounds__(128) void final_kernel(const float* __restrict__ pooled,
   const float* __restrict__ counts, const float* __restrict__ Wl,
   const float* __restrict__ bl, float* __restrict__ out, int G){
  int g=blockIdx.x; int c=threadIdx.x;
  float cnt=fmaxf(counts[g],1.0f);
  float pv=pooled[(size_t)g*128+c]/cnt;
  float p0=pv*Wl[c*2], p1=pv*Wl[c*2+1];
  for(int s=32;s>=1;s>>=1){ p0+=__shfl_down(p0,s); p1+=__shfl_down(p1,s); }
  __shared__ float sm[4];
  int w=c>>6;
  if((c&63)==0){ sm[w*2]=p0; sm[w*2+1]=p1; }
  __syncthreads();
  if(c==0){
    out[g*2+0]=sm[0]+sm[2]+bl[0];
    out[g*2+1]=sm[1]+sm[3]+bl[1];
  }
}

// ---------------- launch ----------------
extern "C" void kernel_launch(void* const* d_in, const int* in_sizes, int n_in,
                              void* d_out, int out_size, void* d_ws, size_t ws_size,
                              hipStream_t stream) {
  const float* x     = (const float*)d_in[0];
  const int*   ei    = (const int*)d_in[1];
  const int*   batch = (const int*)d_in[2];
  const float* W[3]  = {(const float*)d_in[3],(const float*)d_in[7],(const float*)d_in[11]};
  const float* AS[3] = {(const float*)d_in[4],(const float*)d_in[8],(const float*)d_in[12]};
  const float* AD[3] = {(const float*)d_in[5],(const float*)d_in[9],(const float*)d_in[13]};
  const float* BV[3] = {(const float*)d_in[6],(const float*)d_in[10],(const float*)d_in[14]};
  const float* Wih[2]= {(const float*)d_in[15],(const float*)d_in[19]};
  const float* Whh[2]= {(const float*)d_in[16],(const float*)d_in[20]};
  const float* bih[2]= {(const float*)d_in[17],(const float*)d_in[21]};
  const float* bhh[2]= {(const float*)d_in[18],(const float*)d_in[22]};
  const float* Wa    = (const float*)d_in[23];
  const float* Wl    = (const float*)d_in[25];
  const float* bl    = (const float*)d_in[26];
  float* out = (float*)d_out;

  const int N  = in_sizes[2];
  const int E  = in_sizes[1]/2;
  const int ET = E+N;
  const int G  = out_size/2;
  const int Mpad = CDIV(N,128)*128;
  const int GY = CDIV(N,128);
  const int GYp = CDIV(GY,8)*8;

  // ---- workspace carve (256B aligned) ----
  char* p = (char*)d_ws;
  auto alloc = [&](size_t bytes)->char*{ char* r=p; p += ((bytes+255)/256)*256; return r; };
  // fixed region
  int*   deg    = (int*)  alloc((size_t)N*4);
  int*   offs   = (int*)  alloc((size_t)(N+1)*4);
  int*   cursor = (int*)  alloc((size_t)N*4);
  int*   bsums  = (int*)  alloc((size_t)CDIV(N,1024)*4);
  int*   csr    = (int*)  alloc((size_t)ET*4);
  f16*   WtH[3], *WtL[3];
  for(int l=0;l<3;l++){ WtH[l]=(f16*)alloc(128*128*2); WtL[l]=(f16*)alloc(128*128*2); }
  f16 *WihH[2],*WihL[2],*WhhH[2],*WhhL[2];
  float* bsumI[2];
  for(int d2=0;d2<2;d2++){
    WihH[d2]=(f16*)alloc(768*128*2); WihL[d2]=(f16*)alloc(768*128*2);
    WhhH[d2]=(f16*)alloc(768*192*2); WhhL[d2]=(f16*)alloc(768*192*2);
    bsumI[d2]=(float*)alloc(768*4);
  }
  f16*   xs16   = (f16*)  alloc((size_t)3*Mpad*128*2);
  float* score  = (float*)alloc((size_t)N*3*4);
  float* pooled = (float*)alloc((size_t)(G*128+G)*4);
  float* counts = pooled + (size_t)G*128;
  char* P = p;   // phase-overlaid region
  auto al256 = [](size_t b)->size_t{ return ((b+255)/256)*256; };
  // GAT phase overlay
  f16*   x016 = (f16*)P;
  f16*   htmp = (f16*)(P + al256((size_t)Mpad*128*2));
  float* esb  = (float*)((char*)htmp + al256((size_t)Mpad*128*2));
  float* edb  = (float*)((char*)esb + al256((size_t)N*4*4));
  // LSTM phase overlay (GAT buffers dead by then)
  f16*   h16  = (f16*)P;
  float* cbuf = (float*)(P + al256((size_t)Mpad*192*2));

  const size_t xstride = (size_t)Mpad*128;

  // ---- 0. weight/input prep ----
  f2h_kernel<<<512,256,0,stream>>>(x, x016, (size_t)N*128);
  for(int l=0;l<3;l++) wtrans_kernel<<<128,128,0,stream>>>(W[l], WtH[l], WtL[l]);
  for(int d2=0;d2<2;d2++){
    lstm_wprep<<<768,128,0,stream>>>(Wih[d2], WihH[d2], WihL[d2], 128);
    lstm_wprep<<<768,192,0,stream>>>(Whh[d2], WhhH[d2], WhhL[d2], 192);
    lstm_bprep<<<3,256,0,stream>>>(bih[d2], bhh[d2], bsumI[d2]);
  }
  zero_kernel<<<64,256,0,stream>>>(score,(size_t)N*3);
  zero_kernel<<<512,256,0,stream>>>(pooled,(size_t)(G*128+G));

  // ---- 1. CSR build ----
  zero_kernel<<<64,256,0,stream>>>((float*)deg,(size_t)N);
  hist_kernel<<<CDIV(ET,256),256,0,stream>>>(ei,E,N,deg);
  int NB = CDIV(N,1024);
  scan1_kernel<<<NB,1024,0,stream>>>(deg,offs,bsums,N);
  scan2_kernel<<<1,64,0,stream>>>(bsums,offs,NB,N);
  scan3_kernel<<<CDIV(N,256),256,0,stream>>>(offs,bsums,cursor,N);
  scatter_kernel<<<CDIV(ET,256),256,0,stream>>>(ei,E,N,cursor,csr);

  // ---- 2. GAT layers (A fp16, B hi/lo; fused htmp/es/ed epilogue) ----
  const f16* ain = x016;
  for (int l=0; l<3; l++){
    GemmDesc gd{};
    gd.nt=4; gd.M=N; gd.GY=GY; gd.NXB=1;
    gd.htmp=htmp; gd.as_=AS[l]; gd.ad_=AD[l]; gd.es=esb; gd.ed=edb;
    int ti=0;
    for (int q=0;q<2;q++)
      for (int s=0;s<2;s++){
        gd.a[ti]=ain+q*64;                      gd.lda[ti]=128;
        gd.b[ti]=(s? WtL[l]:WtH[l])+q*64;       gd.ldb[ti]=128;
        ti++;
      }
    gemm_mfma<0><<<GYp,256,0,stream>>>(gd);
    attn_kernel<<<CDIV(N,4),256,0,stream>>>(htmp,esb,edb,offs,csr,BV[l],
                                            xs16+(size_t)l*xstride,N);
    ain = xs16+(size_t)l*xstride;
  }

  // ---- 3. bidirectional LSTM, gates + scores fused into GEMM epilogue ----
  for (int dir=0; dir<2; dir++){
    for (int st=0; st<3; st++){
      int l_in = dir? (2-st) : st;
      const f16* xt = xs16 + (size_t)l_in*xstride;
      GemmDesc gd{};
      gd.M=N; gd.GY=GY; gd.NXB=6;
      gd.h16=h16; gd.cbuf=cbuf; gd.bias=bsumI[dir]; gd.wa=Wa+dir*192;
      gd.score=score; gd.l_out=l_in; gd.firstStep=(st==0);
      int ti=0;
      // q-outer, s-inner: hi/lo passes of the same A tile are adjacent (L2 hit)
      for (int q=0;q<2;q++)
        for (int s=0;s<2;s++){
          gd.a[ti]=xt + q*64;                          gd.lda[ti]=128;
          gd.b[ti]=(s? WihL[dir]:WihH[dir]) + q*64;    gd.ldb[ti]=128;
          ti++;
        }
      if (st>0){
        for (int q=0;q<3;q++)
          for (int s=0;s<2;s++){
            gd.a[ti]=h16 + q*64;                       gd.lda[ti]=192;
            gd.b[ti]=(s? WhhL[dir]:WhhH[dir]) + q*64;  gd.ldb[ti]=192;
            ti++;
          }
      }
      gd.nt=ti;   // 4 on first step, 10 otherwise
      gemm_mfma<1><<<6*GYp,256,0,stream>>>(gd);
    }
  }

  // ---- 4. JK attention + pooling + final linear ----
  jk_pool_kernel<<<N,128,0,stream>>>(xs16,xstride,score,batch,pooled,counts,N);
  final_kernel<<<G,128,0,stream>>>(pooled,counts,Wl,bl,out,G);
}

// Round 5
// 1123.603 us; speedup vs baseline: 2.4919x; 1.0901x over previous
//
#include <hip/hip_runtime.h>
#include <math.h>

#define CDIV(a,b) (((a)+(b)-1)/(b))

typedef _Float16 f16;
typedef _Float16 f16x8 __attribute__((ext_vector_type(8)));
typedef float f32x4 __attribute__((ext_vector_type(4)));

__device__ __forceinline__ float rcpf(float x){ return __builtin_amdgcn_rcpf(x); }
__device__ __forceinline__ float fsig(float x){ return rcpf(1.0f+__expf(-x)); }
__device__ __forceinline__ float ftanh(float x){ float e=__expf(2.0f*x); return 1.0f-2.0f*rcpf(e+1.0f); }

// ---------------- utility ----------------
__global__ void zero_kernel(float* __restrict__ p, size_t n){
  size_t i=(size_t)blockIdx.x*blockDim.x+threadIdx.x;
  size_t st=(size_t)gridDim.x*blockDim.x;
  for(;i<n;i+=st) p[i]=0.0f;
}

// ---------------- fp16 conversion prep ----------------
__global__ void f2h_kernel(const float* __restrict__ s, f16* __restrict__ d, size_t n){
  size_t i=(size_t)blockIdx.x*blockDim.x+threadIdx.x;
  size_t st=(size_t)gridDim.x*blockDim.x;
  for(;i<n;i+=st) d[i]=(f16)s[i];
}
// W [128 in][128 out] -> Wt hi/lo [out][in]
__global__ void wtrans_kernel(const float* __restrict__ W, f16* __restrict__ hi,
                              f16* __restrict__ lo){
  int o=blockIdx.x, i=threadIdx.x;
  float f=W[(size_t)i*128+o];
  f16 h=(f16)f; hi[o*128+i]=h; lo[o*128+i]=(f16)(f-(float)h);
}
// LSTM weights: rows reordered gate-major -> interleaved row' = j*4+gate; split hi/lo
__global__ void lstm_wprep(const float* __restrict__ W, f16* __restrict__ hi,
                           f16* __restrict__ lo, int ld){
  int rn=blockIdx.x; int k=threadIdx.x;
  int j=rn>>2, gate=rn&3;
  float f=W[(size_t)(gate*192+j)*ld + k];
  f16 h=(f16)f;
  hi[(size_t)rn*ld+k]=h; lo[(size_t)rn*ld+k]=(f16)(f-(float)h);
}
__global__ void lstm_bprep(const float* __restrict__ bih, const float* __restrict__ bhh,
                           float* __restrict__ bI){
  int rn=blockIdx.x*blockDim.x+threadIdx.x;
  if(rn<768){ int j=rn>>2,g=rn&3; int go=g*192+j; bI[rn]=bih[go]+bhh[go]; }
}

// ---------------- CSR build ----------------
__global__ void hist_kernel(const int* __restrict__ ei, int E, int N, int* __restrict__ deg){
  int e=blockIdx.x*blockDim.x+threadIdx.x;
  if(e>=E+N) return;
  int d=(e<E)? ei[E+e] : (e-E);
  atomicAdd(&deg[d],1);
}
__global__ void scan1_kernel(const int* __restrict__ deg, int* __restrict__ offs,
                             int* __restrict__ bsums, int N){
  __shared__ int sd[1024];
  int t=threadIdx.x;
  int i=blockIdx.x*1024+t;
  int v=(i<N)?deg[i]:0;
  sd[t]=v;
  __syncthreads();
  for(int s=1;s<1024;s<<=1){
    int u=(t>=s)?sd[t-s]:0;
    __syncthreads();
    sd[t]+=u;
    __syncthreads();
  }
  if(i<N) offs[i]=sd[t]-v;
  if(t==1023) bsums[blockIdx.x]=sd[1023];
}
__global__ void scan2_kernel(int* __restrict__ bsums, int* __restrict__ offs, int NB, int N){
  if(threadIdx.x==0&&blockIdx.x==0){
    int run=0;
    for(int b=0;b<NB;b++){int s=bsums[b]; bsums[b]=run; run+=s;}
    offs[N]=run;
  }
}
__global__ void scan3_kernel(int* __restrict__ offs, const int* __restrict__ bsums,
                             int* __restrict__ cursor, int N){
  int i=blockIdx.x*blockDim.x+threadIdx.x;
  if(i<N){
    int o=offs[i]+bsums[i>>10];
    offs[i]=o;
    cursor[i]=o;
  }
}
__global__ void scatter_kernel(const int* __restrict__ ei, int E, int N,
                               int* __restrict__ cursor, int* __restrict__ csr){
  int e=blockIdx.x*blockDim.x+threadIdx.x;
  if(e>=E+N) return;
  int s,d;
  if(e<E){ s=ei[e]; d=ei[E+e]; } else { s=e-E; d=s; }
  int pos=atomicAdd(&cursor[d],1);
  csr[pos]=s;
}

// ---------------- MFMA GEMM (fp16 in), 128x128 tile, BK=64, fused epilogues --------
// MODE 0: GAT  — write htmp f16 + per-head es/ed dots (NXB must be 1)
// MODE 1: LSTM — gate nonlinearities, cbuf/h16 update, JK score atomics
// 1-D grid with bijective XCD remap; LDS XOR-swizzle (T2) on staging+read;
// double-buffered staging with counted vmcnt (T3/T4 minimal pipeline).
struct GemmDesc {
  const f16* a[10]; const f16* b[10];
  int lda[10], ldb[10];
  int nt; int M; int GY; int NXB;
  // MODE 0
  f16* htmp; const float* as_; const float* ad_; float* es; float* ed;
  // MODE 1
  f16* h16; float* cbuf; const float* bias; const float* wa; float* score;
  int l_out; int firstStep;
};

template<int MODE>
__global__ __launch_bounds__(256) void gemm_mfma(GemmDesc d){
  __shared__ __align__(16) char smraw[65536];    // 2 x (As 16KB + Bs 16KB); EP aliases
  const int TILE = 128*64;                       // f16 elems per half-buffer
  f16* As0=(f16*)smraw;  f16* Bs0=As0+TILE;
  f16* As1=Bs0+TILE;     f16* Bs1=As1+TILE;
  float* EP = (float*)smraw;

  // XCD-aware remap: consecutive wg ids round-robin XCDs; give each XCD whole panels
  const int wg = blockIdx.x;
  const int xcd = wg & 7, kk0 = wg >> 3;
  const int xb = kk0 % d.NXB;
  const int yp = xcd + 8*(kk0 / d.NXB);
  if (yp >= d.GY) return;

  const int t = threadIdx.x;
  const int wv = t>>6, ln = t&63;
  const int m0 = yp*128, n0 = xb*128;
  const int wr = (wv>>1)*64, wc = (wv&1)*64;
  f32x4 acc[4][4];
#pragma unroll
  for(int i=0;i<4;i++)
#pragma unroll
  for(int j=0;j<4;j++) acc[i][j]=(f32x4){0.f,0.f,0.f,0.f};

  const int sR = ln>>3;                    // row within 8-row group
  const int sC = ((ln&7)*8) ^ (sR<<3);     // SWIZZLED source col (f16 elems)

  auto stage=[&](int kt,int buf){
    const f16* aS=d.a[kt]; const int lda=d.lda[kt];
    const f16* bS=d.b[kt]; const int ldb=d.ldb[kt];
    f16* As = buf? As1:As0;  f16* Bs = buf? Bs1:Bs0;
#pragma unroll
    for(int i=0;i<4;i++){
      int lrow=i*32+wv*8;
      int gr=m0+lrow+sR; if(gr>=d.M) gr=d.M-1;
      __builtin_amdgcn_global_load_lds(
        (const __attribute__((address_space(1))) unsigned int*)(aS+(size_t)gr*lda+sC),
        (__attribute__((address_space(3))) unsigned int*)&As[lrow*64], 16, 0, 0);
      __builtin_amdgcn_global_load_lds(
        (const __attribute__((address_space(1))) unsigned int*)(bS+(size_t)(n0+lrow+sR)*ldb+sC),
        (__attribute__((address_space(3))) unsigned int*)&Bs[lrow*64], 16, 0, 0);
    }
  };

  stage(0,0);
  for (int kt=0; kt<d.nt; kt++){
    const int cur = kt&1;
    if (kt+1<d.nt){
      stage(kt+1, cur^1);
      asm volatile("s_waitcnt vmcnt(8)" ::: "memory");   // tile kt's 8 loads done; 8 stay in flight
    } else {
      asm volatile("s_waitcnt vmcnt(0)" ::: "memory");
    }
    __builtin_amdgcn_sched_barrier(0);
    __builtin_amdgcn_s_barrier();            // all waves staged tile kt
    __builtin_amdgcn_sched_barrier(0);
    f16* As = cur? As1:As0;  f16* Bs = cur? Bs1:Bs0;
    const int swz = (ln&7)<<3;               // read-side XOR
#pragma unroll
    for (int kk=0; kk<2; kk++){
      f16x8 av[4], bv[4];
#pragma unroll
      for (int i=0;i<4;i++)
        av[i] = *(const f16x8*)&As[(wr + i*16 + (ln&15))*64 + ((kk*32 + (ln>>4)*8) ^ swz)];
#pragma unroll
      for (int j=0;j<4;j++)
        bv[j] = *(const f16x8*)&Bs[(wc + j*16 + (ln&15))*64 + ((kk*32 + (ln>>4)*8) ^ swz)];
#pragma unroll
      for (int i=0;i<4;i++)
#pragma unroll
      for (int j=0;j<4;j++)
        acc[i][j] = __builtin_amdgcn_mfma_f32_16x16x32_f16(av[i], bv[j], acc[i][j], 0,0,0);
    }
    __builtin_amdgcn_sched_barrier(0);
    __builtin_amdgcn_s_barrier();            // reads of buf cur done; safe to overwrite next iter
  }

  // ---- fused epilogue: two 64-row phases staged through EP (aliases staging LDS) ----
  const int lc2 = ln&15, lr4 = (ln>>4)*4;
  const int row4 = t>>2, q4 = t&3;     // 64 rows x 4 col-quarters (32 cols each)
#pragma unroll
  for (int ph=0; ph<2; ph++){
    __syncthreads();
    if ((wv>>1) == ph){
#pragma unroll
      for (int i=0;i<4;i++){
#pragma unroll
        for (int jf=0;jf<4;jf++){
          int col = wc + jf*16 + lc2;
#pragma unroll
          for (int r=0;r<4;r++)
            EP[(i*16+lr4+r)*132 + col] = acc[i][jf][r];
        }
      }
    }
    __syncthreads();
    int grow = m0 + ph*64 + row4;
    if (grow < d.M){
      if (MODE==0){
        float s=0.f, dd=0.f;
        const float* asp = d.as_ + q4*32;
        const float* adp = d.ad_ + q4*32;
#pragma unroll
        for (int q8=0;q8<4;q8++){
          f16x8 pk;
#pragma unroll
          for (int r=0;r<8;r++){
            float v = EP[row4*132 + q4*32 + q8*8 + r];
            pk[r] = (f16)v;
            s  += v*asp[q8*8+r];
            dd += v*adp[q8*8+r];
          }
          *(f16x8*)&d.htmp[(size_t)grow*128 + q4*32 + q8*8] = pk;
        }
        d.es[grow*4+q4] = s;
        d.ed[grow*4+q4] = dd;
      } else {
        float sc = 0.f;
        int jg0 = xb*32 + q4*8;
        size_t hbase = (size_t)grow*192 + jg0;
        const float* bI = d.bias + (size_t)xb*128 + q4*32;
        f16x8 hl;
#pragma unroll
        for (int j=0;j<8;j++){
          float4 z = *(float4*)&EP[row4*132 + q4*32 + j*4];
          float zi=z.x+bI[j*4+0], zf=z.y+bI[j*4+1], zg=z.z+bI[j*4+2], zo=z.w+bI[j*4+3];
          float cold = d.firstStep ? 0.f : d.cbuf[hbase+j];
          float c = fsig(zf)*cold + fsig(zi)*ftanh(zg);
          float h = fsig(zo)*ftanh(c);
          d.cbuf[hbase+j] = c;
          hl[j] = (f16)h;
          sc += h * d.wa[jg0+j];
        }
        *(f16x8*)&d.h16[hbase] = hl;
        sc += __shfl_xor(sc,1);
        sc += __shfl_xor(sc,2);
        if (q4==0) atomicAdd(&d.score[(size_t)grow*3 + d.l_out], sc);
      }
    }
  }
}

// ---------------- GAT attention: single pass, f16 gather ----------------
__global__ __launch_bounds__(256) void attn_kernel(const f16* __restrict__ htmp,
   const float* __restrict__ es, const float* __restrict__ ed,
   const int* __restrict__ offs, const int* __restrict__ csr,
   const float* __restrict__ bias, f16* __restrict__ xsl, int N){
  int v=blockIdx.x*4+(threadIdx.x>>6);
  if(v>=N) return;
  int lane=threadIdx.x&63;
  int hd=lane>>4;          // head for this lane's channels
  int c0=lane*2;
  int beg=offs[v], end=offs[v+1];
  float edv=ed[v*4+hd];
  float ssum=0.f,a0=0.f,a1=0.f;
  for(int i=beg;i<end;i++){
    int s=csr[i];
    float e=es[s*4+hd]+edv;
    e=(e>0.f)?e:0.2f*e;
    float ex=__expf(e);          // no max-shift needed: e is O(+-5), softmax invariant
    ssum+=ex;
    union {unsigned u; f16 h[2];} pk;
    pk.u = *reinterpret_cast<const unsigned*>(&htmp[(size_t)s*128+c0]);
    a0+=ex*(float)pk.h[0]; a1+=ex*(float)pk.h[1];
  }
  float inv=1.0f/(ssum+1e-16f);
  float o0=fmaxf(a0*inv+bias[c0],0.f), o1=fmaxf(a1*inv+bias[c0+1],0.f);
  union { f16 h[2]; unsigned u; } pko;
  pko.h[0]=(f16)o0; pko.h[1]=(f16)o1;
  *reinterpret_cast<unsigned*>(&xsl[(size_t)v*128+c0]) = pko.u;
}

// ---------------- JK softmax + weighted sum + pooling ----------------
__global__ __launch_bounds__(128) void jk_pool_kernel(const f16* __restrict__ xs, size_t xstride,
   const float* __restrict__ score, const int* __restrict__ batch,
   float* __restrict__ pooled, float* __restrict__ counts, int N){
  int n=blockIdx.x; int c=threadIdx.x;
  float s0=score[n*3],s1=score[n*3+1],s2=score[n*3+2];
  float m=fmaxf(s0,fmaxf(s1,s2));
  float e0=expf(s0-m),e1=expf(s1-m),e2=expf(s2-m);
  float inv=1.0f/(e0+e1+e2);
  size_t base=(size_t)n*128+c;
  float jk=((float)xs[base]*e0+(float)xs[xstride+base]*e1+(float)xs[2*xstride+base]*e2)*inv;
  int g=batch[n];
  atomicAdd(&pooled[(size_t)g*128+c],jk);
  if(c==0) atomicAdd(&counts[g],1.0f);
}

__global__ __launch_bounds__(128) void final_kernel(const float* __restrict__ pooled,
   const float* __restrict__ counts, const float* __restrict__ Wl,
   const float* __restrict__ bl, float* __restrict__ out, int G){
  int g=blockIdx.x; int c=threadIdx.x;
  float cnt=fmaxf(counts[g],1.0f);
  float pv=pooled[(size_t)g*128+c]/cnt;
  float p0=pv*Wl[c*2], p1=pv*Wl[c*2+1];
  for(int s=32;s>=1;s>>=1){ p0+=__shfl_down(p0,s); p1+=__shfl_down(p1,s); }
  __shared__ float sm[4];
  int w=c>>6;
  if((c&63)==0){ sm[w*2]=p0; sm[w*2+1]=p1; }
  __syncthreads();
  if(c==0){
    out[g*2+0]=sm[0]+sm[2]+bl[0];
    out[g*2+1]=sm[1]+sm[3]+bl[1];
  }
}

// ---------------- launch ----------------
extern "C" void kernel_launch(void* const* d_in, const int* in_sizes, int n_in,
                              void* d_out, int out_size, void* d_ws, size_t ws_size,
                              hipStream_t stream) {
  const float* x     = (const float*)d_in[0];
  const int*   ei    = (const int*)d_in[1];
  const int*   batch = (const int*)d_in[2];
  const float* W[3]  = {(const float*)d_in[3],(const float*)d_in[7],(const float*)d_in[11]};
  const float* AS[3] = {(const float*)d_in[4],(const float*)d_in[8],(const float*)d_in[12]};
  const float* AD[3] = {(const float*)d_in[5],(const float*)d_in[9],(const float*)d_in[13]};
  const float* BV[3] = {(const float*)d_in[6],(const float*)d_in[10],(const float*)d_in[14]};
  const float* Wih[2]= {(const float*)d_in[15],(const float*)d_in[19]};
  const float* Whh[2]= {(const float*)d_in[16],(const float*)d_in[20]};
  const float* bih[2]= {(const float*)d_in[17],(const float*)d_in[21]};
  const float* bhh[2]= {(const float*)d_in[18],(const float*)d_in[22]};
  const float* Wa    = (const float*)d_in[23];
  const float* Wl    = (const float*)d_in[25];
  const float* bl    = (const float*)d_in[26];
  float* out = (float*)d_out;

  const int N  = in_sizes[2];
  const int E  = in_sizes[1]/2;
  const int ET = E+N;
  const int G  = out_size/2;
  const int Mpad = CDIV(N,128)*128;
  const int GY = CDIV(N,128);
  const int GYp = CDIV(GY,8)*8;

  // ---- workspace carve (256B aligned) ----
  char* p = (char*)d_ws;
  auto alloc = [&](size_t bytes)->char*{ char* r=p; p += ((bytes+255)/256)*256; return r; };
  // fixed region
  int*   deg    = (int*)  alloc((size_t)N*4);
  int*   offs   = (int*)  alloc((size_t)(N+1)*4);
  int*   cursor = (int*)  alloc((size_t)N*4);
  int*   bsums  = (int*)  alloc((size_t)CDIV(N,1024)*4);
  int*   csr    = (int*)  alloc((size_t)ET*4);
  f16*   WtH[3], *WtL[3];
  for(int l=0;l<3;l++){ WtH[l]=(f16*)alloc(128*128*2); WtL[l]=(f16*)alloc(128*128*2); }
  f16 *WihH[2],*WihL[2],*WhhH[2],*WhhL[2];
  float* bsumI[2];
  for(int d2=0;d2<2;d2++){
    WihH[d2]=(f16*)alloc(768*128*2); WihL[d2]=(f16*)alloc(768*128*2);
    WhhH[d2]=(f16*)alloc(768*192*2); WhhL[d2]=(f16*)alloc(768*192*2);
    bsumI[d2]=(float*)alloc(768*4);
  }
  f16*   xs16   = (f16*)  alloc((size_t)3*Mpad*128*2);
  float* score  = (float*)alloc((size_t)N*3*4);
  float* pooled = (float*)alloc((size_t)(G*128+G)*4);
  float* counts = pooled + (size_t)G*128;
  char* P = p;   // phase-overlaid region
  auto al256 = [](size_t b)->size_t{ return ((b+255)/256)*256; };
  // GAT phase overlay
  f16*   x016 = (f16*)P;
  f16*   htmp = (f16*)(P + al256((size_t)Mpad*128*2));
  float* esb  = (float*)((char*)htmp + al256((size_t)Mpad*128*2));
  float* edb  = (float*)((char*)esb + al256((size_t)N*4*4));
  // LSTM phase overlay (GAT buffers dead by then)
  f16*   h16  = (f16*)P;
  float* cbuf = (float*)(P + al256((size_t)Mpad*192*2));

  const size_t xstride = (size_t)Mpad*128;

  // ---- 0. weight/input prep ----
  f2h_kernel<<<512,256,0,stream>>>(x, x016, (size_t)N*128);
  for(int l=0;l<3;l++) wtrans_kernel<<<128,128,0,stream>>>(W[l], WtH[l], WtL[l]);
  for(int d2=0;d2<2;d2++){
    lstm_wprep<<<768,128,0,stream>>>(Wih[d2], WihH[d2], WihL[d2], 128);
    lstm_wprep<<<768,192,0,stream>>>(Whh[d2], WhhH[d2], WhhL[d2], 192);
    lstm_bprep<<<3,256,0,stream>>>(bih[d2], bhh[d2], bsumI[d2]);
  }
  zero_kernel<<<64,256,0,stream>>>(score,(size_t)N*3);
  zero_kernel<<<512,256,0,stream>>>(pooled,(size_t)(G*128+G));

  // ---- 1. CSR build ----
  zero_kernel<<<64,256,0,stream>>>((float*)deg,(size_t)N);
  hist_kernel<<<CDIV(ET,256),256,0,stream>>>(ei,E,N,deg);
  int NB = CDIV(N,1024);
  scan1_kernel<<<NB,1024,0,stream>>>(deg,offs,bsums,N);
  scan2_kernel<<<1,64,0,stream>>>(bsums,offs,NB,N);
  scan3_kernel<<<CDIV(N,256),256,0,stream>>>(offs,bsums,cursor,N);
  scatter_kernel<<<CDIV(ET,256),256,0,stream>>>(ei,E,N,cursor,csr);

  // ---- 2. GAT layers (A fp16, B hi/lo; fused htmp/es/ed epilogue) ----
  const f16* ain = x016;
  for (int l=0; l<3; l++){
    GemmDesc gd{};
    gd.nt=4; gd.M=N; gd.GY=GY; gd.NXB=1;
    gd.htmp=htmp; gd.as_=AS[l]; gd.ad_=AD[l]; gd.es=esb; gd.ed=edb;
    int ti=0;
    for (int q=0;q<2;q++)
      for (int s=0;s<2;s++){
        gd.a[ti]=ain+q*64;                      gd.lda[ti]=128;
        gd.b[ti]=(s? WtL[l]:WtH[l])+q*64;       gd.ldb[ti]=128;
        ti++;
      }
    gemm_mfma<0><<<GYp,256,0,stream>>>(gd);
    attn_kernel<<<CDIV(N,4),256,0,stream>>>(htmp,esb,edb,offs,csr,BV[l],
                                            xs16+(size_t)l*xstride,N);
    ain = xs16+(size_t)l*xstride;
  }

  // ---- 3. bidirectional LSTM, gates + scores fused into GEMM epilogue ----
  for (int dir=0; dir<2; dir++){
    for (int st=0; st<3; st++){
      int l_in = dir? (2-st) : st;
      const f16* xt = xs16 + (size_t)l_in*xstride;
      GemmDesc gd{};
      gd.M=N; gd.GY=GY; gd.NXB=6;
      gd.h16=h16; gd.cbuf=cbuf; gd.bias=bsumI[dir]; gd.wa=Wa+dir*192;
      gd.score=score; gd.l_out=l_in; gd.firstStep=(st==0);
      int ti=0;
      // q-outer, s-inner: hi/lo passes of the same A tile are adjacent (L2 hit)
      for (int q=0;q<2;q++)
        for (int s=0;s<2;s++){
          gd.a[ti]=xt + q*64;                          gd.lda[ti]=128;
          gd.b[ti]=(s? WihL[dir]:WihH[dir]) + q*64;    gd.ldb[ti]=128;
          ti++;
        }
      if (st>0){
        for (int q=0;q<3;q++)
          for (int s=0;s<2;s++){
            gd.a[ti]=h16 + q*64;                       gd.lda[ti]=192;
            gd.b[ti]=(s? WhhL[dir]:WhhH[dir]) + q*64;  gd.ldb[ti]=192;
            ti++;
          }
      }
      gd.nt=ti;   // 4 on first step, 10 otherwise
      gemm_mfma<1><<<6*GYp,256,0,stream>>>(gd);
    }
  }

  // ---- 4. JK attention + pooling + final linear ----
  jk_pool_kernel<<<N,128,0,stream>>>(xs16,xstride,score,batch,pooled,counts,N);
  final_kernel<<<G,128,0,stream>>>(pooled,counts,Wl,bl,out,G);
}

// Round 6
// 1009.631 us; speedup vs baseline: 2.7732x; 1.1129x over previous
//
#include <hip/hip_runtime.h>
#include <math.h>

#define CDIV(a,b) (((a)+(b)-1)/(b))

typedef _Float16 f16;
typedef _Float16 f16x8 __attribute__((ext_vector_type(8)));
typedef float f32x4 __attribute__((ext_vector_type(4)));

__device__ __forceinline__ float rcpf(float x){ return __builtin_amdgcn_rcpf(x); }
__device__ __forceinline__ float fsig(float x){ return rcpf(1.0f+__expf(-x)); }
__device__ __forceinline__ float ftanh(float x){ float e=__expf(2.0f*x); return 1.0f-2.0f*rcpf(e+1.0f); }

// ---------------- utility ----------------
__global__ void zero_kernel(float* __restrict__ p, size_t n){
  size_t i=(size_t)blockIdx.x*blockDim.x+threadIdx.x;
  size_t st=(size_t)gridDim.x*blockDim.x;
  for(;i<n;i+=st) p[i]=0.0f;
}

// ---------------- fp16 conversion prep ----------------
__global__ void f2h_kernel(const float* __restrict__ s, f16* __restrict__ d, size_t n){
  size_t i=(size_t)blockIdx.x*blockDim.x+threadIdx.x;
  size_t st=(size_t)gridDim.x*blockDim.x;
  for(;i<n;i+=st) d[i]=(f16)s[i];
}
// W [128 in][128 out] -> Wt hi/lo [out][in]
__global__ void wtrans_kernel(const float* __restrict__ W, f16* __restrict__ hi,
                              f16* __restrict__ lo){
  int o=blockIdx.x, i=threadIdx.x;
  float f=W[(size_t)i*128+o];
  f16 h=(f16)f; hi[o*128+i]=h; lo[o*128+i]=(f16)(f-(float)h);
}
// LSTM weights: rows reordered gate-major -> interleaved row' = j*4+gate; split hi/lo
__global__ void lstm_wprep(const float* __restrict__ W, f16* __restrict__ hi,
                           f16* __restrict__ lo, int ld){
  int rn=blockIdx.x; int k=threadIdx.x;
  int j=rn>>2, gate=rn&3;
  float f=W[(size_t)(gate*192+j)*ld + k];
  f16 h=(f16)f;
  hi[(size_t)rn*ld+k]=h; lo[(size_t)rn*ld+k]=(f16)(f-(float)h);
}
__global__ void lstm_bprep(const float* __restrict__ bih, const float* __restrict__ bhh,
                           float* __restrict__ bI){
  int rn=blockIdx.x*blockDim.x+threadIdx.x;
  if(rn<768){ int j=rn>>2,g=rn&3; int go=g*192+j; bI[rn]=bih[go]+bhh[go]; }
}

// ---------------- CSR build ----------------
__global__ void hist_kernel(const int* __restrict__ ei, int E, int N, int* __restrict__ deg){
  int e=blockIdx.x*blockDim.x+threadIdx.x;
  if(e>=E+N) return;
  int d=(e<E)? ei[E+e] : (e-E);
  atomicAdd(&deg[d],1);
}
__global__ void scan1_kernel(const int* __restrict__ deg, int* __restrict__ offs,
                             int* __restrict__ bsums, int N){
  __shared__ int sd[1024];
  int t=threadIdx.x;
  int i=blockIdx.x*1024+t;
  int v=(i<N)?deg[i]:0;
  sd[t]=v;
  __syncthreads();
  for(int s=1;s<1024;s<<=1){
    int u=(t>=s)?sd[t-s]:0;
    __syncthreads();
    sd[t]+=u;
    __syncthreads();
  }
  if(i<N) offs[i]=sd[t]-v;
  if(t==1023) bsums[blockIdx.x]=sd[1023];
}
__global__ void scan2_kernel(int* __restrict__ bsums, int* __restrict__ offs, int NB, int N){
  if(threadIdx.x==0&&blockIdx.x==0){
    int run=0;
    for(int b=0;b<NB;b++){int s=bsums[b]; bsums[b]=run; run+=s;}
    offs[N]=run;
  }
}
__global__ void scan3_kernel(int* __restrict__ offs, const int* __restrict__ bsums,
                             int* __restrict__ cursor, int N){
  int i=blockIdx.x*blockDim.x+threadIdx.x;
  if(i<N){
    int o=offs[i]+bsums[i>>10];
    offs[i]=o;
    cursor[i]=o;
  }
}
__global__ void scatter_kernel(const int* __restrict__ ei, int E, int N,
                               int* __restrict__ cursor, int* __restrict__ csr){
  int e=blockIdx.x*blockDim.x+threadIdx.x;
  if(e>=E+N) return;
  int s,d;
  if(e<E){ s=ei[e]; d=ei[E+e]; } else { s=e-E; d=s; }
  int pos=atomicAdd(&cursor[d],1);
  csr[pos]=s;
}

// ---------------- graph offsets: batch is sorted -> binary search ----------------
__global__ void goffs_kernel(const int* __restrict__ batch, int N, int G,
                             int* __restrict__ goffs){
  int g=blockIdx.x*blockDim.x+threadIdx.x;
  if (g>G) return;
  if (g==G){ goffs[G]=N; return; }
  int lo=0, hi=N;
  while (lo<hi){ int mid=(lo+hi)>>1; if (batch[mid]<g) lo=mid+1; else hi=mid; }
  goffs[g]=lo;
}

// ---------------- MFMA GEMM (fp16 in), 128x128 tile, BK=64, fused epilogues --------
// MODE 0: GAT  — write htmp f16 + per-head es/ed dots (NXB must be 1)
// MODE 1: LSTM — gate nonlinearities, cbuf/h16 update, JK score atomics
// 1-D grid with bijective XCD remap; LDS XOR-swizzle (T2) on staging+read;
// double-buffered staging with counted vmcnt (T3/T4 minimal pipeline).
struct GemmDesc {
  const f16* a[10]; const f16* b[10];
  int lda[10], ldb[10];
  int nt; int M; int GY; int NXB;
  // MODE 0
  f16* htmp; const float* as_; const float* ad_; float* es; float* ed;
  // MODE 1
  f16* h16; float* cbuf; const float* bias; const float* wa; float* score;
  int l_out; int firstStep;
};

template<int MODE>
__global__ __launch_bounds__(256) void gemm_mfma(GemmDesc d){
  __shared__ __align__(16) char smraw[65536];    // 2 x (As 16KB + Bs 16KB); EP aliases
  const int TILE = 128*64;                       // f16 elems per half-buffer
  f16* As0=(f16*)smraw;  f16* Bs0=As0+TILE;
  f16* As1=Bs0+TILE;     f16* Bs1=As1+TILE;
  float* EP = (float*)smraw;

  // XCD-aware remap: consecutive wg ids round-robin XCDs; give each XCD whole panels
  const int wg = blockIdx.x;
  const int xcd = wg & 7, kk0 = wg >> 3;
  const int xb = kk0 % d.NXB;
  const int yp = xcd + 8*(kk0 / d.NXB);
  if (yp >= d.GY) return;

  const int t = threadIdx.x;
  const int wv = t>>6, ln = t&63;
  const int m0 = yp*128, n0 = xb*128;
  const int wr = (wv>>1)*64, wc = (wv&1)*64;
  f32x4 acc[4][4];
#pragma unroll
  for(int i=0;i<4;i++)
#pragma unroll
  for(int j=0;j<4;j++) acc[i][j]=(f32x4){0.f,0.f,0.f,0.f};

  const int sR = ln>>3;                    // row within 8-row group
  const int sC = ((ln&7)*8) ^ (sR<<3);     // SWIZZLED source col (f16 elems)

  auto stage=[&](int kt,int buf){
    const f16* aS=d.a[kt]; const int lda=d.lda[kt];
    const f16* bS=d.b[kt]; const int ldb=d.ldb[kt];
    f16* As = buf? As1:As0;  f16* Bs = buf? Bs1:Bs0;
#pragma unroll
    for(int i=0;i<4;i++){
      int lrow=i*32+wv*8;
      int gr=m0+lrow+sR; if(gr>=d.M) gr=d.M-1;
      __builtin_amdgcn_global_load_lds(
        (const __attribute__((address_space(1))) unsigned int*)(aS+(size_t)gr*lda+sC),
        (__attribute__((address_space(3))) unsigned int*)&As[lrow*64], 16, 0, 0);
      __builtin_amdgcn_global_load_lds(
        (const __attribute__((address_space(1))) unsigned int*)(bS+(size_t)(n0+lrow+sR)*ldb+sC),
        (__attribute__((address_space(3))) unsigned int*)&Bs[lrow*64], 16, 0, 0);
    }
  };

  stage(0,0);
  for (int kt=0; kt<d.nt; kt++){
    const int cur = kt&1;
    if (kt+1<d.nt){
      stage(kt+1, cur^1);
      asm volatile("s_waitcnt vmcnt(8)" ::: "memory");   // tile kt's 8 loads done; 8 stay in flight
    } else {
      asm volatile("s_waitcnt vmcnt(0)" ::: "memory");
    }
    __builtin_amdgcn_sched_barrier(0);
    __builtin_amdgcn_s_barrier();            // all waves staged tile kt
    __builtin_amdgcn_sched_barrier(0);
    f16* As = cur? As1:As0;  f16* Bs = cur? Bs1:Bs0;
    const int swz = (ln&7)<<3;               // read-side XOR
#pragma unroll
    for (int kk=0; kk<2; kk++){
      f16x8 av[4], bv[4];
#pragma unroll
      for (int i=0;i<4;i++)
        av[i] = *(const f16x8*)&As[(wr + i*16 + (ln&15))*64 + ((kk*32 + (ln>>4)*8) ^ swz)];
#pragma unroll
      for (int j=0;j<4;j++)
        bv[j] = *(const f16x8*)&Bs[(wc + j*16 + (ln&15))*64 + ((kk*32 + (ln>>4)*8) ^ swz)];
#pragma unroll
      for (int i=0;i<4;i++)
#pragma unroll
      for (int j=0;j<4;j++)
        acc[i][j] = __builtin_amdgcn_mfma_f32_16x16x32_f16(av[i], bv[j], acc[i][j], 0,0,0);
    }
    __builtin_amdgcn_sched_barrier(0);
    __builtin_amdgcn_s_barrier();            // reads of buf cur done; safe to overwrite next iter
  }

  // ---- fused epilogue: two 64-row phases staged through EP (aliases staging LDS) ----
  const int lc2 = ln&15, lr4 = (ln>>4)*4;
  const int row4 = t>>2, q4 = t&3;     // 64 rows x 4 col-quarters (32 cols each)
#pragma unroll
  for (int ph=0; ph<2; ph++){
    __syncthreads();
    if ((wv>>1) == ph){
#pragma unroll
      for (int i=0;i<4;i++){
#pragma unroll
        for (int jf=0;jf<4;jf++){
          int col = wc + jf*16 + lc2;
#pragma unroll
          for (int r=0;r<4;r++)
            EP[(i*16+lr4+r)*132 + col] = acc[i][jf][r];
        }
      }
    }
    __syncthreads();
    int grow = m0 + ph*64 + row4;
    if (grow < d.M){
      if (MODE==0){
        float s=0.f, dd=0.f;
        const float* asp = d.as_ + q4*32;
        const float* adp = d.ad_ + q4*32;
#pragma unroll
        for (int q8=0;q8<4;q8++){
          f16x8 pk;
#pragma unroll
          for (int r=0;r<8;r++){
            float v = EP[row4*132 + q4*32 + q8*8 + r];
            pk[r] = (f16)v;
            s  += v*asp[q8*8+r];
            dd += v*adp[q8*8+r];
          }
          *(f16x8*)&d.htmp[(size_t)grow*128 + q4*32 + q8*8] = pk;
        }
        d.es[grow*4+q4] = s;
        d.ed[grow*4+q4] = dd;
      } else {
        float sc = 0.f;
        int jg0 = xb*32 + q4*8;
        size_t hbase = (size_t)grow*192 + jg0;
        const float* bI = d.bias + (size_t)xb*128 + q4*32;
        f16x8 hl;
#pragma unroll
        for (int j=0;j<8;j++){
          float4 z = *(float4*)&EP[row4*132 + q4*32 + j*4];
          float zi=z.x+bI[j*4+0], zf=z.y+bI[j*4+1], zg=z.z+bI[j*4+2], zo=z.w+bI[j*4+3];
          float cold = d.firstStep ? 0.f : d.cbuf[hbase+j];
          float c = fsig(zf)*cold + fsig(zi)*ftanh(zg);
          float h = fsig(zo)*ftanh(c);
          d.cbuf[hbase+j] = c;
          hl[j] = (f16)h;
          sc += h * d.wa[jg0+j];
        }
        *(f16x8*)&d.h16[hbase] = hl;
        sc += __shfl_xor(sc,1);
        sc += __shfl_xor(sc,2);
        if (q4==0) atomicAdd(&d.score[(size_t)grow*3 + d.l_out], sc);
      }
    }
  }
}

// ---------------- GAT attention: single pass, f16 gather ----------------
__global__ __launch_bounds__(256) void attn_kernel(const f16* __restrict__ htmp,
   const float* __restrict__ es, const float* __restrict__ ed,
   const int* __restrict__ offs, const int* __restrict__ csr,
   const float* __restrict__ bias, f16* __restrict__ xsl, int N){
  int v=blockIdx.x*4+(threadIdx.x>>6);
  if(v>=N) return;
  int lane=threadIdx.x&63;
  int hd=lane>>4;          // head for this lane's channels
  int c0=lane*2;
  int beg=offs[v], end=offs[v+1];
  float edv=ed[v*4+hd];
  float ssum=0.f,a0=0.f,a1=0.f;
  for(int i=beg;i<end;i++){
    int s=csr[i];
    float e=es[s*4+hd]+edv;
    e=(e>0.f)?e:0.2f*e;
    float ex=__expf(e);          // no max-shift needed: e is O(+-5), softmax invariant
    ssum+=ex;
    union {unsigned u; f16 h[2];} pk;
    pk.u = *reinterpret_cast<const unsigned*>(&htmp[(size_t)s*128+c0]);
    a0+=ex*(float)pk.h[0]; a1+=ex*(float)pk.h[1];
  }
  float inv=1.0f/(ssum+1e-16f);
  float o0=fmaxf(a0*inv+bias[c0],0.f), o1=fmaxf(a1*inv+bias[c0+1],0.f);
  union { f16 h[2]; unsigned u; } pko;
  pko.h[0]=(f16)o0; pko.h[1]=(f16)o1;
  *reinterpret_cast<unsigned*>(&xsl[(size_t)v*128+c0]) = pko.u;
}

// ---------------- JK softmax + weighted sum + mean-pool: one block per graph ------
__global__ __launch_bounds__(256) void jk_pool_kernel(const f16* __restrict__ xs, size_t xstride,
   const float* __restrict__ score, const int* __restrict__ goffs,
   float* __restrict__ pooled, int G){
  int g=blockIdx.x;
  int beg=goffs[g], end=goffs[g+1];
  int c=threadIdx.x&127, half=threadIdx.x>>7;
  float acc=0.f;
  for(int n=beg+half; n<end; n+=2){
    float s0=score[n*3],s1=score[n*3+1],s2=score[n*3+2];
    float m=fmaxf(s0,fmaxf(s1,s2));
    float e0=__expf(s0-m),e1=__expf(s1-m),e2=__expf(s2-m);
    float inv=rcpf(e0+e1+e2);
    size_t base=(size_t)n*128+c;
    acc += ((float)xs[base]*e0+(float)xs[xstride+base]*e1+(float)xs[2*xstride+base]*e2)*inv;
  }
  __shared__ float red[128];
  if(half==1) red[c]=acc;
  __syncthreads();
  if(half==0){
    float tot=acc+red[c];
    float cnt=(float)(end-beg);
    pooled[(size_t)g*128+c]=tot*rcpf(fmaxf(cnt,1.0f));
  }
}

__global__ __launch_bounds__(128) void final_kernel(const float* __restrict__ pooled,
   const float* __restrict__ Wl, const float* __restrict__ bl,
   float* __restrict__ out, int G){
  int g=blockIdx.x; int c=threadIdx.x;
  float pv=pooled[(size_t)g*128+c];
  float p0=pv*Wl[c*2], p1=pv*Wl[c*2+1];
  for(int s=32;s>=1;s>>=1){ p0+=__shfl_down(p0,s); p1+=__shfl_down(p1,s); }
  __shared__ float sm[4];
  int w=c>>6;
  if((c&63)==0){ sm[w*2]=p0; sm[w*2+1]=p1; }
  __syncthreads();
  if(c==0){
    out[g*2+0]=sm[0]+sm[2]+bl[0];
    out[g*2+1]=sm[1]+sm[3]+bl[1];
  }
}

// ---------------- launch ----------------
extern "C" void kernel_launch(void* const* d_in, const int* in_sizes, int n_in,
                              void* d_out, int out_size, void* d_ws, size_t ws_size,
                              hipStream_t stream) {
  const float* x     = (const float*)d_in[0];
  const int*   ei    = (const int*)d_in[1];
  const int*   batch = (const int*)d_in[2];
  const float* W[3]  = {(const float*)d_in[3],(const float*)d_in[7],(const float*)d_in[11]};
  const float* AS[3] = {(const float*)d_in[4],(const float*)d_in[8],(const float*)d_in[12]};
  const float* AD[3] = {(const float*)d_in[5],(const float*)d_in[9],(const float*)d_in[13]};
  const float* BV[3] = {(const float*)d_in[6],(const float*)d_in[10],(const float*)d_in[14]};
  const float* Wih[2]= {(const float*)d_in[15],(const float*)d_in[19]};
  const float* Whh[2]= {(const float*)d_in[16],(const float*)d_in[20]};
  const float* bih[2]= {(const float*)d_in[17],(const float*)d_in[21]};
  const float* bhh[2]= {(const float*)d_in[18],(const float*)d_in[22]};
  const float* Wa    = (const float*)d_in[23];
  const float* Wl    = (const float*)d_in[25];
  const float* bl    = (const float*)d_in[26];
  float* out = (float*)d_out;

  const int N  = in_sizes[2];
  const int E  = in_sizes[1]/2;
  const int ET = E+N;
  const int G  = out_size/2;
  const int Mpad = CDIV(N,128)*128;
  const int GY = CDIV(N,128);
  const int GYp = CDIV(GY,8)*8;

  // ---- workspace carve (256B aligned) ----
  char* p = (char*)d_ws;
  auto alloc = [&](size_t bytes)->char*{ char* r=p; p += ((bytes+255)/256)*256; return r; };
  // fixed region
  int*   deg    = (int*)  alloc((size_t)N*4);
  int*   offs   = (int*)  alloc((size_t)(N+1)*4);
  int*   cursor = (int*)  alloc((size_t)N*4);
  int*   bsums  = (int*)  alloc((size_t)CDIV(N,1024)*4);
  int*   csr    = (int*)  alloc((size_t)ET*4);
  int*   goffs  = (int*)  alloc((size_t)(G+1)*4);
  f16*   WtH[3], *WtL[3];
  for(int l=0;l<3;l++){ WtH[l]=(f16*)alloc(128*128*2); WtL[l]=(f16*)alloc(128*128*2); }
  f16 *WihH[2],*WihL[2],*WhhH[2],*WhhL[2];
  float* bsumI[2];
  for(int d2=0;d2<2;d2++){
    WihH[d2]=(f16*)alloc(768*128*2); WihL[d2]=(f16*)alloc(768*128*2);
    WhhH[d2]=(f16*)alloc(768*192*2); WhhL[d2]=(f16*)alloc(768*192*2);
    bsumI[d2]=(float*)alloc(768*4);
  }
  f16*   xs16   = (f16*)  alloc((size_t)3*Mpad*128*2);
  float* score  = (float*)alloc((size_t)N*3*4);
  float* pooled = (float*)alloc((size_t)G*128*4);
  char* P = p;   // phase-overlaid region
  auto al256 = [](size_t b)->size_t{ return ((b+255)/256)*256; };
  // GAT phase overlay
  f16*   x016 = (f16*)P;
  f16*   htmp = (f16*)(P + al256((size_t)Mpad*128*2));
  float* esb  = (float*)((char*)htmp + al256((size_t)Mpad*128*2));
  float* edb  = (float*)((char*)esb + al256((size_t)N*4*4));
  // LSTM phase overlay (GAT buffers dead by then)
  f16*   h16  = (f16*)P;
  float* cbuf = (float*)(P + al256((size_t)Mpad*192*2));

  const size_t xstride = (size_t)Mpad*128;

  // ---- 0. weight/input prep ----
  f2h_kernel<<<512,256,0,stream>>>(x, x016, (size_t)N*128);
  for(int l=0;l<3;l++) wtrans_kernel<<<128,128,0,stream>>>(W[l], WtH[l], WtL[l]);
  for(int d2=0;d2<2;d2++){
    lstm_wprep<<<768,128,0,stream>>>(Wih[d2], WihH[d2], WihL[d2], 128);
    lstm_wprep<<<768,192,0,stream>>>(Whh[d2], WhhH[d2], WhhL[d2], 192);
    lstm_bprep<<<3,256,0,stream>>>(bih[d2], bhh[d2], bsumI[d2]);
  }
  zero_kernel<<<64,256,0,stream>>>(score,(size_t)N*3);
  goffs_kernel<<<CDIV(G+1,256),256,0,stream>>>(batch,N,G,goffs);

  // ---- 1. CSR build ----
  zero_kernel<<<64,256,0,stream>>>((float*)deg,(size_t)N);
  hist_kernel<<<CDIV(ET,256),256,0,stream>>>(ei,E,N,deg);
  int NB = CDIV(N,1024);
  scan1_kernel<<<NB,1024,0,stream>>>(deg,offs,bsums,N);
  scan2_kernel<<<1,64,0,stream>>>(bsums,offs,NB,N);
  scan3_kernel<<<CDIV(N,256),256,0,stream>>>(offs,bsums,cursor,N);
  scatter_kernel<<<CDIV(ET,256),256,0,stream>>>(ei,E,N,cursor,csr);

  // ---- 2. GAT layers (A fp16, B hi/lo; fused htmp/es/ed epilogue) ----
  const f16* ain = x016;
  for (int l=0; l<3; l++){
    GemmDesc gd{};
    gd.nt=4; gd.M=N; gd.GY=GY; gd.NXB=1;
    gd.htmp=htmp; gd.as_=AS[l]; gd.ad_=AD[l]; gd.es=esb; gd.ed=edb;
    int ti=0;
    for (int q=0;q<2;q++)
      for (int s=0;s<2;s++){
        gd.a[ti]=ain+q*64;                      gd.lda[ti]=128;
        gd.b[ti]=(s? WtL[l]:WtH[l])+q*64;       gd.ldb[ti]=128;
        ti++;
      }
    gemm_mfma<0><<<GYp,256,0,stream>>>(gd);
    attn_kernel<<<CDIV(N,4),256,0,stream>>>(htmp,esb,edb,offs,csr,BV[l],
                                            xs16+(size_t)l*xstride,N);
    ain = xs16+(size_t)l*xstride;
  }

  // ---- 3. bidirectional LSTM, gates + scores fused into GEMM epilogue ----
  for (int dir=0; dir<2; dir++){
    for (int st=0; st<3; st++){
      int l_in = dir? (2-st) : st;
      const f16* xt = xs16 + (size_t)l_in*xstride;
      GemmDesc gd{};
      gd.M=N; gd.GY=GY; gd.NXB=6;
      gd.h16=h16; gd.cbuf=cbuf; gd.bias=bsumI[dir]; gd.wa=Wa+dir*192;
      gd.score=score; gd.l_out=l_in; gd.firstStep=(st==0);
      int ti=0;
      // q-outer, s-inner: hi/lo passes of the same A tile are adjacent (L2 hit)
      for (int q=0;q<2;q++)
        for (int s=0;s<2;s++){
          gd.a[ti]=xt + q*64;                          gd.lda[ti]=128;
          gd.b[ti]=(s? WihL[dir]:WihH[dir]) + q*64;    gd.ldb[ti]=128;
          ti++;
        }
      if (st>0){
        for (int q=0;q<3;q++)
          for (int s=0;s<2;s++){
            gd.a[ti]=h16 + q*64;                       gd.lda[ti]=192;
            gd.b[ti]=(s? WhhL[dir]:WhhH[dir]) + q*64;  gd.ldb[ti]=192;
            ti++;
          }
      }
      gd.nt=ti;   // 4 on first step, 10 otherwise
      gemm_mfma<1><<<6*GYp,256,0,stream>>>(gd);
    }
  }

  // ---- 4. JK attention + pooling + final linear ----
  jk_pool_kernel<<<G,256,0,stream>>>(xs16,xstride,score,goffs,pooled,G);
  final_kernel<<<G,128,0,stream>>>(pooled,Wl,bl,out,G);
}

// Round 7
// 981.498 us; speedup vs baseline: 2.8527x; 1.0287x over previous
//
#include <hip/hip_runtime.h>
#include <math.h>

#define CDIV(a,b) (((a)+(b)-1)/(b))

typedef _Float16 f16;
typedef _Float16 f16x8 __attribute__((ext_vector_type(8)));
typedef float f32x4 __attribute__((ext_vector_type(4)));

__device__ __forceinline__ float rcpf(float x){ return __builtin_amdgcn_rcpf(x); }
__device__ __forceinline__ float fsig(float x){ return rcpf(1.0f+__expf(-x)); }
__device__ __forceinline__ float ftanh(float x){ float e=__expf(2.0f*x); return 1.0f-2.0f*rcpf(e+1.0f); }

// ---------------- utility ----------------
__global__ void zero_kernel(float* __restrict__ p, size_t n){
  size_t i=(size_t)blockIdx.x*blockDim.x+threadIdx.x;
  size_t st=(size_t)gridDim.x*blockDim.x;
  for(;i<n;i+=st) p[i]=0.0f;
}

// ---------------- fp16 conversion prep ----------------
__global__ void f2h_kernel(const float* __restrict__ s, f16* __restrict__ d, size_t n){
  size_t i=(size_t)blockIdx.x*blockDim.x+threadIdx.x;
  size_t st=(size_t)gridDim.x*blockDim.x;
  for(;i<n;i+=st) d[i]=(f16)s[i];
}
// W [128 in][128 out] -> Wt hi/lo [out][in]
__global__ void wtrans_kernel(const float* __restrict__ W, f16* __restrict__ hi,
                              f16* __restrict__ lo){
  int o=blockIdx.x, i=threadIdx.x;
  float f=W[(size_t)i*128+o];
  f16 h=(f16)f; hi[o*128+i]=h; lo[o*128+i]=(f16)(f-(float)h);
}
// LSTM weights: rows reordered gate-major -> interleaved row' = j*4+gate; split hi/lo
__global__ void lstm_wprep(const float* __restrict__ W, f16* __restrict__ hi,
                           f16* __restrict__ lo, int ld){
  int rn=blockIdx.x; int k=threadIdx.x;
  int j=rn>>2, gate=rn&3;
  float f=W[(size_t)(gate*192+j)*ld + k];
  f16 h=(f16)f;
  hi[(size_t)rn*ld+k]=h; lo[(size_t)rn*ld+k]=(f16)(f-(float)h);
}
__global__ void lstm_bprep(const float* __restrict__ bih, const float* __restrict__ bhh,
                           float* __restrict__ bI){
  int rn=blockIdx.x*blockDim.x+threadIdx.x;
  if(rn<768){ int j=rn>>2,g=rn&3; int go=g*192+j; bI[rn]=bih[go]+bhh[go]; }
}

// ---------------- CSR build ----------------
__global__ void hist_kernel(const int* __restrict__ ei, int E, int N, int* __restrict__ deg){
  int e=blockIdx.x*blockDim.x+threadIdx.x;
  if(e>=E+N) return;
  int d=(e<E)? ei[E+e] : (e-E);
  atomicAdd(&deg[d],1);
}
__global__ void scan1_kernel(const int* __restrict__ deg, int* __restrict__ offs,
                             int* __restrict__ bsums, int N){
  __shared__ int sd[1024];
  int t=threadIdx.x;
  int i=blockIdx.x*1024+t;
  int v=(i<N)?deg[i]:0;
  sd[t]=v;
  __syncthreads();
  for(int s=1;s<1024;s<<=1){
    int u=(t>=s)?sd[t-s]:0;
    __syncthreads();
    sd[t]+=u;
    __syncthreads();
  }
  if(i<N) offs[i]=sd[t]-v;
  if(t==1023) bsums[blockIdx.x]=sd[1023];
}
__global__ void scan2_kernel(int* __restrict__ bsums, int* __restrict__ offs, int NB, int N){
  if(threadIdx.x==0&&blockIdx.x==0){
    int run=0;
    for(int b=0;b<NB;b++){int s=bsums[b]; bsums[b]=run; run+=s;}
    offs[N]=run;
  }
}
__global__ void scan3_kernel(int* __restrict__ offs, const int* __restrict__ bsums,
                             int* __restrict__ cursor, int N){
  int i=blockIdx.x*blockDim.x+threadIdx.x;
  if(i<N){
    int o=offs[i]+bsums[i>>10];
    offs[i]=o;
    cursor[i]=o;
  }
}
__global__ void scatter_kernel(const int* __restrict__ ei, int E, int N,
                               int* __restrict__ cursor, int* __restrict__ csr){
  int e=blockIdx.x*blockDim.x+threadIdx.x;
  if(e>=E+N) return;
  int s,d;
  if(e<E){ s=ei[e]; d=ei[E+e]; } else { s=e-E; d=s; }
  int pos=atomicAdd(&cursor[d],1);
  csr[pos]=s;
}

// ---------------- graph offsets: batch is sorted -> binary search ----------------
__global__ void goffs_kernel(const int* __restrict__ batch, int N, int G,
                             int* __restrict__ goffs){
  int g=blockIdx.x*blockDim.x+threadIdx.x;
  if (g>G) return;
  if (g==G){ goffs[G]=N; return; }
  int lo=0, hi=N;
  while (lo<hi){ int mid=(lo+hi)>>1; if (batch[mid]<g) lo=mid+1; else hi=mid; }
  goffs[g]=lo;
}

// ---------------- MFMA GEMM (fp16 in), 128x128 tile, fused epilogues --------------
// q-step schedule: per A-tile q, compute A x B_hi then A x B_lo (A staged ONCE).
// 2-step prefetch depth, counted vmcnt(8) steady state (4/0 at tail).
// MODE 0: GAT  — write htmp f16 + per-head es/ed dots (nd=1, NXB=1)
// MODE 1: LSTM — merged fwd+bwd (nd=2): gates, cbuf/h16 update, JK score atomics
struct GemmDesc {
  const f16* aq[2][5];        // [dir][q] A-tile sources
  const f16* bq[2][2][5];     // [dir][s][q] B hi/lo sources
  int lda[5], ldb[5];
  int nq, nd, M, GY, NXB;
  // MODE 0
  f16* htmp; const float* as_; const float* ad_; float* es; float* ed;
  // MODE 1
  f16* h16[2]; float* cbuf[2]; const float* bias[2]; const float* wa[2];
  float* score; int l_out[2]; int firstStep;
};

template<int MODE>
__global__ __launch_bounds__(256) void gemm_mfma(GemmDesc d){
  __shared__ __align__(16) char smraw[65536];   // A dbuf 2x16KB + B dbuf 2x16KB; EP alias
  const int TILE = 128*64;
  f16* Ab0=(f16*)smraw;      f16* Ab1=Ab0+TILE;
  f16* Bb0=Ab1+TILE;         f16* Bb1=Bb0+TILE;
  float* EP = (float*)smraw;

  // XCD-aware remap: all panels of one row-panel land on one XCD
  const int wg = blockIdx.x;
  const int xcd = wg & 7, kk0 = wg >> 3;
  const int nxt = d.nd * d.NXB;
  const int xbg = kk0 % nxt;
  const int yp  = xcd + 8*(kk0 / nxt);
  if (yp >= d.GY) return;
  const int dir = (xbg >= d.NXB) ? 1 : 0;
  const int xb  = xbg - dir*d.NXB;

  const int t = threadIdx.x;
  const int wv = t>>6, ln = t&63;
  const int m0 = yp*128, n0 = xb*128;
  const int wr = (wv>>1)*64, wc = (wv&1)*64;
  f32x4 acc[4][4];
#pragma unroll
  for(int i=0;i<4;i++)
#pragma unroll
  for(int j=0;j<4;j++) acc[i][j]=(f32x4){0.f,0.f,0.f,0.f};

  const int sR = ln>>3;                    // row within 8-row group
  const int sC = ((ln&7)*8) ^ (sR<<3);     // SWIZZLED source col (f16 elems)

  // precomputed per-lane staging offsets (one 64-bit add per load afterwards)
  int offA128[4],offA192[4],offB128[4],offB192[4];
#pragma unroll
  for(int i=0;i<4;i++){
    int ga = m0 + i*32 + wv*8 + sR; if (ga >= d.M) ga = d.M-1;
    int gb = n0 + i*32 + wv*8 + sR;
    offA128[i]=ga*128+sC; offA192[i]=ga*192+sC;
    offB128[i]=gb*128+sC; offB192[i]=gb*192+sC;
  }

  auto issueA=[&](int q,int buf){
    const f16* src = d.aq[dir][q];
    const bool wide = (d.lda[q]==192);
    f16* dst = buf? Ab1:Ab0;
#pragma unroll
    for(int i=0;i<4;i++){
      int off = wide? offA192[i]:offA128[i];
      __builtin_amdgcn_global_load_lds(
        (const __attribute__((address_space(1))) unsigned int*)(src+off),
        (__attribute__((address_space(3))) unsigned int*)&dst[(i*32+wv*8)*64],16,0,0);
    }
  };
  auto issueB=[&](int s,int q,int buf){
    const f16* src = d.bq[dir][s][q];
    const bool wide = (d.ldb[q]==192);
    f16* dst = buf? Bb1:Bb0;
#pragma unroll
    for(int i=0;i<4;i++){
      int off = wide? offB192[i]:offB128[i];
      __builtin_amdgcn_global_load_lds(
        (const __attribute__((address_space(1))) unsigned int*)(src+off),
        (__attribute__((address_space(3))) unsigned int*)&dst[(i*32+wv*8)*64],16,0,0);
    }
  };

  // prologue: A[0]->Ab0, Bhi[0]->Bb0
  issueA(0,0);
  issueB(0,0,0);
  const int nst = 2*d.nq;
  for (int st2=0; st2<nst; st2++){
    const int q = st2>>1, s = st2&1;
    const int pa = q&1, pb = st2&1;
    if (s==0){
      issueB(1,q,pb^1);                      // Blo[q] -> other B buf
      if (q+1<d.nq) issueA(q+1,pa^1);        // A[q+1] -> other A buf
    } else if (q+1<d.nq){
      issueB(0,q+1,pb^1);                    // Bhi[q+1]
    }
    if (st2 < nst-2)       asm volatile("s_waitcnt vmcnt(8)" ::: "memory");
    else if (st2 == nst-2) asm volatile("s_waitcnt vmcnt(4)" ::: "memory");
    else                   asm volatile("s_waitcnt vmcnt(0)" ::: "memory");
    __builtin_amdgcn_sched_barrier(0);
    __builtin_amdgcn_s_barrier();            // current tiles staged by all waves
    __builtin_amdgcn_sched_barrier(0);
    const f16* As = pa? Ab1:Ab0;
    const f16* Bs = pb? Bb1:Bb0;
    const int swz = (ln&7)<<3;               // read-side XOR
#pragma unroll
    for (int kk=0; kk<2; kk++){
      f16x8 av[4], bv[4];
#pragma unroll
      for (int i=0;i<4;i++)
        av[i] = *(const f16x8*)&As[(wr + i*16 + (ln&15))*64 + ((kk*32 + (ln>>4)*8) ^ swz)];
#pragma unroll
      for (int j=0;j<4;j++)
        bv[j] = *(const f16x8*)&Bs[(wc + j*16 + (ln&15))*64 + ((kk*32 + (ln>>4)*8) ^ swz)];
#pragma unroll
      for (int i=0;i<4;i++)
#pragma unroll
      for (int j=0;j<4;j++)
        acc[i][j] = __builtin_amdgcn_mfma_f32_16x16x32_f16(av[i], bv[j], acc[i][j], 0,0,0);
    }
    __builtin_amdgcn_sched_barrier(0);
    __builtin_amdgcn_s_barrier();            // reads done; next step may DMA-overwrite
  }

  // ---- fused epilogue: two 64-row phases staged through EP (aliases staging LDS) ----
  const int lc2 = ln&15, lr4 = (ln>>4)*4;
  const int row4 = t>>2, q4 = t&3;     // 64 rows x 4 col-quarters (32 cols each)
#pragma unroll
  for (int ph=0; ph<2; ph++){
    __syncthreads();
    if ((wv>>1) == ph){
#pragma unroll
      for (int i=0;i<4;i++){
#pragma unroll
        for (int jf=0;jf<4;jf++){
          int col = wc + jf*16 + lc2;
#pragma unroll
          for (int r=0;r<4;r++)
            EP[(i*16+lr4+r)*132 + col] = acc[i][jf][r];
        }
      }
    }
    __syncthreads();
    int grow = m0 + ph*64 + row4;
    if (grow < d.M){
      if (MODE==0){
        float s=0.f, dd=0.f;
        const float* asp = d.as_ + q4*32;
        const float* adp = d.ad_ + q4*32;
#pragma unroll
        for (int q8=0;q8<4;q8++){
          f16x8 pk;
#pragma unroll
          for (int r=0;r<8;r++){
            float v = EP[row4*132 + q4*32 + q8*8 + r];
            pk[r] = (f16)v;
            s  += v*asp[q8*8+r];
            dd += v*adp[q8*8+r];
          }
          *(f16x8*)&d.htmp[(size_t)grow*128 + q4*32 + q8*8] = pk;
        }
        d.es[grow*4+q4] = s;
        d.ed[grow*4+q4] = dd;
      } else {
        float sc = 0.f;
        int jg0 = xb*32 + q4*8;
        size_t hbase = (size_t)grow*192 + jg0;
        const float* bI = d.bias[dir] + xb*128 + q4*32;
        f16* h16d = d.h16[dir];
        float* cbufd = d.cbuf[dir];
        const float* wad = d.wa[dir];
        f16x8 hl;
#pragma unroll
        for (int j=0;j<8;j++){
          float4 z = *(float4*)&EP[row4*132 + q4*32 + j*4];
          float zi=z.x+bI[j*4+0], zf=z.y+bI[j*4+1], zg=z.z+bI[j*4+2], zo=z.w+bI[j*4+3];
          float cold = d.firstStep ? 0.f : cbufd[hbase+j];
          float c = fsig(zf)*cold + fsig(zi)*ftanh(zg);
          float h = fsig(zo)*ftanh(c);
          cbufd[hbase+j] = c;
          hl[j] = (f16)h;
          sc += h * wad[jg0+j];
        }
        *(f16x8*)&h16d[hbase] = hl;
        sc += __shfl_xor(sc,1);
        sc += __shfl_xor(sc,2);
        if (q4==0) atomicAdd(&d.score[(size_t)grow*3 + d.l_out[dir]], sc);
      }
    }
  }
}

// ---------------- GAT attention: single pass, f16 gather ----------------
__global__ __launch_bounds__(256) void attn_kernel(const f16* __restrict__ htmp,
   const float* __restrict__ es, const float* __restrict__ ed,
   const int* __restrict__ offs, const int* __restrict__ csr,
   const float* __restrict__ bias, f16* __restrict__ xsl, int N){
  int v=blockIdx.x*4+(threadIdx.x>>6);
  if(v>=N) return;
  int lane=threadIdx.x&63;
  int hd=lane>>4;          // head for this lane's channels
  int c0=lane*2;
  int beg=offs[v], end=offs[v+1];
  float edv=ed[v*4+hd];
  float ssum=0.f,a0=0.f,a1=0.f;
  for(int i=beg;i<end;i++){
    int s=csr[i];
    float e=es[s*4+hd]+edv;
    e=(e>0.f)?e:0.2f*e;
    float ex=__expf(e);          // no max-shift needed: e is O(+-5), softmax invariant
    ssum+=ex;
    union {unsigned u; f16 h[2];} pk;
    pk.u = *reinterpret_cast<const unsigned*>(&htmp[(size_t)s*128+c0]);
    a0+=ex*(float)pk.h[0]; a1+=ex*(float)pk.h[1];
  }
  float inv=1.0f/(ssum+1e-16f);
  float o0=fmaxf(a0*inv+bias[c0],0.f), o1=fmaxf(a1*inv+bias[c0+1],0.f);
  union { f16 h[2]; unsigned u; } pko;
  pko.h[0]=(f16)o0; pko.h[1]=(f16)o1;
  *reinterpret_cast<unsigned*>(&xsl[(size_t)v*128+c0]) = pko.u;
}

// ---------------- JK softmax + weighted sum + mean-pool: one block per graph ------
__global__ __launch_bounds__(256) void jk_pool_kernel(const f16* __restrict__ xs, size_t xstride,
   const float* __restrict__ score, const int* __restrict__ goffs,
   float* __restrict__ pooled, int G){
  int g=blockIdx.x;
  int beg=goffs[g], end=goffs[g+1];
  int c=threadIdx.x&127, half=threadIdx.x>>7;
  float acc=0.f;
  for(int n=beg+half; n<end; n+=2){
    float s0=score[n*3],s1=score[n*3+1],s2=score[n*3+2];
    float m=fmaxf(s0,fmaxf(s1,s2));
    float e0=__expf(s0-m),e1=__expf(s1-m),e2=__expf(s2-m);
    float inv=rcpf(e0+e1+e2);
    size_t base=(size_t)n*128+c;
    acc += ((float)xs[base]*e0+(float)xs[xstride+base]*e1+(float)xs[2*xstride+base]*e2)*inv;
  }
  __shared__ float red[128];
  if(half==1) red[c]=acc;
  __syncthreads();
  if(half==0){
    float tot=acc+red[c];
    float cnt=(float)(end-beg);
    pooled[(size_t)g*128+c]=tot*rcpf(fmaxf(cnt,1.0f));
  }
}

__global__ __launch_bounds__(128) void final_kernel(const float* __restrict__ pooled,
   const float* __restrict__ Wl, const float* __restrict__ bl,
   float* __restrict__ out, int G){
  int g=blockIdx.x; int c=threadIdx.x;
  float pv=pooled[(size_t)g*128+c];
  float p0=pv*Wl[c*2], p1=pv*Wl[c*2+1];
  for(int s=32;s>=1;s>>=1){ p0+=__shfl_down(p0,s); p1+=__shfl_down(p1,s); }
  __shared__ float sm[4];
  int w=c>>6;
  if((c&63)==0){ sm[w*2]=p0; sm[w*2+1]=p1; }
  __syncthreads();
  if(c==0){
    out[g*2+0]=sm[0]+sm[2]+bl[0];
    out[g*2+1]=sm[1]+sm[3]+bl[1];
  }
}

// ---------------- launch ----------------
extern "C" void kernel_launch(void* const* d_in, const int* in_sizes, int n_in,
                              void* d_out, int out_size, void* d_ws, size_t ws_size,
                              hipStream_t stream) {
  const float* x     = (const float*)d_in[0];
  const int*   ei    = (const int*)d_in[1];
  const int*   batch = (const int*)d_in[2];
  const float* W[3]  = {(const float*)d_in[3],(const float*)d_in[7],(const float*)d_in[11]};
  const float* AS[3] = {(const float*)d_in[4],(const float*)d_in[8],(const float*)d_in[12]};
  const float* AD[3] = {(const float*)d_in[5],(const float*)d_in[9],(const float*)d_in[13]};
  const float* BV[3] = {(const float*)d_in[6],(const float*)d_in[10],(const float*)d_in[14]};
  const float* Wih[2]= {(const float*)d_in[15],(const float*)d_in[19]};
  const float* Whh[2]= {(const float*)d_in[16],(const float*)d_in[20]};
  const float* bih[2]= {(const float*)d_in[17],(const float*)d_in[21]};
  const float* bhh[2]= {(const float*)d_in[18],(const float*)d_in[22]};
  const float* Wa    = (const float*)d_in[23];
  const float* Wl    = (const float*)d_in[25];
  const float* bl    = (const float*)d_in[26];
  float* out = (float*)d_out;

  const int N  = in_sizes[2];
  const int E  = in_sizes[1]/2;
  const int ET = E+N;
  const int G  = out_size/2;
  const int Mpad = CDIV(N,128)*128;
  const int GY = CDIV(N,128);
  const int GYp = CDIV(GY,8)*8;

  // ---- workspace carve (256B aligned) ----
  char* p = (char*)d_ws;
  auto alloc = [&](size_t bytes)->char*{ char* r=p; p += ((bytes+255)/256)*256; return r; };
  // fixed region
  int*   deg    = (int*)  alloc((size_t)N*4);
  int*   offs   = (int*)  alloc((size_t)(N+1)*4);
  int*   cursor = (int*)  alloc((size_t)N*4);
  int*   bsums  = (int*)  alloc((size_t)CDIV(N,1024)*4);
  int*   csr    = (int*)  alloc((size_t)ET*4);
  int*   goffs  = (int*)  alloc((size_t)(G+1)*4);
  f16*   WtH[3], *WtL[3];
  for(int l=0;l<3;l++){ WtH[l]=(f16*)alloc(128*128*2); WtL[l]=(f16*)alloc(128*128*2); }
  f16 *WihH[2],*WihL[2],*WhhH[2],*WhhL[2];
  float* bsumI[2];
  for(int d2=0;d2<2;d2++){
    WihH[d2]=(f16*)alloc(768*128*2); WihL[d2]=(f16*)alloc(768*128*2);
    WhhH[d2]=(f16*)alloc(768*192*2); WhhL[d2]=(f16*)alloc(768*192*2);
    bsumI[d2]=(float*)alloc(768*4);
  }
  f16*   xs16   = (f16*)  alloc((size_t)3*Mpad*128*2);
  float* score  = (float*)alloc((size_t)N*3*4);
  float* pooled = (float*)alloc((size_t)G*128*4);
  char* P = p;   // phase-overlaid region
  auto al256 = [](size_t b)->size_t{ return ((b+255)/256)*256; };
  // GAT phase overlay
  f16*   x016 = (f16*)P;
  f16*   htmp = (f16*)(P + al256((size_t)Mpad*128*2));
  float* esb  = (float*)((char*)htmp + al256((size_t)Mpad*128*2));
  float* edb  = (float*)((char*)esb + al256((size_t)N*4*4));
  // LSTM phase overlay (GAT buffers dead by then): separate state per direction
  f16*  h16s[2]; float* cbufs[2];
  {
    char* q = P;
    h16s[0]=(f16*)q;     q += al256((size_t)Mpad*192*2);
    cbufs[0]=(float*)q;  q += al256((size_t)Mpad*192*4);
    h16s[1]=(f16*)q;     q += al256((size_t)Mpad*192*2);
    cbufs[1]=(float*)q;
  }

  const size_t xstride = (size_t)Mpad*128;

  // ---- 0. weight/input prep ----
  f2h_kernel<<<512,256,0,stream>>>(x, x016, (size_t)N*128);
  for(int l=0;l<3;l++) wtrans_kernel<<<128,128,0,stream>>>(W[l], WtH[l], WtL[l]);
  for(int d2=0;d2<2;d2++){
    lstm_wprep<<<768,128,0,stream>>>(Wih[d2], WihH[d2], WihL[d2], 128);
    lstm_wprep<<<768,192,0,stream>>>(Whh[d2], WhhH[d2], WhhL[d2], 192);
    lstm_bprep<<<3,256,0,stream>>>(bih[d2], bhh[d2], bsumI[d2]);
  }
  zero_kernel<<<64,256,0,stream>>>(score,(size_t)N*3);
  goffs_kernel<<<CDIV(G+1,256),256,0,stream>>>(batch,N,G,goffs);

  // ---- 1. CSR build ----
  zero_kernel<<<64,256,0,stream>>>((float*)deg,(size_t)N);
  hist_kernel<<<CDIV(ET,256),256,0,stream>>>(ei,E,N,deg);
  int NB = CDIV(N,1024);
  scan1_kernel<<<NB,1024,0,stream>>>(deg,offs,bsums,N);
  scan2_kernel<<<1,64,0,stream>>>(bsums,offs,NB,N);
  scan3_kernel<<<CDIV(N,256),256,0,stream>>>(offs,bsums,cursor,N);
  scatter_kernel<<<CDIV(ET,256),256,0,stream>>>(ei,E,N,cursor,csr);

  // ---- 2. GAT layers (A fp16, B hi/lo shared-A q-steps; fused htmp/es/ed epilogue) ----
  const f16* ain = x016;
  for (int l=0; l<3; l++){
    GemmDesc gd{};
    gd.nq=2; gd.nd=1; gd.M=N; gd.GY=GY; gd.NXB=1;
    gd.htmp=htmp; gd.as_=AS[l]; gd.ad_=AD[l]; gd.es=esb; gd.ed=edb;
    for(int qq=0;qq<2;qq++){
      gd.aq[0][qq]=ain+qq*64;           gd.lda[qq]=128;
      gd.bq[0][0][qq]=WtH[l]+qq*64;
      gd.bq[0][1][qq]=WtL[l]+qq*64;     gd.ldb[qq]=128;
    }
    gemm_mfma<0><<<GYp,256,0,stream>>>(gd);
    attn_kernel<<<CDIV(N,4),256,0,stream>>>(htmp,esb,edb,offs,csr,BV[l],
                                            xs16+(size_t)l*xstride,N);
    ain = xs16+(size_t)l*xstride;
  }

  // ---- 3. bidirectional LSTM: fwd+bwd merged per step, gates+scores fused ----
  for (int st=0; st<3; st++){
    GemmDesc gd{};
    gd.nd=2; gd.NXB=6; gd.M=N; gd.GY=GY;
    gd.nq = (st==0)?2:5;
    gd.score=score; gd.firstStep=(st==0);
    for(int dir2=0;dir2<2;dir2++){
      int l_in = dir2? (2-st):st;
      gd.l_out[dir2]=l_in;
      const f16* xt = xs16 + (size_t)l_in*xstride;
      gd.h16[dir2]=h16s[dir2]; gd.cbuf[dir2]=cbufs[dir2];
      gd.bias[dir2]=bsumI[dir2]; gd.wa[dir2]=Wa+dir2*192;
      for(int qq=0;qq<2;qq++){
        gd.aq[dir2][qq]=xt+qq*64;
        gd.bq[dir2][0][qq]=WihH[dir2]+qq*64;
        gd.bq[dir2][1][qq]=WihL[dir2]+qq*64;
      }
      for(int qq=2;qq<5;qq++){
        gd.aq[dir2][qq]=h16s[dir2]+(qq-2)*64;
        gd.bq[dir2][0][qq]=WhhH[dir2]+(qq-2)*64;
        gd.bq[dir2][1][qq]=WhhL[dir2]+(qq-2)*64;
      }
    }
    gd.lda[0]=gd.lda[1]=128; gd.lda[2]=gd.lda[3]=gd.lda[4]=192;
    gd.ldb[0]=gd.ldb[1]=128; gd.ldb[2]=gd.ldb[3]=gd.ldb[4]=192;
    gemm_mfma<1><<<12*GYp,256,0,stream>>>(gd);
  }

  // ---- 4. JK attention + pooling + final linear ----
  jk_pool_kernel<<<G,256,0,stream>>>(xs16,xstride,score,goffs,pooled,G);
  final_kernel<<<G,128,0,stream>>>(pooled,Wl,bl,out,G);
}

// Round 8
// 974.726 us; speedup vs baseline: 2.8725x; 1.0069x over previous
//
#include <hip/hip_runtime.h>
#include <math.h>

#define CDIV(a,b) (((a)+(b)-1)/(b))

typedef _Float16 f16;
typedef _Float16 f16x8 __attribute__((ext_vector_type(8)));
typedef float f32x4 __attribute__((ext_vector_type(4)));

__device__ __forceinline__ float rcpf(float x){ return __builtin_amdgcn_rcpf(x); }
__device__ __forceinline__ float fsig(float x){ return rcpf(1.0f+__expf(-x)); }
__device__ __forceinline__ float ftanh(float x){ float e=__expf(2.0f*x); return 1.0f-2.0f*rcpf(e+1.0f); }

// ---------------- utility ----------------
__global__ void zero_kernel(float* __restrict__ p, size_t n){
  size_t i=(size_t)blockIdx.x*blockDim.x+threadIdx.x;
  size_t st=(size_t)gridDim.x*blockDim.x;
  for(;i<n;i+=st) p[i]=0.0f;
}

// ---------------- fp16 conversion prep ----------------
__global__ void f2h_kernel(const float* __restrict__ s, f16* __restrict__ d, size_t n){
  size_t i=(size_t)blockIdx.x*blockDim.x+threadIdx.x;
  size_t st=(size_t)gridDim.x*blockDim.x;
  for(;i<n;i+=st) d[i]=(f16)s[i];
}
// W [128 in][128 out] -> Wt hi/lo [out][in]
__global__ void wtrans_kernel(const float* __restrict__ W, f16* __restrict__ hi,
                              f16* __restrict__ lo){
  int o=blockIdx.x, i=threadIdx.x;
  float f=W[(size_t)i*128+o];
  f16 h=(f16)f; hi[o*128+i]=h; lo[o*128+i]=(f16)(f-(float)h);
}
// LSTM weights: rows reordered gate-major -> interleaved row' = j*4+gate; split hi/lo
__global__ void lstm_wprep(const float* __restrict__ W, f16* __restrict__ hi,
                           f16* __restrict__ lo, int ld){
  int rn=blockIdx.x; int k=threadIdx.x;
  int j=rn>>2, gate=rn&3;
  float f=W[(size_t)(gate*192+j)*ld + k];
  f16 h=(f16)f;
  hi[(size_t)rn*ld+k]=h; lo[(size_t)rn*ld+k]=(f16)(f-(float)h);
}
__global__ void lstm_bprep(const float* __restrict__ bih, const float* __restrict__ bhh,
                           float* __restrict__ bI){
  int rn=blockIdx.x*blockDim.x+threadIdx.x;
  if(rn<768){ int j=rn>>2,g=rn&3; int go=g*192+j; bI[rn]=bih[go]+bhh[go]; }
}

// ---------------- CSR build ----------------
__global__ void hist_kernel(const int* __restrict__ ei, int E, int N, int* __restrict__ deg){
  int e=blockIdx.x*blockDim.x+threadIdx.x;
  if(e>=E+N) return;
  int d=(e<E)? ei[E+e] : (e-E);
  atomicAdd(&deg[d],1);
}
__global__ void scan1_kernel(const int* __restrict__ deg, int* __restrict__ offs,
                             int* __restrict__ bsums, int N){
  __shared__ int sd[1024];
  int t=threadIdx.x;
  int i=blockIdx.x*1024+t;
  int v=(i<N)?deg[i]:0;
  sd[t]=v;
  __syncthreads();
  for(int s=1;s<1024;s<<=1){
    int u=(t>=s)?sd[t-s]:0;
    __syncthreads();
    sd[t]+=u;
    __syncthreads();
  }
  if(i<N) offs[i]=sd[t]-v;
  if(t==1023) bsums[blockIdx.x]=sd[1023];
}
__global__ void scan2_kernel(int* __restrict__ bsums, int* __restrict__ offs, int NB, int N){
  if(threadIdx.x==0&&blockIdx.x==0){
    int run=0;
    for(int b=0;b<NB;b++){int s=bsums[b]; bsums[b]=run; run+=s;}
    offs[N]=run;
  }
}
__global__ void scan3_kernel(int* __restrict__ offs, const int* __restrict__ bsums,
                             int* __restrict__ cursor, int N){
  int i=blockIdx.x*blockDim.x+threadIdx.x;
  if(i<N){
    int o=offs[i]+bsums[i>>10];
    offs[i]=o;
    cursor[i]=o;
  }
}
__global__ void scatter_kernel(const int* __restrict__ ei, int E, int N,
                               int* __restrict__ cursor, int* __restrict__ csr){
  int e=blockIdx.x*blockDim.x+threadIdx.x;
  if(e>=E+N) return;
  int s,d;
  if(e<E){ s=ei[e]; d=ei[E+e]; } else { s=e-E; d=s; }
  int pos=atomicAdd(&cursor[d],1);
  csr[pos]=s;
}

// ---------------- graph offsets: batch is sorted -> binary search ----------------
__global__ void goffs_kernel(const int* __restrict__ batch, int N, int G,
                             int* __restrict__ goffs){
  int g=blockIdx.x*blockDim.x+threadIdx.x;
  if (g>G) return;
  if (g==G){ goffs[G]=N; return; }
  int lo=0, hi=N;
  while (lo<hi){ int mid=(lo+hi)>>1; if (batch[mid]<g) lo=mid+1; else hi=mid; }
  goffs[g]=lo;
}

// ---------------- MFMA GEMM (fp16 in), 128x128 tile, fused epilogues --------------
// q-step schedule, A-fragments held in REGISTERS across the hi/lo pair.
// A double-buffer (16KBx2) + B TRIPLE-buffer (16KBx3) = 80KB -> one barrier/step:
// DMA at step S overwrites the buffer last read at step S-2 (2-barrier separation).
// Counted waits: vmcnt(8) steady, 4 at nst-2, 0 at last.
// MODE 0: GAT  — write htmp f16 + per-head es/ed dots (nd=1, NXB=1)
// MODE 1: LSTM — merged fwd+bwd (nd=2): gates, cbuf/h16 update, JK score atomics
struct GemmDesc {
  const f16* aq[2][5];        // [dir][q] A-tile sources
  const f16* bq[2][2][5];     // [dir][s][q] B hi/lo sources
  int lda[5], ldb[5];
  int nq, nd, M, GY, NXB;
  // MODE 0
  f16* htmp; const float* as_; const float* ad_; float* es; float* ed;
  // MODE 1
  f16* h16[2]; float* cbuf[2]; const float* bias[2]; const float* wa[2];
  float* score; int l_out[2]; int firstStep;
};

template<int MODE>
__global__ __launch_bounds__(256) void gemm_mfma(GemmDesc d){
  __shared__ __align__(16) char smraw[81920];   // A 2x16KB + B 3x16KB; EP alias (33.8KB)
  const int TILE = 128*64;
  f16* Ab0=(f16*)smraw;      f16* Ab1=Ab0+TILE;
  f16* Bb0=Ab1+TILE;         f16* Bb1=Bb0+TILE;   f16* Bb2=Bb1+TILE;
  float* EP = (float*)smraw;

  // XCD-aware remap: all panels of one row-panel land on one XCD
  const int wg = blockIdx.x;
  const int xcd = wg & 7, kk0 = wg >> 3;
  const int nxt = d.nd * d.NXB;
  const int xbg = kk0 % nxt;
  const int yp  = xcd + 8*(kk0 / nxt);
  if (yp >= d.GY) return;
  const int dir = (xbg >= d.NXB) ? 1 : 0;
  const int xb  = xbg - dir*d.NXB;

  const int t = threadIdx.x;
  const int wv = t>>6, ln = t&63;
  const int m0 = yp*128, n0 = xb*128;
  const int wr = (wv>>1)*64, wc = (wv&1)*64;
  f32x4 acc[4][4];
#pragma unroll
  for(int i=0;i<4;i++)
#pragma unroll
  for(int j=0;j<4;j++) acc[i][j]=(f32x4){0.f,0.f,0.f,0.f};

  const int sR = ln>>3;                    // row within 8-row group
  const int sC = ((ln&7)*8) ^ (sR<<3);     // SWIZZLED source col (f16 elems)

  // precomputed per-lane staging offsets (one 64-bit add per load afterwards)
  int offA128[4],offA192[4],offB128[4],offB192[4];
#pragma unroll
  for(int i=0;i<4;i++){
    int ga = m0 + i*32 + wv*8 + sR; if (ga >= d.M) ga = d.M-1;
    int gb = n0 + i*32 + wv*8 + sR;
    offA128[i]=ga*128+sC; offA192[i]=ga*192+sC;
    offB128[i]=gb*128+sC; offB192[i]=gb*192+sC;
  }

  auto Bsel=[&](int i)->f16*{ return i==0?Bb0:(i==1?Bb1:Bb2); };

  auto issueA=[&](int q,int buf){
    const f16* src = d.aq[dir][q];
    const bool wide = (d.lda[q]==192);
    f16* dst = buf? Ab1:Ab0;
#pragma unroll
    for(int i=0;i<4;i++){
      int off = wide? offA192[i]:offA128[i];
      __builtin_amdgcn_global_load_lds(
        (const __attribute__((address_space(1))) unsigned int*)(src+off),
        (__attribute__((address_space(3))) unsigned int*)&dst[(i*32+wv*8)*64],16,0,0);
    }
  };
  auto issueB=[&](int s,int q,int buf){
    const f16* src = d.bq[dir][s][q];
    const bool wide = (d.ldb[q]==192);
    f16* dst = Bsel(buf);
#pragma unroll
    for(int i=0;i<4;i++){
      int off = wide? offB192[i]:offB128[i];
      __builtin_amdgcn_global_load_lds(
        (const __attribute__((address_space(1))) unsigned int*)(src+off),
        (__attribute__((address_space(3))) unsigned int*)&dst[(i*32+wv*8)*64],16,0,0);
    }
  };

  // prologue: A[0]->Ab0, Bhi[0]->Bb0
  issueA(0,0);
  issueB(0,0,0);
  const int nst = 2*d.nq;
  const int swz = (ln&7)<<3;               // read-side XOR
  f16x8 avr[2][4];                         // A fragments held across the hi/lo pair
  int bcur=0, bnxt=1;
  for (int st2=0; st2<nst; st2++){
    const int q = st2>>1, s = st2&1;
    if (s==0){
      issueB(1,q,bnxt);                    // Blo[q] -> buffer read at step st2-2
      if (q+1<d.nq) issueA(q+1,(q+1)&1);   // A[q+1] -> Ab reg-read at step st2-2
    } else if (q+1<d.nq){
      issueB(0,q+1,bnxt);                  // Bhi[q+1]
    }
    if (st2 < nst-2)       asm volatile("s_waitcnt vmcnt(8)" ::: "memory");
    else if (st2 == nst-2) asm volatile("s_waitcnt vmcnt(4)" ::: "memory");
    else                   asm volatile("s_waitcnt vmcnt(0)" ::: "memory");
    __builtin_amdgcn_sched_barrier(0);
    __builtin_amdgcn_s_barrier();          // single barrier: tiles staged, 2-step reuse dist
    __builtin_amdgcn_sched_barrier(0);
    if (s==0){
      const f16* As = (q&1)? Ab1:Ab0;
#pragma unroll
      for (int kk=0; kk<2; kk++)
#pragma unroll
      for (int i=0;i<4;i++)
        avr[kk][i] = *(const f16x8*)&As[(wr + i*16 + (ln&15))*64 + ((kk*32 + (ln>>4)*8) ^ swz)];
    }
    const f16* Bs = Bsel(bcur);
#pragma unroll
    for (int kk=0; kk<2; kk++){
      f16x8 bv[4];
#pragma unroll
      for (int j=0;j<4;j++)
        bv[j] = *(const f16x8*)&Bs[(wc + j*16 + (ln&15))*64 + ((kk*32 + (ln>>4)*8) ^ swz)];
#pragma unroll
      for (int i=0;i<4;i++)
#pragma unroll
      for (int j=0;j<4;j++)
        acc[i][j] = __builtin_amdgcn_mfma_f32_16x16x32_f16(avr[kk][i], bv[j], acc[i][j], 0,0,0);
    }
    bcur = bnxt; bnxt = (bnxt==2)?0:bnxt+1;
  }

  // ---- fused epilogue: two 64-row phases staged through EP (aliases staging LDS) ----
  const int lc2 = ln&15, lr4 = (ln>>4)*4;
  const int row4 = t>>2, q4 = t&3;     // 64 rows x 4 col-quarters (32 cols each)
#pragma unroll
  for (int ph=0; ph<2; ph++){
    __syncthreads();
    if ((wv>>1) == ph){
#pragma unroll
      for (int i=0;i<4;i++){
#pragma unroll
        for (int jf=0;jf<4;jf++){
          int col = wc + jf*16 + lc2;
#pragma unroll
          for (int r=0;r<4;r++)
            EP[(i*16+lr4+r)*132 + col] = acc[i][jf][r];
        }
      }
    }
    __syncthreads();
    int grow = m0 + ph*64 + row4;
    if (grow < d.M){
      if (MODE==0){
        float s=0.f, dd=0.f;
        const float* asp = d.as_ + q4*32;
        const float* adp = d.ad_ + q4*32;
#pragma unroll
        for (int q8=0;q8<4;q8++){
          f16x8 pk;
#pragma unroll
          for (int r=0;r<8;r++){
            float v = EP[row4*132 + q4*32 + q8*8 + r];
            pk[r] = (f16)v;
            s  += v*asp[q8*8+r];
            dd += v*adp[q8*8+r];
          }
          *(f16x8*)&d.htmp[(size_t)grow*128 + q4*32 + q8*8] = pk;
        }
        d.es[grow*4+q4] = s;
        d.ed[grow*4+q4] = dd;
      } else {
        float sc = 0.f;
        int jg0 = xb*32 + q4*8;
        size_t hbase = (size_t)grow*192 + jg0;
        const float* bI = d.bias[dir] + xb*128 + q4*32;
        f16* h16d = d.h16[dir];
        float* cbufd = d.cbuf[dir];
        const float* wad = d.wa[dir];
        f16x8 hl;
#pragma unroll
        for (int j=0;j<8;j++){
          float4 z = *(float4*)&EP[row4*132 + q4*32 + j*4];
          float zi=z.x+bI[j*4+0], zf=z.y+bI[j*4+1], zg=z.z+bI[j*4+2], zo=z.w+bI[j*4+3];
          float cold = d.firstStep ? 0.f : cbufd[hbase+j];
          float c = fsig(zf)*cold + fsig(zi)*ftanh(zg);
          float h = fsig(zo)*ftanh(c);
          cbufd[hbase+j] = c;
          hl[j] = (f16)h;
          sc += h * wad[jg0+j];
        }
        *(f16x8*)&h16d[hbase] = hl;
        sc += __shfl_xor(sc,1);
        sc += __shfl_xor(sc,2);
        if (q4==0) atomicAdd(&d.score[(size_t)grow*3 + d.l_out[dir]], sc);
      }
    }
  }
}

// ---------------- GAT attention: single pass, f16 gather ----------------
__global__ __launch_bounds__(256) void attn_kernel(const f16* __restrict__ htmp,
   const float* __restrict__ es, const float* __restrict__ ed,
   const int* __restrict__ offs, const int* __restrict__ csr,
   const float* __restrict__ bias, f16* __restrict__ xsl, int N){
  int v=blockIdx.x*4+(threadIdx.x>>6);
  if(v>=N) return;
  int lane=threadIdx.x&63;
  int hd=lane>>4;          // head for this lane's channels
  int c0=lane*2;
  int beg=offs[v], end=offs[v+1];
  float edv=ed[v*4+hd];
  float ssum=0.f,a0=0.f,a1=0.f;
  for(int i=beg;i<end;i++){
    int s=csr[i];
    float e=es[s*4+hd]+edv;
    e=(e>0.f)?e:0.2f*e;
    float ex=__expf(e);          // no max-shift needed: e is O(+-5), softmax invariant
    ssum+=ex;
    union {unsigned u; f16 h[2];} pk;
    pk.u = *reinterpret_cast<const unsigned*>(&htmp[(size_t)s*128+c0]);
    a0+=ex*(float)pk.h[0]; a1+=ex*(float)pk.h[1];
  }
  float inv=1.0f/(ssum+1e-16f);
  float o0=fmaxf(a0*inv+bias[c0],0.f), o1=fmaxf(a1*inv+bias[c0+1],0.f);
  union { f16 h[2]; unsigned u; } pko;
  pko.h[0]=(f16)o0; pko.h[1]=(f16)o1;
  *reinterpret_cast<unsigned*>(&xsl[(size_t)v*128+c0]) = pko.u;
}

// ---------------- JK softmax + weighted sum + mean-pool: one block per graph ------
__global__ __launch_bounds__(256) void jk_pool_kernel(const f16* __restrict__ xs, size_t xstride,
   const float* __restrict__ score, const int* __restrict__ goffs,
   float* __restrict__ pooled, int G){
  int g=blockIdx.x;
  int beg=goffs[g], end=goffs[g+1];
  int c=threadIdx.x&127, half=threadIdx.x>>7;
  float acc=0.f;
  for(int n=beg+half; n<end; n+=2){
    float s0=score[n*3],s1=score[n*3+1],s2=score[n*3+2];
    float m=fmaxf(s0,fmaxf(s1,s2));
    float e0=__expf(s0-m),e1=__expf(s1-m),e2=__expf(s2-m);
    float inv=rcpf(e0+e1+e2);
    size_t base=(size_t)n*128+c;
    acc += ((float)xs[base]*e0+(float)xs[xstride+base]*e1+(float)xs[2*xstride+base]*e2)*inv;
  }
  __shared__ float red[128];
  if(half==1) red[c]=acc;
  __syncthreads();
  if(half==0){
    float tot=acc+red[c];
    float cnt=(float)(end-beg);
    pooled[(size_t)g*128+c]=tot*rcpf(fmaxf(cnt,1.0f));
  }
}

__global__ __launch_bounds__(128) void final_kernel(const float* __restrict__ pooled,
   const float* __restrict__ Wl, const float* __restrict__ bl,
   float* __restrict__ out, int G){
  int g=blockIdx.x; int c=threadIdx.x;
  float pv=pooled[(size_t)g*128+c];
  float p0=pv*Wl[c*2], p1=pv*Wl[c*2+1];
  for(int s=32;s>=1;s>>=1){ p0+=__shfl_down(p0,s); p1+=__shfl_down(p1,s); }
  __shared__ float sm[4];
  int w=c>>6;
  if((c&63)==0){ sm[w*2]=p0; sm[w*2+1]=p1; }
  __syncthreads();
  if(c==0){
    out[g*2+0]=sm[0]+sm[2]+bl[0];
    out[g*2+1]=sm[1]+sm[3]+bl[1];
  }
}

// ---------------- launch ----------------
extern "C" void kernel_launch(void* const* d_in, const int* in_sizes, int n_in,
                              void* d_out, int out_size, void* d_ws, size_t ws_size,
                              hipStream_t stream) {
  const float* x     = (const float*)d_in[0];
  const int*   ei    = (const int*)d_in[1];
  const int*   batch = (const int*)d_in[2];
  const float* W[3]  = {(const float*)d_in[3],(const float*)d_in[7],(const float*)d_in[11]};
  const float* AS[3] = {(const float*)d_in[4],(const float*)d_in[8],(const float*)d_in[12]};
  const float* AD[3] = {(const float*)d_in[5],(const float*)d_in[9],(const float*)d_in[13]};
  const float* BV[3] = {(const float*)d_in[6],(const float*)d_in[10],(const float*)d_in[14]};
  const float* Wih[2]= {(const float*)d_in[15],(const float*)d_in[19]};
  const float* Whh[2]= {(const float*)d_in[16],(const float*)d_in[20]};
  const float* bih[2]= {(const float*)d_in[17],(const float*)d_in[21]};
  const float* bhh[2]= {(const float*)d_in[18],(const float*)d_in[22]};
  const float* Wa    = (const float*)d_in[23];
  const float* Wl    = (const float*)d_in[25];
  const float* bl    = (const float*)d_in[26];
  float* out = (float*)d_out;

  const int N  = in_sizes[2];
  const int E  = in_sizes[1]/2;
  const int ET = E+N;
  const int G  = out_size/2;
  const int Mpad = CDIV(N,128)*128;
  const int GY = CDIV(N,128);
  const int GYp = CDIV(GY,8)*8;

  // ---- workspace carve (256B aligned) ----
  char* p = (char*)d_ws;
  auto alloc = [&](size_t bytes)->char*{ char* r=p; p += ((bytes+255)/256)*256; return r; };
  // fixed region
  int*   deg    = (int*)  alloc((size_t)N*4);
  int*   offs   = (int*)  alloc((size_t)(N+1)*4);
  int*   cursor = (int*)  alloc((size_t)N*4);
  int*   bsums  = (int*)  alloc((size_t)CDIV(N,1024)*4);
  int*   csr    = (int*)  alloc((size_t)ET*4);
  int*   goffs  = (int*)  alloc((size_t)(G+1)*4);
  f16*   WtH[3], *WtL[3];
  for(int l=0;l<3;l++){ WtH[l]=(f16*)alloc(128*128*2); WtL[l]=(f16*)alloc(128*128*2); }
  f16 *WihH[2],*WihL[2],*WhhH[2],*WhhL[2];
  float* bsumI[2];
  for(int d2=0;d2<2;d2++){
    WihH[d2]=(f16*)alloc(768*128*2); WihL[d2]=(f16*)alloc(768*128*2);
    WhhH[d2]=(f16*)alloc(768*192*2); WhhL[d2]=(f16*)alloc(768*192*2);
    bsumI[d2]=(float*)alloc(768*4);
  }
  f16*   xs16   = (f16*)  alloc((size_t)3*Mpad*128*2);
  float* score  = (float*)alloc((size_t)N*3*4);
  float* pooled = (float*)alloc((size_t)G*128*4);
  char* P = p;   // phase-overlaid region
  auto al256 = [](size_t b)->size_t{ return ((b+255)/256)*256; };
  // GAT phase overlay
  f16*   x016 = (f16*)P;
  f16*   htmp = (f16*)(P + al256((size_t)Mpad*128*2));
  float* esb  = (float*)((char*)htmp + al256((size_t)Mpad*128*2));
  float* edb  = (float*)((char*)esb + al256((size_t)N*4*4));
  // LSTM phase overlay (GAT buffers dead by then): separate state per direction
  f16*  h16s[2]; float* cbufs[2];
  {
    char* q = P;
    h16s[0]=(f16*)q;     q += al256((size_t)Mpad*192*2);
    cbufs[0]=(float*)q;  q += al256((size_t)Mpad*192*4);
    h16s[1]=(f16*)q;     q += al256((size_t)Mpad*192*2);
    cbufs[1]=(float*)q;
  }

  const size_t xstride = (size_t)Mpad*128;

  // ---- 0. weight/input prep ----
  f2h_kernel<<<512,256,0,stream>>>(x, x016, (size_t)N*128);
  for(int l=0;l<3;l++) wtrans_kernel<<<128,128,0,stream>>>(W[l], WtH[l], WtL[l]);
  for(int d2=0;d2<2;d2++){
    lstm_wprep<<<768,128,0,stream>>>(Wih[d2], WihH[d2], WihL[d2], 128);
    lstm_wprep<<<768,192,0,stream>>>(Whh[d2], WhhH[d2], WhhL[d2], 192);
    lstm_bprep<<<3,256,0,stream>>>(bih[d2], bhh[d2], bsumI[d2]);
  }
  zero_kernel<<<64,256,0,stream>>>(score,(size_t)N*3);
  goffs_kernel<<<CDIV(G+1,256),256,0,stream>>>(batch,N,G,goffs);

  // ---- 1. CSR build ----
  zero_kernel<<<64,256,0,stream>>>((float*)deg,(size_t)N);
  hist_kernel<<<CDIV(ET,256),256,0,stream>>>(ei,E,N,deg);
  int NB = CDIV(N,1024);
  scan1_kernel<<<NB,1024,0,stream>>>(deg,offs,bsums,N);
  scan2_kernel<<<1,64,0,stream>>>(bsums,offs,NB,N);
  scan3_kernel<<<CDIV(N,256),256,0,stream>>>(offs,bsums,cursor,N);
  scatter_kernel<<<CDIV(ET,256),256,0,stream>>>(ei,E,N,cursor,csr);

  // ---- 2. GAT layers (A fp16, B hi/lo shared-A q-steps; fused htmp/es/ed epilogue) ----
  const f16* ain = x016;
  for (int l=0; l<3; l++){
    GemmDesc gd{};
    gd.nq=2; gd.nd=1; gd.M=N; gd.GY=GY; gd.NXB=1;
    gd.htmp=htmp; gd.as_=AS[l]; gd.ad_=AD[l]; gd.es=esb; gd.ed=edb;
    for(int qq=0;qq<2;qq++){
      gd.aq[0][qq]=ain+qq*64;           gd.lda[qq]=128;
      gd.bq[0][0][qq]=WtH[l]+qq*64;
      gd.bq[0][1][qq]=WtL[l]+qq*64;     gd.ldb[qq]=128;
    }
    gemm_mfma<0><<<GYp,256,0,stream>>>(gd);
    attn_kernel<<<CDIV(N,4),256,0,stream>>>(htmp,esb,edb,offs,csr,BV[l],
                                            xs16+(size_t)l*xstride,N);
    ain = xs16+(size_t)l*xstride;
  }

  // ---- 3. bidirectional LSTM: fwd+bwd merged per step, gates+scores fused ----
  for (int st=0; st<3; st++){
    GemmDesc gd{};
    gd.nd=2; gd.NXB=6; gd.M=N; gd.GY=GY;
    gd.nq = (st==0)?2:5;
    gd.score=score; gd.firstStep=(st==0);
    for(int dir2=0;dir2<2;dir2++){
      int l_in = dir2? (2-st):st;
      gd.l_out[dir2]=l_in;
      const f16* xt = xs16 + (size_t)l_in*xstride;
      gd.h16[dir2]=h16s[dir2]; gd.cbuf[dir2]=cbufs[dir2];
      gd.bias[dir2]=bsumI[dir2]; gd.wa[dir2]=Wa+dir2*192;
      for(int qq=0;qq<2;qq++){
        gd.aq[dir2][qq]=xt+qq*64;
        gd.bq[dir2][0][qq]=WihH[dir2]+qq*64;
        gd.bq[dir2][1][qq]=WihL[dir2]+qq*64;
      }
      for(int qq=2;qq<5;qq++){
        gd.aq[dir2][qq]=h16s[dir2]+(qq-2)*64;
        gd.bq[dir2][0][qq]=WhhH[dir2]+(qq-2)*64;
        gd.bq[dir2][1][qq]=WhhL[dir2]+(qq-2)*64;
      }
    }
    gd.lda[0]=gd.lda[1]=128; gd.lda[2]=gd.lda[3]=gd.lda[4]=192;
    gd.ldb[0]=gd.ldb[1]=128; gd.ldb[2]=gd.ldb[3]=gd.ldb[4]=192;
    gemm_mfma<1><<<12*GYp,256,0,stream>>>(gd);
  }

  // ---- 4. JK attention + pooling + final linear ----
  jk_pool_kernel<<<G,256,0,stream>>>(xs16,xstride,score,goffs,pooled,G);
  final_kernel<<<G,128,0,stream>>>(pooled,Wl,bl,out,G);
}

// Round 9
// 799.183 us; speedup vs baseline: 3.5035x; 1.2197x over previous
//
#include <hip/hip_runtime.h>
#include <math.h>

#define CDIV(a,b) (((a)+(b)-1)/(b))

typedef _Float16 f16;
typedef _Float16 f16x8 __attribute__((ext_vector_type(8)));
typedef float f32x4 __attribute__((ext_vector_type(4)));

__device__ __forceinline__ float rcpf(float x){ return __builtin_amdgcn_rcpf(x); }
__device__ __forceinline__ float fsig(float x){ return rcpf(1.0f+__expf(-x)); }
__device__ __forceinline__ float ftanh(float x){ float e=__expf(2.0f*x); return 1.0f-2.0f*rcpf(e+1.0f); }

// ---------------- utility ----------------
__global__ void zero_kernel(float* __restrict__ p, size_t n){
  size_t i=(size_t)blockIdx.x*blockDim.x+threadIdx.x;
  size_t st=(size_t)gridDim.x*blockDim.x;
  for(;i<n;i+=st) p[i]=0.0f;
}

// ---------------- fp16 conversion prep ----------------
__global__ void f2h_kernel(const float* __restrict__ s, f16* __restrict__ d, size_t n){
  size_t i=(size_t)blockIdx.x*blockDim.x+threadIdx.x;
  size_t st=(size_t)gridDim.x*blockDim.x;
  for(;i<n;i+=st) d[i]=(f16)s[i];
}
// W [128 in][128 out] -> Wt hi/lo [out][in]
__global__ void wtrans_kernel(const float* __restrict__ W, f16* __restrict__ hi,
                              f16* __restrict__ lo){
  int o=blockIdx.x, i=threadIdx.x;
  float f=W[(size_t)i*128+o];
  f16 h=(f16)f; hi[o*128+i]=h; lo[o*128+i]=(f16)(f-(float)h);
}
// LSTM weights: rows reordered gate-major -> interleaved row' = j*4+gate; split hi/lo
__global__ void lstm_wprep(const float* __restrict__ W, f16* __restrict__ hi,
                           f16* __restrict__ lo, int ld){
  int rn=blockIdx.x; int k=threadIdx.x;
  int j=rn>>2, gate=rn&3;
  float f=W[(size_t)(gate*192+j)*ld + k];
  f16 h=(f16)f;
  hi[(size_t)rn*ld+k]=h; lo[(size_t)rn*ld+k]=(f16)(f-(float)h);
}
__global__ void lstm_bprep(const float* __restrict__ bih, const float* __restrict__ bhh,
                           float* __restrict__ bI){
  int rn=blockIdx.x*blockDim.x+threadIdx.x;
  if(rn<768){ int j=rn>>2,g=rn&3; int go=g*192+j; bI[rn]=bih[go]+bhh[go]; }
}

// ---------------- CSR build ----------------
__global__ void hist_kernel(const int* __restrict__ ei, int E, int N, int* __restrict__ deg){
  int e=blockIdx.x*blockDim.x+threadIdx.x;
  if(e>=E+N) return;
  int d=(e<E)? ei[E+e] : (e-E);
  atomicAdd(&deg[d],1);
}
__global__ void scan1_kernel(const int* __restrict__ deg, int* __restrict__ offs,
                             int* __restrict__ bsums, int N){
  __shared__ int sd[1024];
  int t=threadIdx.x;
  int i=blockIdx.x*1024+t;
  int v=(i<N)?deg[i]:0;
  sd[t]=v;
  __syncthreads();
  for(int s=1;s<1024;s<<=1){
    int u=(t>=s)?sd[t-s]:0;
    __syncthreads();
    sd[t]+=u;
    __syncthreads();
  }
  if(i<N) offs[i]=sd[t]-v;
  if(t==1023) bsums[blockIdx.x]=sd[1023];
}
__global__ void scan2_kernel(int* __restrict__ bsums, int* __restrict__ offs, int NB, int N){
  if(threadIdx.x==0&&blockIdx.x==0){
    int run=0;
    for(int b=0;b<NB;b++){int s=bsums[b]; bsums[b]=run; run+=s;}
    offs[N]=run;
  }
}
__global__ void scan3_kernel(int* __restrict__ offs, const int* __restrict__ bsums,
                             int* __restrict__ cursor, int N){
  int i=blockIdx.x*blockDim.x+threadIdx.x;
  if(i<N){
    int o=offs[i]+bsums[i>>10];
    offs[i]=o;
    cursor[i]=o;
  }
}
__global__ void scatter_kernel(const int* __restrict__ ei, int E, int N,
                               int* __restrict__ cursor, int* __restrict__ csr){
  int e=blockIdx.x*blockDim.x+threadIdx.x;
  if(e>=E+N) return;
  int s,d;
  if(e<E){ s=ei[e]; d=ei[E+e]; } else { s=e-E; d=s; }
  int pos=atomicAdd(&cursor[d],1);
  csr[pos]=s;
}

// ---------------- graph offsets: batch is sorted -> binary search ----------------
__global__ void goffs_kernel(const int* __restrict__ batch, int N, int G,
                             int* __restrict__ goffs){
  int g=blockIdx.x*blockDim.x+threadIdx.x;
  if (g>G) return;
  if (g==G){ goffs[G]=N; return; }
  int lo=0, hi=N;
  while (lo<hi){ int mid=(lo+hi)>>1; if (batch[mid]<g) lo=mid+1; else hi=mid; }
  goffs[g]=lo;
}

// ---------------- MFMA GEMM (fp16 in), 128x128 tile, BK=32, fused epilogues ------
// q-step schedule over 32-K tiles, A-frags in regs across the hi/lo pair.
// A 2x8KB + B 3x8KB = 40KB -> 4 blocks/CU (latency hiding via occupancy).
// Counted waits: vmcnt(4) steady, 2 at nst-2, 0 at last. 2-step buffer reuse.
// 16B-granule swizzle: LDS(row,g) holds global granule (g-(row>>1))&3.
struct GemmDesc {
  const f16* aq[2][10];        // [dir][q2] A-tile sources (32-K tiles)
  const f16* bq[2][2][10];     // [dir][s][q2] B hi/lo sources
  int lda[10], ldb[10];
  int nq, nd, M, GY, NXB;
  // MODE 0
  f16* htmp; const float* as_; const float* ad_; float* es; float* ed;
  // MODE 1
  f16* h16[2]; float* cbuf[2]; const float* bias[2]; const float* wa[2];
  float* score; int l_out[2]; int firstStep;
};

template<int MODE>
__global__ __launch_bounds__(256) void gemm_mfma(GemmDesc d){
  __shared__ __align__(16) char smraw[40960];   // A 2x8KB + B 3x8KB; EP alias (33.8KB)
  const int TILE = 128*32;                      // f16 elems per 8KB tile
  f16* Ab0=(f16*)smraw;      f16* Ab1=Ab0+TILE;
  f16* Bb0=Ab1+TILE;         f16* Bb1=Bb0+TILE;   f16* Bb2=Bb1+TILE;
  float* EP = (float*)smraw;

  // XCD-aware remap: all panels of one row-panel land on one XCD
  const int wg = blockIdx.x;
  const int xcd = wg & 7, kk0 = wg >> 3;
  const int nxt = d.nd * d.NXB;
  const int xbg = kk0 % nxt;
  const int yp  = xcd + 8*(kk0 / nxt);
  if (yp >= d.GY) return;
  const int dir = (xbg >= d.NXB) ? 1 : 0;
  const int xb  = xbg - dir*d.NXB;

  const int t = threadIdx.x;
  const int wv = t>>6, ln = t&63;
  const int m0 = yp*128, n0 = xb*128;
  const int wr = (wv>>1)*64, wc = (wv&1)*64;
  f32x4 acc[4][4];
#pragma unroll
  for(int i=0;i<4;i++)
#pragma unroll
  for(int j=0;j<4;j++) acc[i][j]=(f32x4){0.f,0.f,0.f,0.f};

  // staging: lane covers (row = i*64 + wv*16 + (ln>>2), slot g = ln&3); source
  // granule gs = (g - (row>>1))&3 reduces to lane-constant:
  const int gs = ((ln&3) - ((ln>>3)&3)) & 3;
  // read-side granule: gp = (cg + (row>>1))&3, also lane-constant:
  const int gp = ((ln>>4) + (((ln&15)>>1)&3)) & 3;

  // precomputed per-lane staging offsets (f16 elems)
  int offA128[2],offA192[2],offB128[2],offB192[2];
#pragma unroll
  for(int i=0;i<2;i++){
    int ga = m0 + i*64 + wv*16 + (ln>>2); if (ga >= d.M) ga = d.M-1;
    int gb = n0 + i*64 + wv*16 + (ln>>2);
    offA128[i]=ga*128+gs*8; offA192[i]=ga*192+gs*8;
    offB128[i]=gb*128+gs*8; offB192[i]=gb*192+gs*8;
  }

  auto Bsel=[&](int i)->f16*{ return i==0?Bb0:(i==1?Bb1:Bb2); };

  auto issueA=[&](int q,int buf){
    const f16* src = d.aq[dir][q];
    const bool wide = (d.lda[q]==192);
    f16* dst = buf? Ab1:Ab0;
#pragma unroll
    for(int i=0;i<2;i++){
      int off = wide? offA192[i]:offA128[i];
      __builtin_amdgcn_global_load_lds(
        (const __attribute__((address_space(1))) unsigned int*)(src+off),
        (__attribute__((address_space(3))) unsigned int*)&dst[(i*64+wv*16)*32],16,0,0);
    }
  };
  auto issueB=[&](int s,int q,int buf){
    const f16* src = d.bq[dir][s][q];
    const bool wide = (d.ldb[q]==192);
    f16* dst = Bsel(buf);
#pragma unroll
    for(int i=0;i<2;i++){
      int off = wide? offB192[i]:offB128[i];
      __builtin_amdgcn_global_load_lds(
        (const __attribute__((address_space(1))) unsigned int*)(src+off),
        (__attribute__((address_space(3))) unsigned int*)&dst[(i*64+wv*16)*32],16,0,0);
    }
  };

  // prologue: A[0]->Ab0, Bhi[0]->Bb0
  issueA(0,0);
  issueB(0,0,0);
  const int nst = 2*d.nq;
  f16x8 avr[4];                            // A fragments held across the hi/lo pair
  int bcur=0, bnxt=1;
  for (int st2=0; st2<nst; st2++){
    const int q = st2>>1, s = st2&1;
    if (s==0){
      issueB(1,q,bnxt);                    // Blo[q] -> buffer read at step st2-2
      if (q+1<d.nq) issueA(q+1,(q+1)&1);   // A[q+1] -> Ab read at step st2-2
    } else if (q+1<d.nq){
      issueB(0,q+1,bnxt);                  // Bhi[q+1]
    }
    if (st2 < nst-2)       asm volatile("s_waitcnt vmcnt(4)" ::: "memory");
    else if (st2 == nst-2) asm volatile("s_waitcnt vmcnt(2)" ::: "memory");
    else                   asm volatile("s_waitcnt vmcnt(0)" ::: "memory");
    __builtin_amdgcn_sched_barrier(0);
    __builtin_amdgcn_s_barrier();          // tiles staged; 2-step reuse distance
    __builtin_amdgcn_sched_barrier(0);
    if (s==0){
      const f16* As = (q&1)? Ab1:Ab0;
#pragma unroll
      for (int i=0;i<4;i++)
        avr[i] = *(const f16x8*)&As[(wr + i*16 + (ln&15))*32 + gp*8];
    }
    const f16* Bs = Bsel(bcur);
    f16x8 bv[4];
#pragma unroll
    for (int j=0;j<4;j++)
      bv[j] = *(const f16x8*)&Bs[(wc + j*16 + (ln&15))*32 + gp*8];
#pragma unroll
    for (int i=0;i<4;i++)
#pragma unroll
    for (int j=0;j<4;j++)
      acc[i][j] = __builtin_amdgcn_mfma_f32_16x16x32_f16(avr[i], bv[j], acc[i][j], 0,0,0);
    bcur = bnxt; bnxt = (bnxt==2)?0:bnxt+1;
  }

  // ---- fused epilogue: two 64-row phases staged through EP (aliases staging LDS) ----
  const int lc2 = ln&15, lr4 = (ln>>4)*4;
  const int row4 = t>>2, q4 = t&3;     // 64 rows x 4 col-quarters (32 cols each)
#pragma unroll
  for (int ph=0; ph<2; ph++){
    __syncthreads();
    if ((wv>>1) == ph){
#pragma unroll
      for (int i=0;i<4;i++){
#pragma unroll
        for (int jf=0;jf<4;jf++){
          int col = wc + jf*16 + lc2;
#pragma unroll
          for (int r=0;r<4;r++)
            EP[(i*16+lr4+r)*132 + col] = acc[i][jf][r];
        }
      }
    }
    __syncthreads();
    int grow = m0 + ph*64 + row4;
    if (grow < d.M){
      if (MODE==0){
        float s=0.f, dd=0.f;
        const float* asp = d.as_ + q4*32;
        const float* adp = d.ad_ + q4*32;
#pragma unroll
        for (int q8=0;q8<4;q8++){
          f16x8 pk;
#pragma unroll
          for (int r=0;r<8;r++){
            float v = EP[row4*132 + q4*32 + q8*8 + r];
            pk[r] = (f16)v;
            s  += v*asp[q8*8+r];
            dd += v*adp[q8*8+r];
          }
          *(f16x8*)&d.htmp[(size_t)grow*128 + q4*32 + q8*8] = pk;
        }
        d.es[grow*4+q4] = s;
        d.ed[grow*4+q4] = dd;
      } else {
        float sc = 0.f;
        int jg0 = xb*32 + q4*8;
        size_t hbase = (size_t)grow*192 + jg0;
        const float* bI = d.bias[dir] + xb*128 + q4*32;
        f16* h16d = d.h16[dir];
        float* cbufd = d.cbuf[dir];
        const float* wad = d.wa[dir];
        f16x8 hl;
#pragma unroll
        for (int j=0;j<8;j++){
          float4 z = *(float4*)&EP[row4*132 + q4*32 + j*4];
          float zi=z.x+bI[j*4+0], zf=z.y+bI[j*4+1], zg=z.z+bI[j*4+2], zo=z.w+bI[j*4+3];
          float cold = d.firstStep ? 0.f : cbufd[hbase+j];
          float c = fsig(zf)*cold + fsig(zi)*ftanh(zg);
          float h = fsig(zo)*ftanh(c);
          cbufd[hbase+j] = c;
          hl[j] = (f16)h;
          sc += h * wad[jg0+j];
        }
        *(f16x8*)&h16d[hbase] = hl;
        sc += __shfl_xor(sc,1);
        sc += __shfl_xor(sc,2);
        if (q4==0) atomicAdd(&d.score[(size_t)grow*3 + d.l_out[dir]], sc);
      }
    }
  }
}

// ---------------- GAT attention: single pass, f16 gather, 4x batched loads --------
__global__ __launch_bounds__(256) void attn_kernel(const f16* __restrict__ htmp,
   const float* __restrict__ es, const float* __restrict__ ed,
   const int* __restrict__ offs, const int* __restrict__ csr,
   const float* __restrict__ bias, f16* __restrict__ xsl, int N){
  int v=blockIdx.x*4+(threadIdx.x>>6);
  if(v>=N) return;
  int lane=threadIdx.x&63;
  int hd=lane>>4;          // head for this lane's channels
  int c0=lane*2;
  int beg=offs[v], end=offs[v+1];
  float edv=ed[v*4+hd];
  float ssum=0.f,a0=0.f,a1=0.f;
  int i=beg;
  for(; i+4<=end; i+=4){
    int s0=csr[i],s1=csr[i+1],s2=csr[i+2],s3=csr[i+3];
    float E0=es[s0*4+hd],E1=es[s1*4+hd],E2=es[s2*4+hd],E3=es[s3*4+hd];
    unsigned u0=*(const unsigned*)&htmp[(size_t)s0*128+c0];
    unsigned u1=*(const unsigned*)&htmp[(size_t)s1*128+c0];
    unsigned u2=*(const unsigned*)&htmp[(size_t)s2*128+c0];
    unsigned u3=*(const unsigned*)&htmp[(size_t)s3*128+c0];
    float e0=E0+edv; e0=(e0>0.f)?e0:0.2f*e0; float x0=__expf(e0);
    float e1=E1+edv; e1=(e1>0.f)?e1:0.2f*e1; float x1=__expf(e1);
    float e2=E2+edv; e2=(e2>0.f)?e2:0.2f*e2; float x2=__expf(e2);
    float e3=E3+edv; e3=(e3>0.f)?e3:0.2f*e3; float x3=__expf(e3);
    ssum += (x0+x1)+(x2+x3);
    union {unsigned u; f16 h[2];} p0,p1,p2,p3;
    p0.u=u0; p1.u=u1; p2.u=u2; p3.u=u3;
    a0 += x0*(float)p0.h[0] + x1*(float)p1.h[0] + x2*(float)p2.h[0] + x3*(float)p3.h[0];
    a1 += x0*(float)p0.h[1] + x1*(float)p1.h[1] + x2*(float)p2.h[1] + x3*(float)p3.h[1];
  }
  for(; i<end; i++){
    int s=csr[i];
    float e=es[s*4+hd]+edv;
    e=(e>0.f)?e:0.2f*e;
    float ex=__expf(e);
    ssum+=ex;
    union {unsigned u; f16 h[2];} pk;
    pk.u = *reinterpret_cast<const unsigned*>(&htmp[(size_t)s*128+c0]);
    a0+=ex*(float)pk.h[0]; a1+=ex*(float)pk.h[1];
  }
  float inv=1.0f/(ssum+1e-16f);
  float o0=fmaxf(a0*inv+bias[c0],0.f), o1=fmaxf(a1*inv+bias[c0+1],0.f);
  union { f16 h[2]; unsigned u; } pko;
  pko.h[0]=(f16)o0; pko.h[1]=(f16)o1;
  *reinterpret_cast<unsigned*>(&xsl[(size_t)v*128+c0]) = pko.u;
}

// ---------------- JK softmax + weighted sum + mean-pool: one block per graph ------
__global__ __launch_bounds__(256) void jk_pool_kernel(const f16* __restrict__ xs, size_t xstride,
   const float* __restrict__ score, const int* __restrict__ goffs,
   float* __restrict__ pooled, int G){
  int g=blockIdx.x;
  int beg=goffs[g], end=goffs[g+1];
  int c=threadIdx.x&127, half=threadIdx.x>>7;
  float acc=0.f;
  for(int n=beg+half; n<end; n+=2){
    float s0=score[n*3],s1=score[n*3+1],s2=score[n*3+2];
    float m=fmaxf(s0,fmaxf(s1,s2));
    float e0=__expf(s0-m),e1=__expf(s1-m),e2=__expf(s2-m);
    float inv=rcpf(e0+e1+e2);
    size_t base=(size_t)n*128+c;
    acc += ((float)xs[base]*e0+(float)xs[xstride+base]*e1+(float)xs[2*xstride+base]*e2)*inv;
  }
  __shared__ float red[128];
  if(half==1) red[c]=acc;
  __syncthreads();
  if(half==0){
    float tot=acc+red[c];
    float cnt=(float)(end-beg);
    pooled[(size_t)g*128+c]=tot*rcpf(fmaxf(cnt,1.0f));
  }
}

__global__ __launch_bounds__(128) void final_kernel(const float* __restrict__ pooled,
   const float* __restrict__ Wl, const float* __restrict__ bl,
   float* __restrict__ out, int G){
  int g=blockIdx.x; int c=threadIdx.x;
  float pv=pooled[(size_t)g*128+c];
  float p0=pv*Wl[c*2], p1=pv*Wl[c*2+1];
  for(int s=32;s>=1;s>>=1){ p0+=__shfl_down(p0,s); p1+=__shfl_down(p1,s); }
  __shared__ float sm[4];
  int w=c>>6;
  if((c&63)==0){ sm[w*2]=p0; sm[w*2+1]=p1; }
  __syncthreads();
  if(c==0){
    out[g*2+0]=sm[0]+sm[2]+bl[0];
    out[g*2+1]=sm[1]+sm[3]+bl[1];
  }
}

// ---------------- launch ----------------
extern "C" void kernel_launch(void* const* d_in, const int* in_sizes, int n_in,
                              void* d_out, int out_size, void* d_ws, size_t ws_size,
                              hipStream_t stream) {
  const float* x     = (const float*)d_in[0];
  const int*   ei    = (const int*)d_in[1];
  const int*   batch = (const int*)d_in[2];
  const float* W[3]  = {(const float*)d_in[3],(const float*)d_in[7],(const float*)d_in[11]};
  const float* AS[3] = {(const float*)d_in[4],(const float*)d_in[8],(const float*)d_in[12]};
  const float* AD[3] = {(const float*)d_in[5],(const float*)d_in[9],(const float*)d_in[13]};
  const float* BV[3] = {(const float*)d_in[6],(const float*)d_in[10],(const float*)d_in[14]};
  const float* Wih[2]= {(const float*)d_in[15],(const float*)d_in[19]};
  const float* Whh[2]= {(const float*)d_in[16],(const float*)d_in[20]};
  const float* bih[2]= {(const float*)d_in[17],(const float*)d_in[21]};
  const float* bhh[2]= {(const float*)d_in[18],(const float*)d_in[22]};
  const float* Wa    = (const float*)d_in[23];
  const float* Wl    = (const float*)d_in[25];
  const float* bl    = (const float*)d_in[26];
  float* out = (float*)d_out;

  const int N  = in_sizes[2];
  const int E  = in_sizes[1]/2;
  const int ET = E+N;
  const int G  = out_size/2;
  const int Mpad = CDIV(N,128)*128;
  const int GY = CDIV(N,128);
  const int GYp = CDIV(GY,8)*8;

  // ---- workspace carve (256B aligned) ----
  char* p = (char*)d_ws;
  auto alloc = [&](size_t bytes)->char*{ char* r=p; p += ((bytes+255)/256)*256; return r; };
  // fixed region
  int*   deg    = (int*)  alloc((size_t)N*4);
  int*   offs   = (int*)  alloc((size_t)(N+1)*4);
  int*   cursor = (int*)  alloc((size_t)N*4);
  int*   bsums  = (int*)  alloc((size_t)CDIV(N,1024)*4);
  int*   csr    = (int*)  alloc((size_t)ET*4);
  int*   goffs  = (int*)  alloc((size_t)(G+1)*4);
  f16*   WtH[3], *WtL[3];
  for(int l=0;l<3;l++){ WtH[l]=(f16*)alloc(128*128*2); WtL[l]=(f16*)alloc(128*128*2); }
  f16 *WihH[2],*WihL[2],*WhhH[2],*WhhL[2];
  float* bsumI[2];
  for(int d2=0;d2<2;d2++){
    WihH[d2]=(f16*)alloc(768*128*2); WihL[d2]=(f16*)alloc(768*128*2);
    WhhH[d2]=(f16*)alloc(768*192*2); WhhL[d2]=(f16*)alloc(768*192*2);
    bsumI[d2]=(float*)alloc(768*4);
  }
  f16*   xs16   = (f16*)  alloc((size_t)3*Mpad*128*2);
  float* score  = (float*)alloc((size_t)N*3*4);
  float* pooled = (float*)alloc((size_t)G*128*4);
  char* P = p;   // phase-overlaid region
  auto al256 = [](size_t b)->size_t{ return ((b+255)/256)*256; };
  // GAT phase overlay
  f16*   x016 = (f16*)P;
  f16*   htmp = (f16*)(P + al256((size_t)Mpad*128*2));
  float* esb  = (float*)((char*)htmp + al256((size_t)Mpad*128*2));
  float* edb  = (float*)((char*)esb + al256((size_t)N*4*4));
  // LSTM phase overlay (GAT buffers dead by then): separate state per direction
  f16*  h16s[2]; float* cbufs[2];
  {
    char* q = P;
    h16s[0]=(f16*)q;     q += al256((size_t)Mpad*192*2);
    cbufs[0]=(float*)q;  q += al256((size_t)Mpad*192*4);
    h16s[1]=(f16*)q;     q += al256((size_t)Mpad*192*2);
    cbufs[1]=(float*)q;
  }

  const size_t xstride = (size_t)Mpad*128;

  // ---- 0. weight/input prep ----
  f2h_kernel<<<512,256,0,stream>>>(x, x016, (size_t)N*128);
  for(int l=0;l<3;l++) wtrans_kernel<<<128,128,0,stream>>>(W[l], WtH[l], WtL[l]);
  for(int d2=0;d2<2;d2++){
    lstm_wprep<<<768,128,0,stream>>>(Wih[d2], WihH[d2], WihL[d2], 128);
    lstm_wprep<<<768,192,0,stream>>>(Whh[d2], WhhH[d2], WhhL[d2], 192);
    lstm_bprep<<<3,256,0,stream>>>(bih[d2], bhh[d2], bsumI[d2]);
  }
  zero_kernel<<<64,256,0,stream>>>(score,(size_t)N*3);
  goffs_kernel<<<CDIV(G+1,256),256,0,stream>>>(batch,N,G,goffs);

  // ---- 1. CSR build ----
  zero_kernel<<<64,256,0,stream>>>((float*)deg,(size_t)N);
  hist_kernel<<<CDIV(ET,256),256,0,stream>>>(ei,E,N,deg);
  int NB = CDIV(N,1024);
  scan1_kernel<<<NB,1024,0,stream>>>(deg,offs,bsums,N);
  scan2_kernel<<<1,64,0,stream>>>(bsums,offs,NB,N);
  scan3_kernel<<<CDIV(N,256),256,0,stream>>>(offs,bsums,cursor,N);
  scatter_kernel<<<CDIV(ET,256),256,0,stream>>>(ei,E,N,cursor,csr);

  // ---- 2. GAT layers (A fp16, B hi/lo shared-A q-steps; fused htmp/es/ed epilogue) ----
  const f16* ain = x016;
  for (int l=0; l<3; l++){
    GemmDesc gd{};
    gd.nq=4; gd.nd=1; gd.M=N; gd.GY=GY; gd.NXB=1;
    gd.htmp=htmp; gd.as_=AS[l]; gd.ad_=AD[l]; gd.es=esb; gd.ed=edb;
    for(int qq=0;qq<4;qq++){
      gd.aq[0][qq]=ain+qq*32;           gd.lda[qq]=128;
      gd.bq[0][0][qq]=WtH[l]+qq*32;
      gd.bq[0][1][qq]=WtL[l]+qq*32;     gd.ldb[qq]=128;
    }
    gemm_mfma<0><<<GYp,256,0,stream>>>(gd);
    attn_kernel<<<CDIV(N,4),256,0,stream>>>(htmp,esb,edb,offs,csr,BV[l],
                                            xs16+(size_t)l*xstride,N);
    ain = xs16+(size_t)l*xstride;
  }

  // ---- 3. bidirectional LSTM: fwd+bwd merged per step, gates+scores fused ----
  for (int st=0; st<3; st++){
    GemmDesc gd{};
    gd.nd=2; gd.NXB=6; gd.M=N; gd.GY=GY;
    gd.nq = (st==0)?4:10;
    gd.score=score; gd.firstStep=(st==0);
    for(int dir2=0;dir2<2;dir2++){
      int l_in = dir2? (2-st):st;
      gd.l_out[dir2]=l_in;
      const f16* xt = xs16 + (size_t)l_in*xstride;
      gd.h16[dir2]=h16s[dir2]; gd.cbuf[dir2]=cbufs[dir2];
      gd.bias[dir2]=bsumI[dir2]; gd.wa[dir2]=Wa+dir2*192;
      for(int qq=0;qq<4;qq++){
        gd.aq[dir2][qq]=xt+qq*32;
        gd.bq[dir2][0][qq]=WihH[dir2]+qq*32;
        gd.bq[dir2][1][qq]=WihL[dir2]+qq*32;
      }
      for(int qq=4;qq<10;qq++){
        gd.aq[dir2][qq]=h16s[dir2]+(qq-4)*32;
        gd.bq[dir2][0][qq]=WhhH[dir2]+(qq-4)*32;
        gd.bq[dir2][1][qq]=WhhL[dir2]+(qq-4)*32;
      }
    }
    for(int qq=0;qq<4;qq++){ gd.lda[qq]=128; gd.ldb[qq]=128; }
    for(int qq=4;qq<10;qq++){ gd.lda[qq]=192; gd.ldb[qq]=192; }
    gemm_mfma<1><<<12*GYp,256,0,stream>>>(gd);
  }

  // ---- 4. JK attention + pooling + final linear ----
  jk_pool_kernel<<<G,256,0,stream>>>(xs16,xstride,score,goffs,pooled,G);
  final_kernel<<<G,128,0,stream>>>(pooled,Wl,bl,out,G);
}

// Round 10
// 616.900 us; speedup vs baseline: 4.5387x; 1.2955x over previous
//
#include <hip/hip_runtime.h>
#include <math.h>

#define CDIV(a,b) (((a)+(b)-1)/(b))

typedef _Float16 f16;
typedef _Float16 f16x8 __attribute__((ext_vector_type(8)));
typedef float f32x4 __attribute__((ext_vector_type(4)));

__device__ __forceinline__ float rcpf(float x){ return __builtin_amdgcn_rcpf(x); }
__device__ __forceinline__ float fsig(float x){ return rcpf(1.0f+__expf(-x)); }
__device__ __forceinline__ float ftanh(float x){ float e=__expf(2.0f*x); return 1.0f-2.0f*rcpf(e+1.0f); }

// ---------------- utility ----------------
__global__ void zero_kernel(float* __restrict__ p, size_t n){
  size_t i=(size_t)blockIdx.x*blockDim.x+threadIdx.x;
  size_t st=(size_t)gridDim.x*blockDim.x;
  for(;i<n;i+=st) p[i]=0.0f;
}

// ---------------- fp16 conversion prep ----------------
__global__ void f2h_kernel(const float* __restrict__ s, f16* __restrict__ d, size_t n){
  size_t i=(size_t)blockIdx.x*blockDim.x+threadIdx.x;
  size_t st=(size_t)gridDim.x*blockDim.x;
  for(;i<n;i+=st) d[i]=(f16)s[i];
}
// W [128 in][128 out] -> Wt hi/lo [out][in]
__global__ void wtrans_kernel(const float* __restrict__ W, f16* __restrict__ hi,
                              f16* __restrict__ lo){
  int o=blockIdx.x, i=threadIdx.x;
  float f=W[(size_t)i*128+o];
  f16 h=(f16)f; hi[o*128+i]=h; lo[o*128+i]=(f16)(f-(float)h);
}
// LSTM weights: rows reordered gate-major -> interleaved row' = j*4+gate (fp16 hi only)
__global__ void lstm_wprep(const float* __restrict__ W, f16* __restrict__ hi, int ld){
  int rn=blockIdx.x; int k=threadIdx.x;
  int j=rn>>2, gate=rn&3;
  hi[(size_t)rn*ld+k]=(f16)W[(size_t)(gate*192+j)*ld + k];
}
__global__ void lstm_bprep(const float* __restrict__ bih, const float* __restrict__ bhh,
                           float* __restrict__ bI){
  int rn=blockIdx.x*blockDim.x+threadIdx.x;
  if(rn<768){ int j=rn>>2,g=rn&3; int go=g*192+j; bI[rn]=bih[go]+bhh[go]; }
}

// ---------------- CSR build ----------------
__global__ void hist_kernel(const int* __restrict__ ei, int E, int N, int* __restrict__ deg){
  int e=blockIdx.x*blockDim.x+threadIdx.x;
  if(e>=E+N) return;
  int d=(e<E)? ei[E+e] : (e-E);
  atomicAdd(&deg[d],1);
}
__global__ void scan1_kernel(const int* __restrict__ deg, int* __restrict__ offs,
                             int* __restrict__ bsums, int N){
  __shared__ int sd[1024];
  int t=threadIdx.x;
  int i=blockIdx.x*1024+t;
  int v=(i<N)?deg[i]:0;
  sd[t]=v;
  __syncthreads();
  for(int s=1;s<1024;s<<=1){
    int u=(t>=s)?sd[t-s]:0;
    __syncthreads();
    sd[t]+=u;
    __syncthreads();
  }
  if(i<N) offs[i]=sd[t]-v;
  if(t==1023) bsums[blockIdx.x]=sd[1023];
}
__global__ void scan2_kernel(int* __restrict__ bsums, int* __restrict__ offs, int NB, int N){
  if(threadIdx.x==0&&blockIdx.x==0){
    int run=0;
    for(int b=0;b<NB;b++){int s=bsums[b]; bsums[b]=run; run+=s;}
    offs[N]=run;
  }
}
__global__ void scan3_kernel(int* __restrict__ offs, const int* __restrict__ bsums,
                             int* __restrict__ cursor, int N){
  int i=blockIdx.x*blockDim.x+threadIdx.x;
  if(i<N){
    int o=offs[i]+bsums[i>>10];
    offs[i]=o;
    cursor[i]=o;
  }
}
__global__ void scatter_kernel(const int* __restrict__ ei, int E, int N,
                               int* __restrict__ cursor, int* __restrict__ csr){
  int e=blockIdx.x*blockDim.x+threadIdx.x;
  if(e>=E+N) return;
  int s,d;
  if(e<E){ s=ei[e]; d=ei[E+e]; } else { s=e-E; d=s; }
  int pos=atomicAdd(&cursor[d],1);
  csr[pos]=s;
}

// ---------------- graph offsets: batch is sorted -> binary search ----------------
__global__ void goffs_kernel(const int* __restrict__ batch, int N, int G,
                             int* __restrict__ goffs){
  int g=blockIdx.x*blockDim.x+threadIdx.x;
  if (g>G) return;
  if (g==G){ goffs[G]=N; return; }
  int lo=0, hi=N;
  while (lo<hi){ int mid=(lo+hi)>>1; if (batch[mid]<g) lo=mid+1; else hi=mid; }
  goffs[g]=lo;
}

// ---------------- MFMA GEMM (fp16 in), 128x128 tile, BK=32, fused epilogues ------
// Flat pair list: step q consumes (aq[q], bq[q]). Double-buffered A/B (4x8KB=32KB),
// two barriers/step, counted vmcnt(4)/0. 16B-granule swizzle on stage+read.
// MODE 0: GAT  — hi/lo pairs; write htmp f16 + per-head es/ed (nd=1, NXB=1)
// MODE 1: LSTM — fp16-hi only, merged fwd+bwd (nd=2): gates, f16 c/h state, scores
struct GemmDesc {
  const f16* aq[2][12];        // [dir][q] A-tile sources (32-K tiles)
  const f16* bq[2][12];        // [dir][q] B-tile sources
  int lda[12], ldb[12];
  int nq, nd, M, GY, NXB;
  // MODE 0
  f16* htmp; const float* as_; const float* ad_; float* es; float* ed;
  // MODE 1
  f16* h16[2]; f16* cbuf[2]; const float* bias[2]; const float* wa[2];
  float* score; int l_out[2]; int firstStep; int lastStep;
};

template<int MODE>
__global__ __launch_bounds__(256) void gemm_mfma(GemmDesc d){
  __shared__ __align__(16) char smraw[33792];   // A 2x8KB + B 2x8KB; EP alias 33.8KB
  const int TILE = 128*32;                      // f16 elems per 8KB tile
  f16* Ab0=(f16*)smraw;      f16* Ab1=Ab0+TILE;
  f16* Bb0=Ab1+TILE;         f16* Bb1=Bb0+TILE;
  float* EP = (float*)smraw;

  // XCD-aware remap: all panels of one row-panel land on one XCD
  const int wg = blockIdx.x;
  const int xcd = wg & 7, kk0 = wg >> 3;
  const int nxt = d.nd * d.NXB;
  const int xbg = kk0 % nxt;
  const int yp  = xcd + 8*(kk0 / nxt);
  if (yp >= d.GY) return;
  const int dir = (xbg >= d.NXB) ? 1 : 0;
  const int xb  = xbg - dir*d.NXB;

  const int t = threadIdx.x;
  const int wv = t>>6, ln = t&63;
  const int m0 = yp*128, n0 = xb*128;
  const int wr = (wv>>1)*64, wc = (wv&1)*64;
  f32x4 acc[4][4];
#pragma unroll
  for(int i=0;i<4;i++)
#pragma unroll
  for(int j=0;j<4;j++) acc[i][j]=(f32x4){0.f,0.f,0.f,0.f};

  // staging: lane covers (row = i*64 + wv*16 + (ln>>2), slot g = ln&3)
  const int gs = ((ln&3) - ((ln>>3)&3)) & 3;           // source granule (lane-const)
  const int gp = ((ln>>4) + (((ln&15)>>1)&3)) & 3;     // read granule (lane-const)

  // precomputed per-lane staging offsets (f16 elems)
  int offA128[2],offA192[2],offB128[2],offB192[2];
#pragma unroll
  for(int i=0;i<2;i++){
    int ga = m0 + i*64 + wv*16 + (ln>>2); if (ga >= d.M) ga = d.M-1;
    int gb = n0 + i*64 + wv*16 + (ln>>2);
    offA128[i]=ga*128+gs*8; offA192[i]=ga*192+gs*8;
    offB128[i]=gb*128+gs*8; offB192[i]=gb*192+gs*8;
  }

  auto issue=[&](int q,int buf){
    const f16* aS=d.aq[dir][q]; const bool wa_=(d.lda[q]==192);
    const f16* bS=d.bq[dir][q]; const bool wb_=(d.ldb[q]==192);
    f16* Adst = buf? Ab1:Ab0;
    f16* Bdst = buf? Bb1:Bb0;
#pragma unroll
    for(int i=0;i<2;i++){
      int offa = wa_? offA192[i]:offA128[i];
      __builtin_amdgcn_global_load_lds(
        (const __attribute__((address_space(1))) unsigned int*)(aS+offa),
        (__attribute__((address_space(3))) unsigned int*)&Adst[(i*64+wv*16)*32],16,0,0);
      int offb = wb_? offB192[i]:offB128[i];
      __builtin_amdgcn_global_load_lds(
        (const __attribute__((address_space(1))) unsigned int*)(bS+offb),
        (__attribute__((address_space(3))) unsigned int*)&Bdst[(i*64+wv*16)*32],16,0,0);
    }
  };

  issue(0,0);
  for (int s=0; s<d.nq; s++){
    const int cur = s&1;
    if (s+1<d.nq){
      issue(s+1,cur^1);
      asm volatile("s_waitcnt vmcnt(4)" ::: "memory");   // step s's 4 loads done
    } else {
      asm volatile("s_waitcnt vmcnt(0)" ::: "memory");
    }
    __builtin_amdgcn_sched_barrier(0);
    __builtin_amdgcn_s_barrier();          // tile s staged by all waves
    __builtin_amdgcn_sched_barrier(0);
    const f16* As = cur? Ab1:Ab0;
    const f16* Bs = cur? Bb1:Bb0;
    f16x8 av[4], bv[4];
#pragma unroll
    for (int i=0;i<4;i++)
      av[i] = *(const f16x8*)&As[(wr + i*16 + (ln&15))*32 + gp*8];
#pragma unroll
    for (int j=0;j<4;j++)
      bv[j] = *(const f16x8*)&Bs[(wc + j*16 + (ln&15))*32 + gp*8];
#pragma unroll
    for (int i=0;i<4;i++)
#pragma unroll
    for (int j=0;j<4;j++)
      acc[i][j] = __builtin_amdgcn_mfma_f32_16x16x32_f16(av[i], bv[j], acc[i][j], 0,0,0);
    __builtin_amdgcn_sched_barrier(0);
    __builtin_amdgcn_s_barrier();          // reads done; next iter may DMA-overwrite
  }

  // ---- fused epilogue: two 64-row phases staged through EP (aliases staging LDS) ----
  const int lc2 = ln&15, lr4 = (ln>>4)*4;
  const int row4 = t>>2, q4 = t&3;     // 64 rows x 4 col-quarters (32 cols each)
#pragma unroll
  for (int ph=0; ph<2; ph++){
    __syncthreads();
    if ((wv>>1) == ph){
#pragma unroll
      for (int i=0;i<4;i++){
#pragma unroll
        for (int jf=0;jf<4;jf++){
          int col = wc + jf*16 + lc2;
#pragma unroll
          for (int r=0;r<4;r++)
            EP[(i*16+lr4+r)*132 + col] = acc[i][jf][r];
        }
      }
    }
    __syncthreads();
    int grow = m0 + ph*64 + row4;
    if (grow < d.M){
      if (MODE==0){
        float s=0.f, dd=0.f;
        const float* asp = d.as_ + q4*32;
        const float* adp = d.ad_ + q4*32;
#pragma unroll
        for (int q8=0;q8<4;q8++){
          f16x8 pk;
#pragma unroll
          for (int r=0;r<8;r++){
            float v = EP[row4*132 + q4*32 + q8*8 + r];
            pk[r] = (f16)v;
            s  += v*asp[q8*8+r];
            dd += v*adp[q8*8+r];
          }
          *(f16x8*)&d.htmp[(size_t)grow*128 + q4*32 + q8*8] = pk;
        }
        d.es[grow*4+q4] = s;
        d.ed[grow*4+q4] = dd;
      } else {
        float sc = 0.f;
        int jg0 = xb*32 + q4*8;
        size_t hbase = (size_t)grow*192 + jg0;
        const float* bI = d.bias[dir] + xb*128 + q4*32;
        f16* h16d = d.h16[dir];
        f16* cbufd = d.cbuf[dir];
        const float* wad = d.wa[dir];
        f16x8 cold8;
        if (!d.firstStep) cold8 = *(const f16x8*)&cbufd[hbase];
        f16x8 hl, cl;
#pragma unroll
        for (int j=0;j<8;j++){
          float4 z = *(float4*)&EP[row4*132 + q4*32 + j*4];
          float zi=z.x+bI[j*4+0], zf=z.y+bI[j*4+1], zg=z.z+bI[j*4+2], zo=z.w+bI[j*4+3];
          float cold = d.firstStep ? 0.f : (float)cold8[j];
          float c = fsig(zf)*cold + fsig(zi)*ftanh(zg);
          float h = fsig(zo)*ftanh(c);
          cl[j] = (f16)c;
          hl[j] = (f16)h;
          sc += h * wad[jg0+j];
        }
        if (!d.lastStep){
          *(f16x8*)&cbufd[hbase] = cl;
          *(f16x8*)&h16d[hbase] = hl;
        }
        sc += __shfl_xor(sc,1);
        sc += __shfl_xor(sc,2);
        if (q4==0) atomicAdd(&d.score[(size_t)grow*3 + d.l_out[dir]], sc);
      }
    }
  }
}

// ---------------- GAT attention: single pass, f16 gather, 4x batched loads --------
__global__ __launch_bounds__(256) void attn_kernel(const f16* __restrict__ htmp,
   const float* __restrict__ es, const float* __restrict__ ed,
   const int* __restrict__ offs, const int* __restrict__ csr,
   const float* __restrict__ bias, f16* __restrict__ xsl, int N){
  int v=blockIdx.x*4+(threadIdx.x>>6);
  if(v>=N) return;
  int lane=threadIdx.x&63;
  int hd=lane>>4;          // head for this lane's channels
  int c0=lane*2;
  int beg=offs[v], end=offs[v+1];
  float edv=ed[v*4+hd];
  float ssum=0.f,a0=0.f,a1=0.f;
  int i=beg;
  for(; i+4<=end; i+=4){
    int s0=csr[i],s1=csr[i+1],s2=csr[i+2],s3=csr[i+3];
    float E0=es[s0*4+hd],E1=es[s1*4+hd],E2=es[s2*4+hd],E3=es[s3*4+hd];
    unsigned u0=*(const unsigned*)&htmp[(size_t)s0*128+c0];
    unsigned u1=*(const unsigned*)&htmp[(size_t)s1*128+c0];
    unsigned u2=*(const unsigned*)&htmp[(size_t)s2*128+c0];
    unsigned u3=*(const unsigned*)&htmp[(size_t)s3*128+c0];
    float e0=E0+edv; e0=(e0>0.f)?e0:0.2f*e0; float x0=__expf(e0);
    float e1=E1+edv; e1=(e1>0.f)?e1:0.2f*e1; float x1=__expf(e1);
    float e2=E2+edv; e2=(e2>0.f)?e2:0.2f*e2; float x2=__expf(e2);
    float e3=E3+edv; e3=(e3>0.f)?e3:0.2f*e3; float x3=__expf(e3);
    ssum += (x0+x1)+(x2+x3);
    union {unsigned u; f16 h[2];} p0,p1,p2,p3;
    p0.u=u0; p1.u=u1; p2.u=u2; p3.u=u3;
    a0 += x0*(float)p0.h[0] + x1*(float)p1.h[0] + x2*(float)p2.h[0] + x3*(float)p3.h[0];
    a1 += x0*(float)p0.h[1] + x1*(float)p1.h[1] + x2*(float)p2.h[1] + x3*(float)p3.h[1];
  }
  for(; i<end; i++){
    int s=csr[i];
    float e=es[s*4+hd]+edv;
    e=(e>0.f)?e:0.2f*e;
    float ex=__expf(e);
    ssum+=ex;
    union {unsigned u; f16 h[2];} pk;
    pk.u = *reinterpret_cast<const unsigned*>(&htmp[(size_t)s*128+c0]);
    a0+=ex*(float)pk.h[0]; a1+=ex*(float)pk.h[1];
  }
  float inv=1.0f/(ssum+1e-16f);
  float o0=fmaxf(a0*inv+bias[c0],0.f), o1=fmaxf(a1*inv+bias[c0+1],0.f);
  union { f16 h[2]; unsigned u; } pko;
  pko.h[0]=(f16)o0; pko.h[1]=(f16)o1;
  *reinterpret_cast<unsigned*>(&xsl[(size_t)v*128+c0]) = pko.u;
}

// ---------------- JK softmax + weighted sum + mean-pool: one block per graph ------
__global__ __launch_bounds__(256) void jk_pool_kernel(const f16* __restrict__ xs, size_t xstride,
   const float* __restrict__ score, const int* __restrict__ goffs,
   float* __restrict__ pooled, int G){
  int g=blockIdx.x;
  int beg=goffs[g], end=goffs[g+1];
  int c=threadIdx.x&127, half=threadIdx.x>>7;
  float acc=0.f;
  for(int n=beg+half; n<end; n+=2){
    float s0=score[n*3],s1=score[n*3+1],s2=score[n*3+2];
    float m=fmaxf(s0,fmaxf(s1,s2));
    float e0=__expf(s0-m),e1=__expf(s1-m),e2=__expf(s2-m);
    float inv=rcpf(e0+e1+e2);
    size_t base=(size_t)n*128+c;
    acc += ((float)xs[base]*e0+(float)xs[xstride+base]*e1+(float)xs[2*xstride+base]*e2)*inv;
  }
  __shared__ float red[128];
  if(half==1) red[c]=acc;
  __syncthreads();
  if(half==0){
    float tot=acc+red[c];
    float cnt=(float)(end-beg);
    pooled[(size_t)g*128+c]=tot*rcpf(fmaxf(cnt,1.0f));
  }
}

__global__ __launch_bounds__(128) void final_kernel(const float* __restrict__ pooled,
   const float* __restrict__ Wl, const float* __restrict__ bl,
   float* __restrict__ out, int G){
  int g=blockIdx.x; int c=threadIdx.x;
  float pv=pooled[(size_t)g*128+c];
  float p0=pv*Wl[c*2], p1=pv*Wl[c*2+1];
  for(int s=32;s>=1;s>>=1){ p0+=__shfl_down(p0,s); p1+=__shfl_down(p1,s); }
  __shared__ float sm[4];
  int w=c>>6;
  if((c&63)==0){ sm[w*2]=p0; sm[w*2+1]=p1; }
  __syncthreads();
  if(c==0){
    out[g*2+0]=sm[0]+sm[2]+bl[0];
    out[g*2+1]=sm[1]+sm[3]+bl[1];
  }
}

// ---------------- launch ----------------
extern "C" void kernel_launch(void* const* d_in, const int* in_sizes, int n_in,
                              void* d_out, int out_size, void* d_ws, size_t ws_size,
                              hipStream_t stream) {
  const float* x     = (const float*)d_in[0];
  const int*   ei    = (const int*)d_in[1];
  const int*   batch = (const int*)d_in[2];
  const float* W[3]  = {(const float*)d_in[3],(const float*)d_in[7],(const float*)d_in[11]};
  const float* AS[3] = {(const float*)d_in[4],(const float*)d_in[8],(const float*)d_in[12]};
  const float* AD[3] = {(const float*)d_in[5],(const float*)d_in[9],(const float*)d_in[13]};
  const float* BV[3] = {(const float*)d_in[6],(const float*)d_in[10],(const float*)d_in[14]};
  const float* Wih[2]= {(const float*)d_in[15],(const float*)d_in[19]};
  const float* Whh[2]= {(const float*)d_in[16],(const float*)d_in[20]};
  const float* bih[2]= {(const float*)d_in[17],(const float*)d_in[21]};
  const float* bhh[2]= {(const float*)d_in[18],(const float*)d_in[22]};
  const float* Wa    = (const float*)d_in[23];
  const float* Wl    = (const float*)d_in[25];
  const float* bl    = (const float*)d_in[26];
  float* out = (float*)d_out;

  const int N  = in_sizes[2];
  const int E  = in_sizes[1]/2;
  const int ET = E+N;
  const int G  = out_size/2;
  const int Mpad = CDIV(N,128)*128;
  const int GY = CDIV(N,128);
  const int GYp = CDIV(GY,8)*8;

  // ---- workspace carve (256B aligned) ----
  char* p = (char*)d_ws;
  auto alloc = [&](size_t bytes)->char*{ char* r=p; p += ((bytes+255)/256)*256; return r; };
  // fixed region
  int*   deg    = (int*)  alloc((size_t)N*4);
  int*   offs   = (int*)  alloc((size_t)(N+1)*4);
  int*   cursor = (int*)  alloc((size_t)N*4);
  int*   bsums  = (int*)  alloc((size_t)CDIV(N,1024)*4);
  int*   csr    = (int*)  alloc((size_t)ET*4);
  int*   goffs  = (int*)  alloc((size_t)(G+1)*4);
  f16*   WtH[3], *WtL[3];
  for(int l=0;l<3;l++){ WtH[l]=(f16*)alloc(128*128*2); WtL[l]=(f16*)alloc(128*128*2); }
  f16 *WihH[2],*WhhH[2];
  float* bsumI[2];
  for(int d2=0;d2<2;d2++){
    WihH[d2]=(f16*)alloc(768*128*2);
    WhhH[d2]=(f16*)alloc(768*192*2);
    bsumI[d2]=(float*)alloc(768*4);
  }
  f16*   xs16   = (f16*)  alloc((size_t)3*Mpad*128*2);
  float* score  = (float*)alloc((size_t)N*3*4);
  float* pooled = (float*)alloc((size_t)G*128*4);
  char* P = p;   // phase-overlaid region
  auto al256 = [](size_t b)->size_t{ return ((b+255)/256)*256; };
  // GAT phase overlay
  f16*   x016 = (f16*)P;
  f16*   htmp = (f16*)(P + al256((size_t)Mpad*128*2));
  float* esb  = (float*)((char*)htmp + al256((size_t)Mpad*128*2));
  float* edb  = (float*)((char*)esb + al256((size_t)N*4*4));
  // LSTM phase overlay (GAT buffers dead by then): separate f16 state per direction
  f16*  h16s[2]; f16* cbufs[2];
  {
    char* q = P;
    h16s[0]=(f16*)q;   q += al256((size_t)Mpad*192*2);
    cbufs[0]=(f16*)q;  q += al256((size_t)Mpad*192*2);
    h16s[1]=(f16*)q;   q += al256((size_t)Mpad*192*2);
    cbufs[1]=(f16*)q;
  }

  const size_t xstride = (size_t)Mpad*128;

  // ---- 0. weight/input prep ----
  f2h_kernel<<<512,256,0,stream>>>(x, x016, (size_t)N*128);
  for(int l=0;l<3;l++) wtrans_kernel<<<128,128,0,stream>>>(W[l], WtH[l], WtL[l]);
  for(int d2=0;d2<2;d2++){
    lstm_wprep<<<768,128,0,stream>>>(Wih[d2], WihH[d2], 128);
    lstm_wprep<<<768,192,0,stream>>>(Whh[d2], WhhH[d2], 192);
    lstm_bprep<<<3,256,0,stream>>>(bih[d2], bhh[d2], bsumI[d2]);
  }
  zero_kernel<<<64,256,0,stream>>>(score,(size_t)N*3);
  goffs_kernel<<<CDIV(G+1,256),256,0,stream>>>(batch,N,G,goffs);

  // ---- 1. CSR build ----
  zero_kernel<<<64,256,0,stream>>>((float*)deg,(size_t)N);
  hist_kernel<<<CDIV(ET,256),256,0,stream>>>(ei,E,N,deg);
  int NB = CDIV(N,1024);
  scan1_kernel<<<NB,1024,0,stream>>>(deg,offs,bsums,N);
  scan2_kernel<<<1,64,0,stream>>>(bsums,offs,NB,N);
  scan3_kernel<<<CDIV(N,256),256,0,stream>>>(offs,bsums,cursor,N);
  scatter_kernel<<<CDIV(ET,256),256,0,stream>>>(ei,E,N,cursor,csr);

  // ---- 2. GAT layers (A fp16, B hi/lo pair list; fused htmp/es/ed epilogue) ----
  const f16* ain = x016;
  for (int l=0; l<3; l++){
    GemmDesc gd{};
    gd.nq=8; gd.nd=1; gd.M=N; gd.GY=GY; gd.NXB=1;
    gd.htmp=htmp; gd.as_=AS[l]; gd.ad_=AD[l]; gd.es=esb; gd.ed=edb;
    for(int qq=0;qq<4;qq++){
      gd.aq[0][2*qq+0]=ain+qq*32;  gd.bq[0][2*qq+0]=WtH[l]+qq*32;
      gd.aq[0][2*qq+1]=ain+qq*32;  gd.bq[0][2*qq+1]=WtL[l]+qq*32;
    }
    for(int qq=0;qq<8;qq++){ gd.lda[qq]=128; gd.ldb[qq]=128; }
    gemm_mfma<0><<<GYp,256,0,stream>>>(gd);
    attn_kernel<<<CDIV(N,4),256,0,stream>>>(htmp,esb,edb,offs,csr,BV[l],
                                            xs16+(size_t)l*xstride,N);
    ain = xs16+(size_t)l*xstride;
  }

  // ---- 3. bidirectional LSTM (fp16-hi weights): fwd+bwd merged, gates+scores fused ----
  for (int st=0; st<3; st++){
    GemmDesc gd{};
    gd.nd=2; gd.NXB=6; gd.M=N; gd.GY=GY;
    gd.nq = (st==0)?4:10;
    gd.score=score; gd.firstStep=(st==0); gd.lastStep=(st==2);
    for(int dir2=0;dir2<2;dir2++){
      int l_in = dir2? (2-st):st;
      gd.l_out[dir2]=l_in;
      const f16* xt = xs16 + (size_t)l_in*xstride;
      gd.h16[dir2]=h16s[dir2]; gd.cbuf[dir2]=cbufs[dir2];
      gd.bias[dir2]=bsumI[dir2]; gd.wa[dir2]=Wa+dir2*192;
      for(int qq=0;qq<4;qq++){
        gd.aq[dir2][qq]=xt+qq*32;
        gd.bq[dir2][qq]=WihH[dir2]+qq*32;
      }
      for(int qq=4;qq<10;qq++){
        gd.aq[dir2][qq]=h16s[dir2]+(qq-4)*32;
        gd.bq[dir2][qq]=WhhH[dir2]+(qq-4)*32;
      }
    }
    for(int qq=0;qq<4;qq++){ gd.lda[qq]=128; gd.ldb[qq]=128; }
    for(int qq=4;qq<10;qq++){ gd.lda[qq]=192; gd.ldb[qq]=192; }
    gemm_mfma<1><<<12*GYp,256,0,stream>>>(gd);
  }

  // ---- 4. JK attention + pooling + final linear ----
  jk_pool_kernel<<<G,256,0,stream>>>(xs16,xstride,score,goffs,pooled,G);
  final_kernel<<<G,128,0,stream>>>(pooled,Wl,bl,out,G);
}